// Round 9
// baseline (398.538 us; speedup 1.0000x reference)
//
#include <hip/hip_runtime.h>

typedef unsigned short u16;
typedef unsigned int u32;
typedef float f32x4v __attribute__((ext_vector_type(4)));
typedef __bf16 bf16x8 __attribute__((ext_vector_type(8)));

#define GAS __attribute__((address_space(1)))
#define LAS __attribute__((address_space(3)))

__device__ __forceinline__ u16 f2bf(float f) {
  u32 u = __builtin_bit_cast(u32, f);
  u32 r = (u + 0x7FFFu + ((u >> 16) & 1u)) >> 16;  // RNE
  return (u16)r;
}
__device__ __forceinline__ float bf2f(u16 h) {
  return __builtin_bit_cast(float, (u32)h << 16);
}
__device__ __forceinline__ void gld_lds16(const void* g, void* l) {
  __builtin_amdgcn_global_load_lds((const GAS void*)g, (LAS void*)l, 16, 0, 0);
}
#define VMCNT(N) asm volatile("s_waitcnt vmcnt(" #N ")" ::: "memory")
#define MFMA16(a, b, c) __builtin_amdgcn_mfma_f32_16x16x32_bf16((a), (b), (c), 0, 0, 0)

// ---------------------------------------------------------------------------
// 8-PHASE 256x256 MFMA GEMM (m201 structure, plain HIP).
// BK=64 K-tiles; 512 thr / 8 waves (2M x 4N), per-wave 128x64, acc 8x4.
// LDS 128 KB dynamic: A 2dbuf x 2half x [128][64] bf16 (64 KB) + B same.
// Per K-tile tau: 4 phases. Phase Q:
//   ds_read A-quadrant (4 x b128; Q0 also reads all 8 B frags -> registers)
//   stage ONE half-tile (2 glds): Q0->A0(t+1) Q1->A1(t+1) Q2->B0(t+2) Q3->B1(t+2)
//   Q3: vmcnt(4)  (3 half-tiles remain in flight - never drain in loop)
//   barrier; setprio(1); 16 MFMA; setprio(0); barrier
// Tail: stage targets clamp to T-1 -> identical-data restage (race-free).
// Bank-conflict fix: per-row chunk rotation slot=(g+(row&7))&7 applied on the
// glds SOURCE k-chunk and the ds_read address (both-sides; LDS dest linear).
// 1D grid + XCD-chunked remap, y(N)-fastest so A-tile sharers stay on 1 XCD.
// C[m][n] = sum_k A[m][k]*B[n][k]; fp32 partial at Cp + z*strC; z = zb*S+s.
// CONV=1: B rows are pixels of zero-padded channel-last stack [nImg][900][Cin].
// ---------------------------------------------------------------------------
template <int CONV>
__global__ __launch_bounds__(512, 2) void gemm8p(
    const u16* __restrict__ A, const u16* __restrict__ B, float* __restrict__ Cp,
    int M, int N, int Kc, int fullK, int S,
    long strA, long strB, long strC, int Cin, int gx, int gy, int nwg)
{
  const int cpx = (int)gridDim.x >> 3;
  const int L = ((int)blockIdx.x & 7) * cpx + ((int)blockIdx.x >> 3);
  if (L >= nwg) return;
  const int by = L % gy;
  const int rest = L / gy;
  const int bx = rest % gx;
  const int z = rest / gx;

  extern __shared__ u16 smem[];          // A: 4 x 8192 u16, B: +32768
  const int t = threadIdx.x, lane = t & 63, wave = t >> 6;
  const int zb = z / S, s = z - zb * S;
  const int m0 = bx * 256, n0 = by * 256;
  const int kbeg = s * Kc;
  const int T = Kc >> 6;                 // K-tiles of 64 (always >= 2 here)

  // ---- staging map: thread t -> (row q*64+(t>>3), slot t&7) per half.
  // source k-chunk g = (slot - (row&7)) & 7  (row&7 == (t>>3)&7 for both q).
  const int srow = t >> 3;
  const int g = ((t & 7) - (srow & 7)) & 7;
  const int ldsoff = t * 8;              // u16; within wave = lane*16B (glds-legal)

  const u16* Asrc[2][2];
  #pragma unroll
  for (int h = 0; h < 2; ++h)
    #pragma unroll
    for (int q = 0; q < 2; ++q) {
      int r = m0 + h * 128 + q * 64 + srow; if (r >= M) r = M - 1;
      Asrc[h][q] = A + (long)zb * strA + (long)r * fullK + kbeg + g * 8;
    }
  const u16* Bsrc[2][2];
  #pragma unroll
  for (int h = 0; h < 2; ++h)
    #pragma unroll
    for (int q = 0; q < 2; ++q) {
      if constexpr (CONV) {
        int pn = n0 + h * 128 + q * 64 + srow; if (pn >= N) pn = 0;
        const int img = pn / 784, p = pn - img * 784;
        const int py = p / 28, px = p - py * 28;
        Bsrc[h][q] = B + ((long)img * 900 + (py + 1) * 30 + (px + 1)) * Cin + g * 8;
      } else {
        int r = n0 + h * 128 + q * 64 + srow; if (r >= N) r = N - 1;
        Bsrc[h][q] = B + (long)zb * strB + (long)r * fullK + kbeg + g * 8;
      }
    }

  auto stageA = [&](int tile, int h) {
    u16* d = smem + (((tile & 1) * 2 + h) * 8192);
    const long ko = (long)tile * 64;
    gld_lds16(Asrc[h][0] + ko, d + ldsoff);
    gld_lds16(Asrc[h][1] + ko, d + 4096 + ldsoff);
  };
  auto stageB = [&](int tile, int h) {
    u16* d = smem + 32768 + (((tile & 1) * 2 + h) * 8192);
    long off;
    if constexpr (CONV) {
      const int kg = kbeg + tile * 64;         // 64-aligned; Cin%64==0 -> tap uniform
      const int tap = kg / Cin, kc2 = kg - tap * Cin;
      off = (long)((tap / 3 - 1) * 30 + (tap % 3 - 1)) * Cin + kc2;
    } else {
      off = (long)tile * 64;
    }
    gld_lds16(Bsrc[h][0] + off, d + ldsoff);
    gld_lds16(Bsrc[h][1] + off, d + 4096 + ldsoff);
  };

  // ---- reader setup ----
  const int wm = wave & 1, wn = wave >> 1;
  const int lr = lane & 15, hi = lane >> 4;
  const int slot0 = ((hi + (lr & 7)) & 7) * 8;        // u16 offset, k-step 0
  const int slot1 = (((hi + 4) + (lr & 7)) & 7) * 8;  // k-step 1
  f32x4v acc[8][4] = {};
  bf16x8 breg[4][2];

  // ---- prologue: queue = B0(0),B1(0),A0(0),A1(0),B0(1),B1(1) ----
  stageB(0, 0); stageB(0, 1);
  stageA(0, 0); stageA(0, 1);
  if (T > 1) { stageB(1, 0); stageB(1, 1); }
  else       { stageB(0, 0); stageB(0, 1); }    // keep queue depth (idempotent)
  VMCNT(4);                                     // tile0 halves complete
  __builtin_amdgcn_s_barrier();

  for (int tau = 0; tau < T; ++tau) {
    const int d = tau & 1;
    const u16* aB = smem + ((d * 2 + wm) * 8192);
    const u16* bB = smem + 32768 + ((d * 2 + (wn >> 1)) * 8192);
    const int ta = (tau + 1 < T) ? tau + 1 : T - 1;
    const int tb = (tau + 2 < T) ? tau + 2 : T - 1;
    #pragma unroll
    for (int Q = 0; Q < 4; ++Q) {
      bf16x8 aph[2][2];
      #pragma unroll
      for (int m2 = 0; m2 < 2; ++m2) {
        const int lrow = (Q * 2 + m2) * 16 + lr;
        aph[m2][0] = *(const bf16x8*)&aB[lrow * 64 + slot0];
        aph[m2][1] = *(const bf16x8*)&aB[lrow * 64 + slot1];
      }
      if (Q == 0) {
        #pragma unroll
        for (int n = 0; n < 4; ++n) {
          const int lrow = (wn & 1) * 64 + n * 16 + lr;
          breg[n][0] = *(const bf16x8*)&bB[lrow * 64 + slot0];
          breg[n][1] = *(const bf16x8*)&bB[lrow * 64 + slot1];
        }
      }
      if      (Q == 0) stageA(ta, 0);
      else if (Q == 1) stageA(ta, 1);
      else if (Q == 2) stageB(tb, 0);
      else             { stageB(tb, 1); VMCNT(4); }
      __builtin_amdgcn_sched_barrier(0);
      __builtin_amdgcn_s_barrier();
      __builtin_amdgcn_s_setprio(1);
      #pragma unroll
      for (int m2 = 0; m2 < 2; ++m2)
        #pragma unroll
        for (int n = 0; n < 4; ++n) {
          acc[Q * 2 + m2][n] = MFMA16(aph[m2][0], breg[n][0], acc[Q * 2 + m2][n]);
          acc[Q * 2 + m2][n] = MFMA16(aph[m2][1], breg[n][1], acc[Q * 2 + m2][n]);
        }
      __builtin_amdgcn_s_setprio(0);
      __builtin_amdgcn_sched_barrier(0);
      __builtin_amdgcn_s_barrier();
    }
  }
  VMCNT(0);

  // ---- epilogue: D lane l reg r -> row=(l>>4)*4+r, col=l&15 ----
  float* Co = Cp + (long)z * strC;
  #pragma unroll
  for (int m = 0; m < 8; ++m)
    #pragma unroll
    for (int r = 0; r < 4; ++r) {
      const int row = m0 + wm * 128 + m * 16 + hi * 4 + r;
      if (row >= M) continue;
      #pragma unroll
      for (int n = 0; n < 4; ++n) {
        const int col = n0 + wn * 64 + n * 16 + lr;
        if (col < N) Co[(long)row * N + col] = acc[m][n][r];
      }
    }
}

// ---------------------------------------------------------------------------
// 128x128 glds GEMM (logits). Counted-vmcnt, depth-1. OUT=1: bf16 *scale.
// ---------------------------------------------------------------------------
template <int BK, int OUT>
__global__ __launch_bounds__(256) void gemm_glds(
    const u16* __restrict__ A, const u16* __restrict__ B, void* __restrict__ C,
    int M, int N, int Kc, int fullK, int S,
    long strA, long strB, long strC, float scale)
{
  constexpr int CPR = BK / 8;
  constexpr int ISS = BK / 16;
  __shared__ u16 sA[2][128 * BK];
  __shared__ u16 sB[2][128 * BK];
  const int t = threadIdx.x, lane = t & 63, wave = t >> 6;
  const int z = blockIdx.z, zb = z / S, s = z - zb * S;
  const int m0 = blockIdx.x * 128, n0 = blockIdx.y * 128;
  const int kbeg = s * Kc;

  const u16* Aptr[ISS]; const u16* Bptr[ISS]; int lofs[ISS];
  #pragma unroll
  for (int i = 0; i < ISS; ++i) {
    const int tp = i * 256 + t;
    const int r = tp / CPR;
    int c16 = tp % CPR;
    if constexpr (BK == 32) c16 = c16 ^ ((tp >> 4) & 3);
    int ra = m0 + r; if (ra >= M) ra = M - 1;
    int rb = n0 + r; if (rb >= N) rb = N - 1;
    Aptr[i] = A + (long)zb * strA + (long)ra * fullK + kbeg + c16 * 8;
    Bptr[i] = B + (long)zb * strB + (long)rb * fullK + kbeg + c16 * 8;
    lofs[i] = (i * 256 + (wave << 6)) * 8;
  }
  auto stage = [&](int buf, int k0) {
    #pragma unroll
    for (int i = 0; i < ISS; ++i) {
      gld_lds16(Aptr[i] + k0, &sA[buf][lofs[i]]);
      gld_lds16(Bptr[i] + k0, &sB[buf][lofs[i]]);
    }
  };

  const int wr = (wave >> 1) * 64, wc = (wave & 1) * 64;
  const int lr = lane & 15, hi = lane >> 4;
  f32x4v acc[4][4] = {};
  const int niter = Kc / BK;

  stage(0, 0);
  for (int it = 0; it < niter; ++it) {
    const int cur = it & 1;
    if (it + 1 < niter) {
      stage(cur ^ 1, (it + 1) * BK);
      if constexpr (ISS == 2) VMCNT(4); else VMCNT(8);
    } else {
      VMCNT(0);
    }
    __builtin_amdgcn_s_barrier();
    __builtin_amdgcn_sched_barrier(0);
    #pragma unroll
    for (int kk = 0; kk < BK; kk += 32) {
      int lk = kk + hi * 8;
      if constexpr (BK == 32) lk = kk + ((hi ^ (lr >> 2)) * 8);
      bf16x8 af[4], bv[4];
      #pragma unroll
      for (int i = 0; i < 4; ++i) af[i] = *(const bf16x8*)&sA[cur][(wr + i*16 + lr) * BK + lk];
      #pragma unroll
      for (int j = 0; j < 4; ++j) bv[j] = *(const bf16x8*)&sB[cur][(wc + j*16 + lr) * BK + lk];
      __builtin_amdgcn_s_setprio(1);
      #pragma unroll
      for (int i = 0; i < 4; ++i)
        #pragma unroll
        for (int j = 0; j < 4; ++j)
          acc[i][j] = MFMA16(af[i], bv[j], acc[i][j]);
      __builtin_amdgcn_s_setprio(0);
    }
    __builtin_amdgcn_sched_barrier(0);
    __builtin_amdgcn_s_barrier();
  }

  const int lq = hi * 4;
  if constexpr (OUT == 0) {
    float* Cw = (float*)C + (long)z * strC;
    #pragma unroll
    for (int i = 0; i < 4; ++i)
      #pragma unroll
      for (int r = 0; r < 4; ++r) {
        const int row = m0 + wr + i*16 + lq + r;
        if (row >= M) continue;
        #pragma unroll
        for (int j = 0; j < 4; ++j) {
          const int col = n0 + wc + j*16 + lr;
          if (col < N) Cw[(long)row * N + col] = acc[i][j][r];
        }
      }
  } else {
    u16* Cw = (u16*)C + (long)zb * strC;
    #pragma unroll
    for (int i = 0; i < 4; ++i)
      #pragma unroll
      for (int r = 0; r < 4; ++r) {
        const int row = m0 + wr + i*16 + lq + r;
        if (row >= M) continue;
        #pragma unroll
        for (int j = 0; j < 4; ++j) {
          const int col = n0 + wc + j*16 + lr;
          if (col < N) Cw[(long)row * N + col] = f2bf(acc[i][j][r] * scale);
        }
      }
  }
}

// ---------------------------------------------------------------------------
// 128x128 implicit-conv (conv2: M=64). Counted-vmcnt depth-1.
// ---------------------------------------------------------------------------
__global__ __launch_bounds__(256) void conv_glds(
    const u16* __restrict__ Wt, const u16* __restrict__ imgP,
    float* __restrict__ Cp, int M, int Cin, int Ntot, int Kc)
{
  __shared__ u16 sA[2][128 * 32];
  __shared__ u16 sB[2][128 * 32];
  const int t = threadIdx.x, lane = t & 63, wave = t >> 6;
  const int z = blockIdx.z;
  const int m0 = blockIdx.x * 128, n0 = blockIdx.y * 128;
  const int kbeg = z * Kc;

  const u16* Aptr[2]; const u16* Bptr[2]; int lofs[2];
  #pragma unroll
  for (int i = 0; i < 2; ++i) {
    const int tp = i * 256 + t;
    const int r = tp >> 2;
    const int c16 = (tp & 3) ^ ((tp >> 4) & 3);
    int ra = m0 + r; if (ra >= M) ra = M - 1;
    int pn = n0 + r; if (pn >= Ntot) pn = 0;
    const int img = pn / 784, p = pn - img * 784;
    const int py = p / 28, px = p - py * 28;
    Aptr[i] = Wt + (long)ra * (9 * Cin) + c16 * 8;
    Bptr[i] = imgP + ((long)img * 900 + (py + 1) * 30 + (px + 1)) * Cin + c16 * 8;
    lofs[i] = (i * 256 + (wave << 6)) * 8;
  }
  auto stage = [&](int buf, int kg) {
    const int tap = kg / Cin, kc = kg - tap * Cin;
    const long off = (long)((tap / 3 - 1) * 30 + (tap % 3 - 1)) * Cin + kc;
    #pragma unroll
    for (int i = 0; i < 2; ++i) {
      gld_lds16(Aptr[i] + kg, &sA[buf][lofs[i]]);
      gld_lds16(Bptr[i] + off, &sB[buf][lofs[i]]);
    }
  };

  const int wr = (wave >> 1) * 64, wc = (wave & 1) * 64;
  const int lr = lane & 15, hi = lane >> 4;
  const int csw = (hi ^ (lr >> 2)) * 8;
  f32x4v acc[4][4] = {};
  const int niter = Kc >> 5;

  stage(0, kbeg);
  for (int it = 0; it < niter; ++it) {
    const int cur = it & 1;
    if (it + 1 < niter) {
      stage(cur ^ 1, kbeg + (it + 1) * 32);
      VMCNT(4);
    } else {
      VMCNT(0);
    }
    __builtin_amdgcn_s_barrier();
    __builtin_amdgcn_sched_barrier(0);
    bf16x8 af[4], bv[4];
    #pragma unroll
    for (int i = 0; i < 4; ++i) af[i] = *(const bf16x8*)&sA[cur][(wr + i*16 + lr) * 32 + csw];
    #pragma unroll
    for (int j = 0; j < 4; ++j) bv[j] = *(const bf16x8*)&sB[cur][(wc + j*16 + lr) * 32 + csw];
    __builtin_amdgcn_s_setprio(1);
    #pragma unroll
    for (int i = 0; i < 4; ++i)
      #pragma unroll
      for (int j = 0; j < 4; ++j)
        acc[i][j] = MFMA16(af[i], bv[j], acc[i][j]);
    __builtin_amdgcn_s_setprio(0);
    __builtin_amdgcn_sched_barrier(0);
    __builtin_amdgcn_s_barrier();
  }

  float* Co = Cp + (long)z * M * Ntot;
  const int lq = hi * 4;
  #pragma unroll
  for (int i = 0; i < 4; ++i)
    #pragma unroll
    for (int r = 0; r < 4; ++r) {
      const int row = m0 + wr + i*16 + lq + r;
      if (row >= M) continue;
      #pragma unroll
      for (int j = 0; j < 4; ++j) {
        const int col = n0 + wc + j*16 + lr;
        if (col < Ntot) Co[(long)row * Ntot + col] = acc[i][j][r];
      }
    }
}

// ---------------------------------------------------------------------------
// Helpers
// ---------------------------------------------------------------------------
__global__ __launch_bounds__(256) void transpose_bf(
    const float* __restrict__ in, u16* __restrict__ out,
    int R, int C, long strOutZ, int ldOut, int colOff)
{
  __shared__ float tile[32][33];
  in  += (long)blockIdx.z * R * C;
  out += (long)blockIdx.z * strOutZ;
  const int c0 = blockIdx.x * 32, r0 = blockIdx.y * 32;
  const int tx = threadIdx.x & 31, ty = threadIdx.x >> 5;
  for (int i = ty; i < 32; i += 8) {
    const int r = r0 + i, c = c0 + tx;
    tile[i][tx] = (r < R && c < C) ? in[(long)r * C + c] : 0.0f;
  }
  __syncthreads();
  for (int i = ty; i < 32; i += 8) {
    const int r = r0 + tx, c = c0 + i;
    if (c < C && r < R)
      out[(long)c * ldOut + colOff + r] = f2bf(tile[tx][i]);
  }
}

__global__ __launch_bounds__(256) void convert_bf(
    const float* __restrict__ in, u16* __restrict__ out, long n8)
{
  const long i = (long)blockIdx.x * 256 + threadIdx.x;
  if (i >= n8) return;
  const float4* p = (const float4*)in + i * 2;
  const float4 a = p[0], b = p[1];
  u16 o[8] = {f2bf(a.x), f2bf(a.y), f2bf(a.z), f2bf(a.w),
              f2bf(b.x), f2bf(b.y), f2bf(b.z), f2bf(b.w)};
  ((uint4*)out)[i] = *(uint4*)o;
}

__global__ __launch_bounds__(256) void permute_w(
    const float* __restrict__ src, u16* __restrict__ dst, int M, int Cin)
{
  const long total = (long)M * 9 * Cin;
  const long idx = (long)blockIdx.x * 256 + threadIdx.x;
  if (idx >= total) return;
  const int c = (int)(idx % Cin);
  const int tap = (int)((idx / Cin) % 9);
  const int m = (int)(idx / ((long)9 * Cin));
  dst[idx] = f2bf(src[((long)m * Cin + c) * 9 + tap]);
}

__global__ __launch_bounds__(256) void zfill(u32* __restrict__ p, long n) {
  const long stride = (long)gridDim.x * 256;
  for (long i = (long)blockIdx.x * 256 + threadIdx.x; i < n; i += stride) p[i] = 0;
}

// ---------------------------------------------------------------------------
// Reduce kernels
// ---------------------------------------------------------------------------
// conv1: parts[S][1568][512] (pixel-major) -> out1P[b][900pad][512] bf16 +b1
__global__ __launch_bounds__(256) void reduce_c1_cl(
    const float* __restrict__ parts, u16* __restrict__ dst,
    const float* __restrict__ bias, int S)
{
  const long idx = (long)blockIdx.x * 256 + threadIdx.x;
  if (idx >= 1568L * 128) return;
  const int c4 = (int)(idx & 127), p = (int)(idx >> 7);
  const int c = c4 * 4;
  f32x4v sum = *(const f32x4v*)&bias[c];
  for (int s = 0; s < S; ++s)
    sum += *(const f32x4v*)&parts[((long)s * 1568 + p) * 512 + c];
  const int im = p / 784, q = p - im * 784;
  const int qpad = (q / 28 + 1) * 30 + (q % 28 + 1);
  u16 o[4] = {f2bf(sum[0]), f2bf(sum[1]), f2bf(sum[2]), f2bf(sum[3])};
  *(uint2*)&dst[((long)im * 900 + qpad) * 512 + c] = *(uint2*)o;
}

// readout: parts[(b*S+s)][1536][784] (channel-major) -> concatP[b*3+n][900pad][768]
__global__ __launch_bounds__(256) void reduceT_ro(
    const float* __restrict__ parts, u16* __restrict__ dst, int S)
{
  __shared__ float tile[32][33];
  const int b = blockIdx.z, c0 = blockIdx.x * 32, p0 = blockIdx.y * 32;
  const int tx = threadIdx.x & 31, ty = threadIdx.x >> 5;
  for (int i = ty; i < 32; i += 8) {
    const int pc = min(p0 + tx, 783);
    float s = 0;
    for (int k = 0; k < S; ++k)
      s += parts[((long)(b * S + k) * 1536 + c0 + i) * 784 + pc];
    tile[i][tx] = s;
  }
  __syncthreads();
  for (int i = ty; i < 32; i += 8) {
    const int p = p0 + i, c = c0 + tx;
    if (p < 784) {
      const int n = c >> 9, cc = c & 511;
      const int qpad = (p / 28 + 1) * 30 + (p % 28 + 1);
      dst[((long)(b * 3 + n) * 900 + qpad) * 768 + cc] = f2bf(tile[tx][i]);
    }
  }
}

// conv2: parts[S][64][1568] -> qkT[b][784][64] (+b2)
__global__ __launch_bounds__(256) void reduceT_qk(
    const float* __restrict__ parts, u16* __restrict__ dst,
    const float* __restrict__ bias, int S)
{
  __shared__ float tile[32][33];
  const int b = blockIdx.z, c0 = blockIdx.x * 32, p0 = blockIdx.y * 32;
  const int tx = threadIdx.x & 31, ty = threadIdx.x >> 5;
  for (int i = ty; i < 32; i += 8) {
    const int pc = min(p0 + tx, 783);
    const long base = (long)(c0 + i) * 1568 + b * 784 + pc;
    float s = 0;
    for (int k = 0; k < S; ++k) s += parts[(long)k * 64 * 1568 + base];
    tile[i][tx] = s;
  }
  __syncthreads();
  for (int i = ty; i < 32; i += 8) {
    const int p = p0 + i, c = c0 + tx;
    if (p < 784)
      dst[((long)b * 784 + p) * 64 + c] = f2bf(tile[tx][i] + bias[c]);
  }
}

__global__ __launch_bounds__(256) void transT_h(
    const float* __restrict__ h, u16* __restrict__ dst)
{
  __shared__ float tile[32][33];
  const int zimg = blockIdx.z, c0 = blockIdx.x * 32, p0 = blockIdx.y * 32;
  const int tx = threadIdx.x & 31, ty = threadIdx.x >> 5;
  for (int i = ty; i < 32; i += 8) {
    const int pc = min(p0 + tx, 783);
    tile[i][tx] = h[((long)zimg * 256 + c0 + i) * 784 + pc];
  }
  __syncthreads();
  for (int i = ty; i < 32; i += 8) {
    const int p = p0 + i, c = c0 + tx;
    if (p < 784) {
      const int qpad = (p / 28 + 1) * 30 + (p % 28 + 1);
      dst[((long)zimg * 900 + qpad) * 768 + 512 + c] = f2bf(tile[tx][i]);
    }
  }
}

// ---------------------------------------------------------------------------
// SINGLE-PASS in-place softmax over rows of 12544 bf16 (one block per row)
// ---------------------------------------------------------------------------
__global__ __launch_bounds__(256) void softmax_inplace(u16* __restrict__ buf)
{
  uint4* p4 = (uint4*)(buf + (long)blockIdx.x * 12544);
  const int t = threadIdx.x;
  __shared__ float red[4];
  uint4 v[7];
  float mx = -3.0e38f;
  #pragma unroll
  for (int q = 0; q < 7; ++q) {
    const int idx = t + q * 256;
    if (idx < 1568) {
      v[q] = p4[idx];
      const u32 w[4] = {v[q].x, v[q].y, v[q].z, v[q].w};
      #pragma unroll
      for (int e = 0; e < 4; ++e) {
        mx = fmaxf(mx, bf2f((u16)(w[e] & 0xFFFFu)));
        mx = fmaxf(mx, bf2f((u16)(w[e] >> 16)));
      }
    }
  }
  #pragma unroll
  for (int o = 32; o > 0; o >>= 1) mx = fmaxf(mx, __shfl_xor(mx, o));
  if ((t & 63) == 0) red[t >> 6] = mx;
  __syncthreads();
  mx = fmaxf(fmaxf(red[0], red[1]), fmaxf(red[2], red[3]));

  float s = 0.0f;
  #pragma unroll
  for (int q = 0; q < 7; ++q) {
    const int idx = t + q * 256;
    if (idx < 1568) {
      const u32 w[4] = {v[q].x, v[q].y, v[q].z, v[q].w};
      #pragma unroll
      for (int e = 0; e < 4; ++e) {
        s += __expf(bf2f((u16)(w[e] & 0xFFFFu)) - mx);
        s += __expf(bf2f((u16)(w[e] >> 16)) - mx);
      }
    }
  }
  #pragma unroll
  for (int o = 32; o > 0; o >>= 1) s += __shfl_xor(s, o);
  __syncthreads();
  if ((t & 63) == 0) red[t >> 6] = s;
  __syncthreads();
  const float inv = 1.0f / (red[0] + red[1] + red[2] + red[3]);

  #pragma unroll
  for (int q = 0; q < 7; ++q) {
    const int idx = t + q * 256;
    if (idx < 1568) {
      u32 w[4] = {v[q].x, v[q].y, v[q].z, v[q].w};
      #pragma unroll
      for (int e = 0; e < 4; ++e) {
        const float a = __expf(bf2f((u16)(w[e] & 0xFFFFu)) - mx) * inv;
        const float b = __expf(bf2f((u16)(w[e] >> 16)) - mx) * inv;
        w[e] = (u32)f2bf(a) | ((u32)f2bf(b) << 16);
      }
      p4[idx] = make_uint4(w[0], w[1], w[2], w[3]);
    }
  }
}

// ---------------------------------------------------------------------------
// Fused transform-reduce + gating. parts: [S][768][4704] fp32 (channel-major)
// ---------------------------------------------------------------------------
__global__ __launch_bounds__(256) void treduce_gate(
    const float* __restrict__ parts, const float* __restrict__ bt,
    const float* __restrict__ h, float* __restrict__ out, int S)
{
  const long i = (long)blockIdx.x * 256 + threadIdx.x;
  if (i >= 6L * 256 * 196) return;
  const int p4 = (int)(i % 196);
  const int rest = (int)(i / 196);
  const int cs = rest % 256, im = rest / 256;
  const long slice4 = (768L * 4704) >> 2;
  const long colBase = ((long)im * 784) >> 2;
  f32x4v F = {0,0,0,0}, U = {0,0,0,0}, NV = {0,0,0,0};
  for (int s = 0; s < S; ++s) {
    const f32x4v* P = (const f32x4v*)parts + (long)s * slice4;
    F  += P[(((long)cs        * 4704) >> 2) + colBase + p4];
    U  += P[(((long)(256 + cs) * 4704) >> 2) + colBase + p4];
    NV += P[(((long)(512 + cs) * 4704) >> 2) + colBase + p4];
  }
  const float bF = bt[cs], bU = bt[256 + cs], bN = bt[512 + cs];
  const f32x4v hv = ((const f32x4v*)h)[((long)(im * 256 + cs) * 784 >> 2) + p4];
  f32x4v o;
  #pragma unroll
  for (int q = 0; q < 4; ++q) {
    const float f = F[q] + bF, u = U[q] + bU, nv = NV[q] + bN;
    const float sf = 1.0f / (1.0f + __expf(-f));
    const float su = 1.0f / (1.0f + __expf(-u));
    const float e2 = __expf(2.0f * nv);
    const float tv = (e2 - 1.0f) / (e2 + 1.0f);
    o[q] = sf * hv[q] * (1.0f - su) + su * tv;
  }
  ((f32x4v*)out)[((long)(im * 256 + cs) * 784 >> 2) + p4] = o;
}

__global__ __launch_bounds__(256) void fill_sentinel(float* p, long n) {
  const long i = (long)blockIdx.x * 256 + threadIdx.x;
  if (i < n) p[i] = 12345.0f;
}

// ---------------------------------------------------------------------------
extern "C" void kernel_launch(void* const* d_in, const int* in_sizes, int n_in,
                              void* d_out, int out_size, void* d_ws, size_t ws_size,
                              hipStream_t stream) {
  const float* f16 = (const float*)d_in[0];
  const float* mk  = (const float*)d_in[1];
  const float* mv  = (const float*)d_in[2];
  const float* hin = (const float*)d_in[3];
  const float* w1  = (const float*)d_in[4];
  const float* b1  = (const float*)d_in[5];
  const float* w2  = (const float*)d_in[6];
  const float* b2  = (const float*)d_in[7];
  const float* wt  = (const float*)d_in[8];
  const float* bt  = (const float*)d_in[9];
  float* out = (float*)d_out;

  (void)hipFuncSetAttribute((const void*)gemm8p<0>,
                            hipFuncAttributeMaxDynamicSharedMemorySize, 131072);
  (void)hipFuncSetAttribute((const void*)gemm8p<1>,
                            hipFuncAttributeMaxDynamicSharedMemorySize, 131072);
  constexpr unsigned DSM = 131072;

  const size_t B_f16T   = 2UL*784*1024*2;
  const size_t B_w1b    = 512UL*1024*2;
  const size_t B_w2R    = 64UL*4608*2;
  const size_t B_out1P  = 2UL*900*512*2;
  const size_t B_qkT    = 2UL*784*64*2;
  const size_t B_concat = 6UL*900*768*2;
  const size_t B_wtR    = 768UL*6912*2;
  const size_t B_mkT    = 2UL*12544*64*2;
  const size_t B_logaff = 2UL*784*12544*2;
  const size_t B_mvb    = 38535168UL*2;
  auto al = [](size_t x) { return (x + 255) & ~(size_t)255; };
  auto pad8 = [](int n) { return (n + 7) & ~7; };

  const size_t phase1 = al(B_f16T) + al(B_w1b) + al(B_w2R) + al(B_out1P) + al(B_qkT);
  const size_t regionA = phase1 > al(B_concat) ? phase1 : al(B_concat);

  const int S_tr = 4;                     // Kc 1728 = 27 K-tiles, grid 228
  auto poolFor = [&](int S_ro) -> size_t {
    size_t p1 = 8UL*1568*512*4, p2 = 18UL*64*1568*4;
    size_t pr = (size_t)(2*S_ro)*1536*784*4, pt = (size_t)S_tr*768*4704*4;
    size_t m = p1; if (p2 > m) m = p2; if (pr > m) m = pr; if (pt > m) m = pt;
    return m;
  };
  const size_t fixed = regionA + al(B_wtR) + al(B_mkT) + al(B_logaff) + al(B_mvb);

  int S_ro = 14;                          // Kc 896 = 14 tiles; grid 672
  if (fixed + poolFor(S_ro) > ws_size) S_ro = 4;   // Kc 3136 = 49 tiles; grid 192
  if (fixed + poolFor(S_ro) > ws_size) {
    fill_sentinel<<<4704, 256, 0, stream>>>(out, (long)out_size);
    return;
  }
  const int Kc_ro = 12544 / S_ro;
  const int Kc_tr = 6912 / S_tr;

  char* base = (char*)d_ws;
  size_t off = 0;
  auto alloc = [&](size_t bytes) -> char* { char* p = base + off; off += al(bytes); return p; };
  char* rA = alloc(regionA);
  u16* f16T   = (u16*)rA;
  u16* w1b    = (u16*)(rA + al(B_f16T));
  u16* w2R    = (u16*)(rA + al(B_f16T) + al(B_w1b));
  u16* out1P  = (u16*)(rA + al(B_f16T) + al(B_w1b) + al(B_w2R));
  u16* qkT    = (u16*)(rA + al(B_f16T) + al(B_w1b) + al(B_w2R) + al(B_out1P));
  u16* concatP = (u16*)rA;   // overlays phase-1 buffers (dead by then)
  u16*   wtR    = (u16*)alloc(B_wtR);
  u16*   mkT    = (u16*)alloc(B_mkT);
  u16*   logaff = (u16*)alloc(B_logaff);
  u16*   mvb    = (u16*)alloc(B_mvb);
  float* parts  = (float*)alloc(poolFor(S_ro));

  // ---- zero padded conv1 image ----
  zfill<<<512, 256, 0, stream>>>((u32*)out1P, (long)(B_out1P / 4));

  // ---- operand prep ----
  convert_bf<<<256, 256, 0, stream>>>(w1, w1b, 65536);
  permute_w<<<1152, 256, 0, stream>>>(w2, w2R, 64, 512);
  permute_w<<<20736, 256, 0, stream>>>(wt, wtR, 768, 768);
  transpose_bf<<<dim3(25, 32, 2), 256, 0, stream>>>(f16, f16T, 1024, 784, 784L*1024, 1024, 0);
  transpose_bf<<<dim3(392, 2, 2), 256, 0, stream>>>(mk, mkT, 64, 12544, 12544L*64, 64, 0);
  convert_bf<<<18816, 256, 0, stream>>>(mv, mvb, 4816896);

  // ---- conv1 (1x1): A=f16T[1568][1024], B=w1b[512][1024], S=8 ----
  {
    const int nwg = 7 * 2 * 8;   // gx=7 (M=1568), gy=2 (N=512), z=8
    gemm8p<0><<<pad8(nwg), 512, DSM, stream>>>(
        f16T, w1b, parts, 1568, 512, 128, 1024, 8, 0, 0, 1568L*512, 0, 7, 2, nwg);
  }
  reduce_c1_cl<<<784, 256, 0, stream>>>(parts, out1P, b1, 8);

  // ---- conv2 (3x3 implicit 128-tile): M=64, Cin=512, Ntot=1568, S=18 ----
  conv_glds<<<dim3(1, 13, 18), 256, 0, stream>>>(w2R, out1P, parts, 64, 512, 1568, 256);
  reduceT_qk<<<dim3(2, 25, 2), 256, 0, stream>>>(parts, qkT, b2, 18);

  // ---- logits: M=784, N=12544, K=64 -> bf16, scale 1/8 ----
  gemm_glds<64, 1><<<dim3(7, 98, 2), 256, 0, stream>>>(
      qkT, mkT, logaff, 784, 12544, 64, 64, 1,
      784L*64, 12544L*64, 784L*12544, 0.125f);

  // ---- softmax over memory axis ----
  softmax_inplace<<<1568, 256, 0, stream>>>(logaff);

  // ---- zero concat image, fill h channels ----
  zfill<<<2048, 256, 0, stream>>>((u32*)concatP, (long)(B_concat / 4));
  transT_h<<<dim3(8, 25, 6), 256, 0, stream>>>(hin, concatP);

  // ---- readout: A=mvb[1536][12544], B=logaff[784][12544] ----
  {
    const int nwg = 6 * 4 * 2 * S_ro;   // gx=6 (M), gy=4 (N=784->1024), z=2*S
    gemm8p<0><<<pad8(nwg), 512, DSM, stream>>>(
        mvb, logaff, parts, 1536, 784, Kc_ro, 12544, S_ro,
        1536L*12544, 784L*12544, 1536L*784, 0, 6, 4, nwg);
  }
  reduceT_ro<<<dim3(48, 25, 2), 256, 0, stream>>>(parts, concatP, S_ro);

  // ---- transform conv: A=wtR[768][6912], B=concatP pixels ----
  {
    const int nwg = 3 * 19 * S_tr;      // gx=3 (M=768), gy=19 (N=4704->4864)
    gemm8p<1><<<pad8(nwg), 512, DSM, stream>>>(
        wtR, concatP, parts, 768, 4704, Kc_tr, 6912, S_tr,
        0, 0, 768L*4704, 768, 3, 19, nwg);
  }

  // ---- fused reduce + gating -> d_out ----
  treduce_gate<<<1176, 256, 0, stream>>>(parts, bt, hin, out, S_tr);
}

// Round 10
// 356.226 us; speedup vs baseline: 1.1188x; 1.1188x over previous
//
#include <hip/hip_runtime.h>

typedef unsigned short u16;
typedef unsigned int u32;
typedef float f32x4v __attribute__((ext_vector_type(4)));
typedef __bf16 bf16x8 __attribute__((ext_vector_type(8)));

#define GAS __attribute__((address_space(1)))
#define LAS __attribute__((address_space(3)))

__device__ __forceinline__ u16 f2bf(float f) {
  u32 u = __builtin_bit_cast(u32, f);
  u32 r = (u + 0x7FFFu + ((u >> 16) & 1u)) >> 16;  // RNE
  return (u16)r;
}
__device__ __forceinline__ float bf2f(u16 h) {
  return __builtin_bit_cast(float, (u32)h << 16);
}
__device__ __forceinline__ void gld_lds16(const void* g, void* l) {
  __builtin_amdgcn_global_load_lds((const GAS void*)g, (LAS void*)l, 16, 0, 0);
}
#define VMCNT(N) asm volatile("s_waitcnt vmcnt(" #N ")" ::: "memory")
#define MFMA16(a, b, c) __builtin_amdgcn_mfma_f32_16x16x32_bf16((a), (b), (c), 0, 0, 0)

// ---------------------------------------------------------------------------
// 256x128 MFMA GEMM, BK=32, 512 thr / 8 waves, depth-3 circular pipeline
// (72 KB dynamic LDS, 2 blocks/CU), counted vmcnt(6).
// 1D grid + XCD-chunked remap (y fastest -> A-tile sharers on one XCD).
// Partials written as BF16 (fp32 accum internally): Cp + z*strC, u16.
// CONV=1: B rows are pixels of zero-padded channel-last stack [nImg][900][Cin].
// ---------------------------------------------------------------------------
template <int CONV>
__global__ __launch_bounds__(512, 4) void gemmRC(
    const u16* __restrict__ A, const u16* __restrict__ B, u16* __restrict__ Cp,
    int M, int N, int Kc, int fullK, int S,
    long strA, long strB, long strC, int Cin, int gx, int gy, int nwg)
{
  const int cpx = (int)gridDim.x >> 3;
  const int L = ((int)blockIdx.x & 7) * cpx + ((int)blockIdx.x >> 3);
  if (L >= nwg) return;
  const int by = L % gy;
  const int rest = L / gy;
  const int bx = rest % gx;
  const int z = rest / gx;

  extern __shared__ u16 smem[];       // A: 3 bufs x 8192 u16, B: 3 x 4096 u16
  u16* sA = smem;
  u16* sB = smem + 3 * 8192;
  const int t = threadIdx.x, lane = t & 63, wave = t >> 6;
  const int zb = z / S, s = z - zb * S;
  const int m0 = bx * 256, n0 = by * 128;
  const int kbeg = s * Kc;
  const int kavail = fullK - kbeg;
  const int kc = Kc < kavail ? Kc : kavail;
  const int niter = kc >> 5;

  const int schunk = ((t & 3) ^ ((t >> 4) & 3)) * 8;
  const u16* Ap[2]; const u16* Bp;
  #pragma unroll
  for (int q = 0; q < 2; ++q) {
    int ra = m0 + q * 128 + (t >> 2); if (ra >= M) ra = M - 1;
    Ap[q] = A + (long)zb * strA + (long)ra * fullK + schunk;
  }
  if constexpr (CONV) {
    int pn = n0 + (t >> 2); if (pn >= N) pn = 0;
    const int img = pn / 784, p = pn - img * 784;
    const int py = p / 28, px = p - py * 28;
    Bp = B + ((long)img * 900 + (py + 1) * 30 + (px + 1)) * Cin + schunk;
  } else {
    int rb = n0 + (t >> 2); if (rb >= N) rb = N - 1;
    Bp = B + (long)zb * strB + (long)rb * fullK + schunk;
  }
  const int ldst = t * 8;

  auto stage = [&](int buf, int kg) {
    long boff;
    if constexpr (CONV) {
      const int tap = kg / Cin, kcc = kg - tap * Cin;
      boff = (long)((tap / 3 - 1) * 30 + (tap % 3 - 1)) * Cin + kcc;
    } else {
      boff = kg;
    }
    u16* dA = sA + buf * 8192;
    gld_lds16(Ap[0] + kg, &dA[ldst]);
    gld_lds16(Ap[1] + kg, &dA[4096 + ldst]);
    gld_lds16(Bp + boff,  &sB[buf * 4096 + ldst]);
  };

  const int wrow = (wave & 3) * 64, wcol = (wave >> 2) * 64;
  const int lr = lane & 15, hi = lane >> 4;
  const int csw = (hi ^ (lr >> 2)) * 8;
  f32x4v acc[4][4] = {};

  for (int p = 0; p < 2 && p < niter; ++p) stage(p, kbeg + p * 32);
  int cur = 0, nxt = 2;
  for (int it = 0; it < niter; ++it) {
    if (it + 2 < niter) {
      stage(nxt, kbeg + (it + 2) * 32);
      VMCNT(6);
    } else {
      const int rem = niter - 1 - it;
      if (rem == 1) VMCNT(3); else VMCNT(0);
    }
    __builtin_amdgcn_s_barrier();
    __builtin_amdgcn_sched_barrier(0);
    const u16* cA = sA + cur * 8192;
    const u16* cB = sB + cur * 4096;
    bf16x8 af[4], bf[4];
    #pragma unroll
    for (int m = 0; m < 4; ++m) af[m] = *(const bf16x8*)&cA[(wrow + m*16 + lr) * 32 + csw];
    #pragma unroll
    for (int n = 0; n < 4; ++n) bf[n] = *(const bf16x8*)&cB[(wcol + n*16 + lr) * 32 + csw];
    __builtin_amdgcn_s_setprio(1);
    #pragma unroll
    for (int m = 0; m < 4; ++m)
      #pragma unroll
      for (int n = 0; n < 4; ++n)
        acc[m][n] = MFMA16(af[m], bf[n], acc[m][n]);
    __builtin_amdgcn_s_setprio(0);
    __builtin_amdgcn_sched_barrier(0);
    __builtin_amdgcn_s_barrier();
    cur = (cur + 1 == 3) ? 0 : cur + 1;
    nxt = (nxt + 1 == 3) ? 0 : nxt + 1;
  }

  // D: lane l reg r -> row=(l>>4)*4+r, col=l&15; bf16 partial out
  u16* Co = Cp + (long)z * strC;
  const int lq = hi * 4;
  #pragma unroll
  for (int m = 0; m < 4; ++m)
    #pragma unroll
    for (int r = 0; r < 4; ++r) {
      const int row = m0 + wrow + m * 16 + lq + r;
      if (row >= M) continue;
      #pragma unroll
      for (int n = 0; n < 4; ++n) {
        const int col = n0 + wcol + n * 16 + lr;
        if (col < N) Co[(long)row * N + col] = f2bf(acc[m][n][r]);
      }
    }
}

// ---------------------------------------------------------------------------
// 128x128 glds GEMM. Counted-vmcnt depth-1. Chunk-rotation LDS swizzle (BK=64).
// OUT=1: bf16 final C[row][col] *scale.
// OUT=2: conv1 epilogue — bf16 to padded channel-last out1P with +bias:
//        row = global pixel (im*784+q), col = channel; dst[(im*900+qpad)*512+col].
// ---------------------------------------------------------------------------
template <int BK, int OUT>
__global__ __launch_bounds__(256) void gemm_glds(
    const u16* __restrict__ A, const u16* __restrict__ B, void* __restrict__ C,
    const float* __restrict__ bias,
    int M, int N, int Kc, int fullK, int S,
    long strA, long strB, long strC, float scale)
{
  constexpr int CPR = BK / 8;
  constexpr int ISS = BK / 16;
  __shared__ u16 sA[2][128 * BK];
  __shared__ u16 sB[2][128 * BK];
  const int t = threadIdx.x, lane = t & 63, wave = t >> 6;
  const int z = blockIdx.z, zb = z / S, s = z - zb * S;
  const int m0 = blockIdx.x * 128, n0 = blockIdx.y * 128;
  const int kbeg = s * Kc;

  const u16* Aptr[ISS]; const u16* Bptr[ISS]; int lofs[ISS];
  #pragma unroll
  for (int i = 0; i < ISS; ++i) {
    const int tp = i * 256 + t;
    const int r = tp / CPR;
    int c16 = tp % CPR;
    if constexpr (BK == 32) c16 = c16 ^ ((tp >> 4) & 3);
    else                    c16 = (c16 - (r & 7)) & 7;      // rotation (8 chunks)
    int ra = m0 + r; if (ra >= M) ra = M - 1;
    int rb = n0 + r; if (rb >= N) rb = N - 1;
    Aptr[i] = A + (long)zb * strA + (long)ra * fullK + kbeg + c16 * 8;
    Bptr[i] = B + (long)zb * strB + (long)rb * fullK + kbeg + c16 * 8;
    lofs[i] = (i * 256 + (wave << 6)) * 8;
  }
  auto stage = [&](int buf, int k0) {
    #pragma unroll
    for (int i = 0; i < ISS; ++i) {
      gld_lds16(Aptr[i] + k0, &sA[buf][lofs[i]]);
      gld_lds16(Bptr[i] + k0, &sB[buf][lofs[i]]);
    }
  };

  const int wr = (wave >> 1) * 64, wc = (wave & 1) * 64;
  const int lr = lane & 15, hi = lane >> 4;
  f32x4v acc[4][4] = {};
  const int niter = Kc / BK;

  stage(0, 0);
  for (int it = 0; it < niter; ++it) {
    const int cur = it & 1;
    if (it + 1 < niter) {
      stage(cur ^ 1, (it + 1) * BK);
      if constexpr (ISS == 2) VMCNT(4); else VMCNT(8);
    } else {
      VMCNT(0);
    }
    __builtin_amdgcn_s_barrier();
    __builtin_amdgcn_sched_barrier(0);
    #pragma unroll
    for (int kk = 0; kk < BK; kk += 32) {
      bf16x8 af[4], bv[4];
      #pragma unroll
      for (int i = 0; i < 4; ++i) {
        const int row = wr + i*16 + lr;
        int lk;
        if constexpr (BK == 32) lk = kk + ((hi ^ (lr >> 2)) * 8);
        else                    lk = ((((kk >> 3) + hi) + (row & 7)) & 7) * 8;
        af[i] = *(const bf16x8*)&sA[cur][row * BK + lk];
      }
      #pragma unroll
      for (int j = 0; j < 4; ++j) {
        const int row = wc + j*16 + lr;
        int lk;
        if constexpr (BK == 32) lk = kk + ((hi ^ (lr >> 2)) * 8);
        else                    lk = ((((kk >> 3) + hi) + (row & 7)) & 7) * 8;
        bv[j] = *(const bf16x8*)&sB[cur][row * BK + lk];
      }
      __builtin_amdgcn_s_setprio(1);
      #pragma unroll
      for (int i = 0; i < 4; ++i)
        #pragma unroll
        for (int j = 0; j < 4; ++j)
          acc[i][j] = MFMA16(af[i], bv[j], acc[i][j]);
      __builtin_amdgcn_s_setprio(0);
    }
    __builtin_amdgcn_sched_barrier(0);
    __builtin_amdgcn_s_barrier();
  }

  const int lq = hi * 4;
  if constexpr (OUT == 1) {
    u16* Cw = (u16*)C + (long)zb * strC;
    #pragma unroll
    for (int i = 0; i < 4; ++i)
      #pragma unroll
      for (int r = 0; r < 4; ++r) {
        const int row = m0 + wr + i*16 + lq + r;
        if (row >= M) continue;
        #pragma unroll
        for (int j = 0; j < 4; ++j) {
          const int col = n0 + wc + j*16 + lr;
          if (col < N) Cw[(long)row * N + col] = f2bf(acc[i][j][r] * scale);
        }
      }
  } else {   // OUT == 2: conv1 padded channel-last + bias
    u16* Cw = (u16*)C;
    #pragma unroll
    for (int i = 0; i < 4; ++i)
      #pragma unroll
      for (int r = 0; r < 4; ++r) {
        const int row = m0 + wr + i*16 + lq + r;
        if (row >= M) continue;
        const int im = row / 784, q = row - im * 784;
        const int qpad = (q / 28 + 1) * 30 + (q % 28 + 1);
        u16* drow = Cw + ((long)im * 900 + qpad) * 512;
        #pragma unroll
        for (int j = 0; j < 4; ++j) {
          const int col = n0 + wc + j*16 + lr;
          if (col < N) drow[col] = f2bf(acc[i][j][r] + bias[col]);
        }
      }
  }
}

// ---------------------------------------------------------------------------
// 128x128 implicit-conv (conv2: M=64). Counted-vmcnt depth-1. fp32 partials.
// ---------------------------------------------------------------------------
__global__ __launch_bounds__(256) void conv_glds(
    const u16* __restrict__ Wt, const u16* __restrict__ imgP,
    float* __restrict__ Cp, int M, int Cin, int Ntot, int Kc)
{
  __shared__ u16 sA[2][128 * 32];
  __shared__ u16 sB[2][128 * 32];
  const int t = threadIdx.x, lane = t & 63, wave = t >> 6;
  const int z = blockIdx.z;
  const int m0 = blockIdx.x * 128, n0 = blockIdx.y * 128;
  const int kbeg = z * Kc;

  const u16* Aptr[2]; const u16* Bptr[2]; int lofs[2];
  #pragma unroll
  for (int i = 0; i < 2; ++i) {
    const int tp = i * 256 + t;
    const int r = tp >> 2;
    const int c16 = (tp & 3) ^ ((tp >> 4) & 3);
    int ra = m0 + r; if (ra >= M) ra = M - 1;
    int pn = n0 + r; if (pn >= Ntot) pn = 0;
    const int img = pn / 784, p = pn - img * 784;
    const int py = p / 28, px = p - py * 28;
    Aptr[i] = Wt + (long)ra * (9 * Cin) + c16 * 8;
    Bptr[i] = imgP + ((long)img * 900 + (py + 1) * 30 + (px + 1)) * Cin + c16 * 8;
    lofs[i] = (i * 256 + (wave << 6)) * 8;
  }
  auto stage = [&](int buf, int kg) {
    const int tap = kg / Cin, kc = kg - tap * Cin;
    const long off = (long)((tap / 3 - 1) * 30 + (tap % 3 - 1)) * Cin + kc;
    #pragma unroll
    for (int i = 0; i < 2; ++i) {
      gld_lds16(Aptr[i] + kg, &sA[buf][lofs[i]]);
      gld_lds16(Bptr[i] + off, &sB[buf][lofs[i]]);
    }
  };

  const int wr = (wave >> 1) * 64, wc = (wave & 1) * 64;
  const int lr = lane & 15, hi = lane >> 4;
  const int csw = (hi ^ (lr >> 2)) * 8;
  f32x4v acc[4][4] = {};
  const int niter = Kc >> 5;

  stage(0, kbeg);
  for (int it = 0; it < niter; ++it) {
    const int cur = it & 1;
    if (it + 1 < niter) {
      stage(cur ^ 1, kbeg + (it + 1) * 32);
      VMCNT(4);
    } else {
      VMCNT(0);
    }
    __builtin_amdgcn_s_barrier();
    __builtin_amdgcn_sched_barrier(0);
    bf16x8 af[4], bv[4];
    #pragma unroll
    for (int i = 0; i < 4; ++i) af[i] = *(const bf16x8*)&sA[cur][(wr + i*16 + lr) * 32 + csw];
    #pragma unroll
    for (int j = 0; j < 4; ++j) bv[j] = *(const bf16x8*)&sB[cur][(wc + j*16 + lr) * 32 + csw];
    __builtin_amdgcn_s_setprio(1);
    #pragma unroll
    for (int i = 0; i < 4; ++i)
      #pragma unroll
      for (int j = 0; j < 4; ++j)
        acc[i][j] = MFMA16(af[i], bv[j], acc[i][j]);
    __builtin_amdgcn_s_setprio(0);
    __builtin_amdgcn_sched_barrier(0);
    __builtin_amdgcn_s_barrier();
  }

  float* Co = Cp + (long)z * M * Ntot;
  const int lq = hi * 4;
  #pragma unroll
  for (int i = 0; i < 4; ++i)
    #pragma unroll
    for (int r = 0; r < 4; ++r) {
      const int row = m0 + wr + i*16 + lq + r;
      if (row >= M) continue;
      #pragma unroll
      for (int j = 0; j < 4; ++j) {
        const int col = n0 + wc + j*16 + lr;
        if (col < Ntot) Co[(long)row * Ntot + col] = acc[i][j][r];
      }
    }
}

// ---------------------------------------------------------------------------
// Helpers
// ---------------------------------------------------------------------------
__global__ __launch_bounds__(256) void transpose_bf(
    const float* __restrict__ in, u16* __restrict__ out,
    int R, int C, long strOutZ, int ldOut, int colOff)
{
  __shared__ float tile[32][33];
  in  += (long)blockIdx.z * R * C;
  out += (long)blockIdx.z * strOutZ;
  const int c0 = blockIdx.x * 32, r0 = blockIdx.y * 32;
  const int tx = threadIdx.x & 31, ty = threadIdx.x >> 5;
  for (int i = ty; i < 32; i += 8) {
    const int r = r0 + i, c = c0 + tx;
    tile[i][tx] = (r < R && c < C) ? in[(long)r * C + c] : 0.0f;
  }
  __syncthreads();
  for (int i = ty; i < 32; i += 8) {
    const int r = r0 + tx, c = c0 + i;
    if (c < C && r < R)
      out[(long)c * ldOut + colOff + r] = f2bf(tile[tx][i]);
  }
}

__global__ __launch_bounds__(256) void convert_bf(
    const float* __restrict__ in, u16* __restrict__ out, long n8)
{
  const long i = (long)blockIdx.x * 256 + threadIdx.x;
  if (i >= n8) return;
  const float4* p = (const float4*)in + i * 2;
  const float4 a = p[0], b = p[1];
  u16 o[8] = {f2bf(a.x), f2bf(a.y), f2bf(a.z), f2bf(a.w),
              f2bf(b.x), f2bf(b.y), f2bf(b.z), f2bf(b.w)};
  ((uint4*)out)[i] = *(uint4*)o;
}

__global__ __launch_bounds__(256) void permute_w(
    const float* __restrict__ src, u16* __restrict__ dst, int M, int Cin)
{
  const long total = (long)M * 9 * Cin;
  const long idx = (long)blockIdx.x * 256 + threadIdx.x;
  if (idx >= total) return;
  const int c = (int)(idx % Cin);
  const int tap = (int)((idx / Cin) % 9);
  const int m = (int)(idx / ((long)9 * Cin));
  dst[idx] = f2bf(src[((long)m * Cin + c) * 9 + tap]);
}

__global__ __launch_bounds__(256) void zfill(u32* __restrict__ p, long n) {
  const long stride = (long)gridDim.x * 256;
  for (long i = (long)blockIdx.x * 256 + threadIdx.x; i < n; i += stride) p[i] = 0;
}

// ---------------------------------------------------------------------------
// Reduce kernels
// ---------------------------------------------------------------------------
// readout: bf16 parts[(b*S+s)][1536][784] -> concatP[b*3+n][900pad][768]
__global__ __launch_bounds__(256) void reduceT_ro(
    const u16* __restrict__ parts, u16* __restrict__ dst, int S)
{
  __shared__ float tile[32][33];
  const int b = blockIdx.z, c0 = blockIdx.x * 32, p0 = blockIdx.y * 32;
  const int tx = threadIdx.x & 31, ty = threadIdx.x >> 5;
  for (int i = ty; i < 32; i += 8) {
    const int pc = min(p0 + tx, 783);
    float s = 0;
    for (int k = 0; k < S; ++k)
      s += bf2f(parts[((long)(b * S + k) * 1536 + c0 + i) * 784 + pc]);
    tile[i][tx] = s;
  }
  __syncthreads();
  for (int i = ty; i < 32; i += 8) {
    const int p = p0 + i, c = c0 + tx;
    if (p < 784) {
      const int n = c >> 9, cc = c & 511;
      const int qpad = (p / 28 + 1) * 30 + (p % 28 + 1);
      dst[((long)(b * 3 + n) * 900 + qpad) * 768 + cc] = f2bf(tile[tx][i]);
    }
  }
}

// conv2: fp32 parts[S][64][1568] -> qkT[b][784][64] (+b2)
__global__ __launch_bounds__(256) void reduceT_qk(
    const float* __restrict__ parts, u16* __restrict__ dst,
    const float* __restrict__ bias, int S)
{
  __shared__ float tile[32][33];
  const int b = blockIdx.z, c0 = blockIdx.x * 32, p0 = blockIdx.y * 32;
  const int tx = threadIdx.x & 31, ty = threadIdx.x >> 5;
  for (int i = ty; i < 32; i += 8) {
    const int pc = min(p0 + tx, 783);
    const long base = (long)(c0 + i) * 1568 + b * 784 + pc;
    float s = 0;
    for (int k = 0; k < S; ++k) s += parts[(long)k * 64 * 1568 + base];
    tile[i][tx] = s;
  }
  __syncthreads();
  for (int i = ty; i < 32; i += 8) {
    const int p = p0 + i, c = c0 + tx;
    if (p < 784)
      dst[((long)b * 784 + p) * 64 + c] = f2bf(tile[tx][i] + bias[c]);
  }
}

__global__ __launch_bounds__(256) void transT_h(
    const float* __restrict__ h, u16* __restrict__ dst)
{
  __shared__ float tile[32][33];
  const int zimg = blockIdx.z, c0 = blockIdx.x * 32, p0 = blockIdx.y * 32;
  const int tx = threadIdx.x & 31, ty = threadIdx.x >> 5;
  for (int i = ty; i < 32; i += 8) {
    const int pc = min(p0 + tx, 783);
    tile[i][tx] = h[((long)zimg * 256 + c0 + i) * 784 + pc];
  }
  __syncthreads();
  for (int i = ty; i < 32; i += 8) {
    const int p = p0 + i, c = c0 + tx;
    if (p < 784) {
      const int qpad = (p / 28 + 1) * 30 + (p % 28 + 1);
      dst[((long)zimg * 900 + qpad) * 768 + 512 + c] = f2bf(tile[tx][i]);
    }
  }
}

// ---------------------------------------------------------------------------
// SINGLE-PASS in-place softmax over rows of 12544 bf16 (one block per row)
// ---------------------------------------------------------------------------
__global__ __launch_bounds__(256) void softmax_inplace(u16* __restrict__ buf)
{
  uint4* p4 = (uint4*)(buf + (long)blockIdx.x * 12544);
  const int t = threadIdx.x;
  __shared__ float red[4];
  uint4 v[7];
  float mx = -3.0e38f;
  #pragma unroll
  for (int q = 0; q < 7; ++q) {
    const int idx = t + q * 256;
    if (idx < 1568) {
      v[q] = p4[idx];
      const u32 w[4] = {v[q].x, v[q].y, v[q].z, v[q].w};
      #pragma unroll
      for (int e = 0; e < 4; ++e) {
        mx = fmaxf(mx, bf2f((u16)(w[e] & 0xFFFFu)));
        mx = fmaxf(mx, bf2f((u16)(w[e] >> 16)));
      }
    }
  }
  #pragma unroll
  for (int o = 32; o > 0; o >>= 1) mx = fmaxf(mx, __shfl_xor(mx, o));
  if ((t & 63) == 0) red[t >> 6] = mx;
  __syncthreads();
  mx = fmaxf(fmaxf(red[0], red[1]), fmaxf(red[2], red[3]));

  float s = 0.0f;
  #pragma unroll
  for (int q = 0; q < 7; ++q) {
    const int idx = t + q * 256;
    if (idx < 1568) {
      const u32 w[4] = {v[q].x, v[q].y, v[q].z, v[q].w};
      #pragma unroll
      for (int e = 0; e < 4; ++e) {
        s += __expf(bf2f((u16)(w[e] & 0xFFFFu)) - mx);
        s += __expf(bf2f((u16)(w[e] >> 16)) - mx);
      }
    }
  }
  #pragma unroll
  for (int o = 32; o > 0; o >>= 1) s += __shfl_xor(s, o);
  __syncthreads();
  if ((t & 63) == 0) red[t >> 6] = s;
  __syncthreads();
  const float inv = 1.0f / (red[0] + red[1] + red[2] + red[3]);

  #pragma unroll
  for (int q = 0; q < 7; ++q) {
    const int idx = t + q * 256;
    if (idx < 1568) {
      u32 w[4] = {v[q].x, v[q].y, v[q].z, v[q].w};
      #pragma unroll
      for (int e = 0; e < 4; ++e) {
        const float a = __expf(bf2f((u16)(w[e] & 0xFFFFu)) - mx) * inv;
        const float b = __expf(bf2f((u16)(w[e] >> 16)) - mx) * inv;
        w[e] = (u32)f2bf(a) | ((u32)f2bf(b) << 16);
      }
      p4[idx] = make_uint4(w[0], w[1], w[2], w[3]);
    }
  }
}

// ---------------------------------------------------------------------------
// Fused transform-reduce + gating. bf16 parts [S][768][4704] (channel-major)
// ---------------------------------------------------------------------------
__device__ __forceinline__ void addbf4(float* a, uint2 v) {
  a[0] += bf2f((u16)(v.x & 0xFFFFu));
  a[1] += bf2f((u16)(v.x >> 16));
  a[2] += bf2f((u16)(v.y & 0xFFFFu));
  a[3] += bf2f((u16)(v.y >> 16));
}

__global__ __launch_bounds__(256) void treduce_gate(
    const u16* __restrict__ parts, const float* __restrict__ bt,
    const float* __restrict__ h, float* __restrict__ out, int S)
{
  const long i = (long)blockIdx.x * 256 + threadIdx.x;
  if (i >= 6L * 256 * 196) return;
  const int p4 = (int)(i % 196);
  const int rest = (int)(i / 196);
  const int cs = rest % 256, im = rest / 256;
  const long slice = 768L * 4704;
  const long pbase = (long)im * 784 + p4 * 4;
  float F[4] = {}, U[4] = {}, NV[4] = {};
  for (int s = 0; s < S; ++s) {
    const u16* P = parts + (long)s * slice;
    addbf4(F,  *(const uint2*)&P[(long)cs         * 4704 + pbase]);
    addbf4(U,  *(const uint2*)&P[(long)(256 + cs) * 4704 + pbase]);
    addbf4(NV, *(const uint2*)&P[(long)(512 + cs) * 4704 + pbase]);
  }
  const float bF = bt[cs], bU = bt[256 + cs], bN = bt[512 + cs];
  const f32x4v hv = ((const f32x4v*)h)[((long)(im * 256 + cs) * 784 >> 2) + p4];
  f32x4v o;
  #pragma unroll
  for (int q = 0; q < 4; ++q) {
    const float f = F[q] + bF, u = U[q] + bU, nv = NV[q] + bN;
    const float sf = 1.0f / (1.0f + __expf(-f));
    const float su = 1.0f / (1.0f + __expf(-u));
    const float e2 = __expf(2.0f * nv);
    const float tv = (e2 - 1.0f) / (e2 + 1.0f);
    o[q] = sf * hv[q] * (1.0f - su) + su * tv;
  }
  ((f32x4v*)out)[((long)(im * 256 + cs) * 784 >> 2) + p4] = o;
}

__global__ __launch_bounds__(256) void fill_sentinel(float* p, long n) {
  const long i = (long)blockIdx.x * 256 + threadIdx.x;
  if (i < n) p[i] = 12345.0f;
}

// ---------------------------------------------------------------------------
extern "C" void kernel_launch(void* const* d_in, const int* in_sizes, int n_in,
                              void* d_out, int out_size, void* d_ws, size_t ws_size,
                              hipStream_t stream) {
  const float* f16 = (const float*)d_in[0];
  const float* mk  = (const float*)d_in[1];
  const float* mv  = (const float*)d_in[2];
  const float* hin = (const float*)d_in[3];
  const float* w1  = (const float*)d_in[4];
  const float* b1  = (const float*)d_in[5];
  const float* w2  = (const float*)d_in[6];
  const float* b2  = (const float*)d_in[7];
  const float* wt  = (const float*)d_in[8];
  const float* bt  = (const float*)d_in[9];
  float* out = (float*)d_out;

  (void)hipFuncSetAttribute((const void*)gemmRC<0>,
                            hipFuncAttributeMaxDynamicSharedMemorySize, 73728);
  (void)hipFuncSetAttribute((const void*)gemmRC<1>,
                            hipFuncAttributeMaxDynamicSharedMemorySize, 73728);
  constexpr unsigned DSM = 73728;

  const size_t B_f16T   = 2UL*784*1024*2;
  const size_t B_w1b    = 512UL*1024*2;
  const size_t B_w2R    = 64UL*4608*2;
  const size_t B_out1P  = 2UL*900*512*2;
  const size_t B_qkT    = 2UL*784*64*2;
  const size_t B_concat = 6UL*900*768*2;
  const size_t B_wtR    = 768UL*6912*2;
  const size_t B_mkT    = 2UL*12544*64*2;
  const size_t B_logaff = 2UL*784*12544*2;
  const size_t B_mvb    = 38535168UL*2;
  auto al = [](size_t x) { return (x + 255) & ~(size_t)255; };
  auto kcFor = [](int K, int S) { return ((K + S - 1) / S + 31) & ~31; };
  auto pad8 = [](int n) { return (n + 7) & ~7; };

  const size_t phase1 = al(B_f16T) + al(B_w1b) + al(B_w2R) + al(B_out1P) + al(B_qkT);
  const size_t regionA = phase1 > al(B_concat) ? phase1 : al(B_concat);

  auto poolFor = [&](int S_ro, int S_tr) -> size_t {
    size_t p2 = 18UL*64*1568*4;                       // conv2 fp32 partials
    size_t pr = (size_t)(2*S_ro)*1536*784*2;          // readout bf16 partials
    size_t pt = (size_t)S_tr*768*4704*2;              // transform bf16 partials
    size_t m = p2; if (pr > m) m = pr; if (pt > m) m = pt;
    return m;
  };
  const size_t fixed = regionA + al(B_wtR) + al(B_mkT) + al(B_logaff) + al(B_mvb);

  int S_ro = 6, S_tr = 4;   // readout grid 504 (2 blk/CU, 98% fill); transform 444
  if (fixed + poolFor(S_ro, S_tr) > ws_size) { S_ro = 3; S_tr = 2; }
  if (fixed + poolFor(S_ro, S_tr) > ws_size) {
    fill_sentinel<<<4704, 256, 0, stream>>>(out, (long)out_size);
    return;
  }
  const int Kc_ro = kcFor(12544, S_ro);   // 2112 (S=6)
  const int Kc_tr = kcFor(6912, S_tr);    // 1728 (S=4)

  char* base = (char*)d_ws;
  size_t off = 0;
  auto alloc = [&](size_t bytes) -> char* { char* p = base + off; off += al(bytes); return p; };
  char* rA = alloc(regionA);
  u16* f16T   = (u16*)rA;
  u16* w1b    = (u16*)(rA + al(B_f16T));
  u16* w2R    = (u16*)(rA + al(B_f16T) + al(B_w1b));
  u16* out1P  = (u16*)(rA + al(B_f16T) + al(B_w1b) + al(B_w2R));
  u16* qkT    = (u16*)(rA + al(B_f16T) + al(B_w1b) + al(B_w2R) + al(B_out1P));
  u16* concatP = (u16*)rA;   // overlays phase-1 buffers (dead by then)
  u16*   wtR     = (u16*)alloc(B_wtR);
  u16*   mkT     = (u16*)alloc(B_mkT);
  u16*   logaff  = (u16*)alloc(B_logaff);
  u16*   mvb     = (u16*)alloc(B_mvb);
  char*  partsRaw = alloc(poolFor(S_ro, S_tr));
  float* partsF  = (float*)partsRaw;
  u16*   partsH  = (u16*)partsRaw;

  // ---- zero padded conv1 image (borders must stay 0) ----
  zfill<<<512, 256, 0, stream>>>((u32*)out1P, (long)(B_out1P / 4));

  // ---- operand prep ----
  convert_bf<<<256, 256, 0, stream>>>(w1, w1b, 65536);
  permute_w<<<1152, 256, 0, stream>>>(w2, w2R, 64, 512);
  permute_w<<<20736, 256, 0, stream>>>(wt, wtR, 768, 768);
  transpose_bf<<<dim3(25, 32, 2), 256, 0, stream>>>(f16, f16T, 1024, 784, 784L*1024, 1024, 0);
  transpose_bf<<<dim3(392, 2, 2), 256, 0, stream>>>(mk, mkT, 64, 12544, 12544L*64, 64, 0);
  convert_bf<<<18816, 256, 0, stream>>>(mv, mvb, 4816896);

  // ---- conv1 (1x1) DIRECT: A=f16T[1568][1024] pixels, B=w1b[512][1024];
  //      fused bias + padded channel-last bf16 output (no split, no reduce) ----
  gemm_glds<64, 2><<<dim3(13, 4, 1), 256, 0, stream>>>(
      f16T, w1b, out1P, b1, 1568, 512, 1024, 1024, 1, 0, 0, 0, 1.0f);

  // ---- conv2 (3x3 implicit 128-tile): M=64, Cin=512, Ntot=1568, S=18 ----
  conv_glds<<<dim3(1, 13, 18), 256, 0, stream>>>(w2R, out1P, partsF, 64, 512, 1568, 256);
  reduceT_qk<<<dim3(2, 25, 2), 256, 0, stream>>>(partsF, qkT, b2, 18);

  // ---- logits: M=784, N=12544, K=64 -> bf16, scale 1/8 ----
  gemm_glds<64, 1><<<dim3(7, 98, 2), 256, 0, stream>>>(
      qkT, mkT, logaff, nullptr, 784, 12544, 64, 64, 1,
      784L*64, 12544L*64, 784L*12544, 0.125f);

  // ---- softmax over memory axis (single-pass, reg-resident) ----
  softmax_inplace<<<1568, 256, 0, stream>>>(logaff);

  // ---- zero concat image, fill h channels ----
  zfill<<<2048, 256, 0, stream>>>((u32*)concatP, (long)(B_concat / 4));
  transT_h<<<dim3(8, 25, 6), 256, 0, stream>>>(hin, concatP);

  // ---- readout: A=mvb[1536][12544], B=logaff[784][12544], XCD-chunked ----
  {
    const int nwg = 6 * 7 * 2 * S_ro;
    gemmRC<0><<<pad8(nwg), 512, DSM, stream>>>(
        mvb, logaff, partsH, 1536, 784, Kc_ro, 12544, S_ro,
        1536L*12544, 784L*12544, 1536L*784, 0, 6, 7, nwg);
  }
  reduceT_ro<<<dim3(48, 25, 2), 256, 0, stream>>>(partsH, concatP, S_ro);

  // ---- transform conv: A=wtR[768][6912], B=concatP pixels, XCD-chunked ----
  {
    const int nwg = 3 * 37 * S_tr;
    gemmRC<1><<<pad8(nwg), 512, DSM, stream>>>(
        wtR, concatP, partsH, 768, 4704, Kc_tr, 6912, S_tr,
        0, 0, 768L*4704, 768, 3, 37, nwg);
  }

  // ---- fused reduce + gating -> d_out ----
  treduce_gate<<<1176, 256, 0, stream>>>(partsH, bt, hin, out, S_tr);
}

// Round 11
// 324.664 us; speedup vs baseline: 1.2275x; 1.0972x over previous
//
#include <hip/hip_runtime.h>

typedef unsigned short u16;
typedef unsigned int u32;
typedef float f32x4v __attribute__((ext_vector_type(4)));
typedef __bf16 bf16x8 __attribute__((ext_vector_type(8)));

#define GAS __attribute__((address_space(1)))
#define LAS __attribute__((address_space(3)))

__device__ __forceinline__ u16 f2bf(float f) {
  u32 u = __builtin_bit_cast(u32, f);
  u32 r = (u + 0x7FFFu + ((u >> 16) & 1u)) >> 16;  // RNE
  return (u16)r;
}
__device__ __forceinline__ float bf2f(u16 h) {
  return __builtin_bit_cast(float, (u32)h << 16);
}
__device__ __forceinline__ void gld_lds16(const void* g, void* l) {
  __builtin_amdgcn_global_load_lds((const GAS void*)g, (LAS void*)l, 16, 0, 0);
}
#define VMCNT(N) asm volatile("s_waitcnt vmcnt(" #N ")" ::: "memory")
#define MFMA16(a, b, c) __builtin_amdgcn_mfma_f32_16x16x32_bf16((a), (b), (c), 0, 0, 0)

// ---------------------------------------------------------------------------
// 8-PHASE 256x256 MFMA GEMM (m201 structure). BK=64 K-tiles; 512 thr / 8
// waves (2M x 4N), per-wave 128x64, acc 8x4. LDS 128 KB dynamic.
// Per K-tile tau, 4 phases: {ds_read A-quadrant (Q0 also all B frags->regs);
// stage ONE half-tile; Q3: vmcnt(4); barrier; setprio+16 MFMA; barrier}.
// 3 half-tiles stay in flight across barriers — never drained in loop.
// Tail: stage targets clamp to T-1 (idempotent restage, race-free).
// Bank-conflict-free via per-row chunk rotation (slot=(g+row&7)&7), applied
// on glds SOURCE k-chunk and ds_read address (both-sides; LDS dest linear).
// 1D grid + XCD-chunked remap (y fastest -> A-tile sharers on one XCD).
// BF16 partials (fp32 accum): Cp + z*strC; z = zb*S + s; uneven tail K ok.
// CONV=1: B rows are pixels of zero-padded channel-last stack [nImg][900][Cin].
// ---------------------------------------------------------------------------
template <int CONV>
__global__ __launch_bounds__(512, 2) void gemm8p(
    const u16* __restrict__ A, const u16* __restrict__ B, u16* __restrict__ Cp,
    int M, int N, int Kc, int fullK, int S,
    long strA, long strB, long strC, int Cin, int gx, int gy, int nwg)
{
  const int cpx = (int)gridDim.x >> 3;
  const int L = ((int)blockIdx.x & 7) * cpx + ((int)blockIdx.x >> 3);
  if (L >= nwg) return;
  const int by = L % gy;
  const int rest = L / gy;
  const int bx = rest % gx;
  const int z = rest / gx;

  extern __shared__ u16 smem[];          // A: 4 x 8192 u16, B: +32768
  const int t = threadIdx.x, lane = t & 63, wave = t >> 6;
  const int zb = z / S, s = z - zb * S;
  const int m0 = bx * 256, n0 = by * 256;
  const int kbeg = s * Kc;
  const int kavail = fullK - kbeg;
  const int kc = Kc < kavail ? Kc : kavail;
  const int T = kc >> 6;                 // K-tiles of 64 (>= 2 in all uses)

  const int srow = t >> 3;
  const int g = ((t & 7) - (srow & 7)) & 7;
  const int ldsoff = t * 8;

  const u16* Asrc[2][2];
  #pragma unroll
  for (int h = 0; h < 2; ++h)
    #pragma unroll
    for (int q = 0; q < 2; ++q) {
      int r = m0 + h * 128 + q * 64 + srow; if (r >= M) r = M - 1;
      Asrc[h][q] = A + (long)zb * strA + (long)r * fullK + kbeg + g * 8;
    }
  const u16* Bsrc[2][2];
  #pragma unroll
  for (int h = 0; h < 2; ++h)
    #pragma unroll
    for (int q = 0; q < 2; ++q) {
      if constexpr (CONV) {
        int pn = n0 + h * 128 + q * 64 + srow; if (pn >= N) pn = 0;
        const int img = pn / 784, p = pn - img * 784;
        const int py = p / 28, px = p - py * 28;
        Bsrc[h][q] = B + ((long)img * 900 + (py + 1) * 30 + (px + 1)) * Cin + g * 8;
      } else {
        int r = n0 + h * 128 + q * 64 + srow; if (r >= N) r = N - 1;
        Bsrc[h][q] = B + (long)zb * strB + (long)r * fullK + kbeg + g * 8;
      }
    }

  auto stageA = [&](int tile, int h) {
    u16* d = smem + (((tile & 1) * 2 + h) * 8192);
    const long ko = (long)tile * 64;
    gld_lds16(Asrc[h][0] + ko, d + ldsoff);
    gld_lds16(Asrc[h][1] + ko, d + 4096 + ldsoff);
  };
  auto stageB = [&](int tile, int h) {
    u16* d = smem + 32768 + (((tile & 1) * 2 + h) * 8192);
    long off;
    if constexpr (CONV) {
      const int kg = kbeg + tile * 64;   // Cin%64==0 -> tap uniform in chunk
      const int tap = kg / Cin, kc2 = kg - tap * Cin;
      off = (long)((tap / 3 - 1) * 30 + (tap % 3 - 1)) * Cin + kc2;
    } else {
      off = (long)tile * 64;
    }
    gld_lds16(Bsrc[h][0] + off, d + ldsoff);
    gld_lds16(Bsrc[h][1] + off, d + 4096 + ldsoff);
  };

  const int wm = wave & 1, wn = wave >> 1;
  const int lr = lane & 15, hi = lane >> 4;
  const int slot0 = ((hi + (lr & 7)) & 7) * 8;
  const int slot1 = (((hi + 4) + (lr & 7)) & 7) * 8;
  f32x4v acc[8][4] = {};
  bf16x8 breg[4][2];

  // prologue: queue = B0(0),B1(0),A0(0),A1(0),B0(1),B1(1)
  stageB(0, 0); stageB(0, 1);
  stageA(0, 0); stageA(0, 1);
  stageB(1, 0); stageB(1, 1);            // T >= 2 always
  VMCNT(4);
  __builtin_amdgcn_s_barrier();

  for (int tau = 0; tau < T; ++tau) {
    const int d = tau & 1;
    const u16* aB = smem + ((d * 2 + wm) * 8192);
    const u16* bB = smem + 32768 + ((d * 2 + (wn >> 1)) * 8192);
    const int ta = (tau + 1 < T) ? tau + 1 : T - 1;
    const int tb = (tau + 2 < T) ? tau + 2 : T - 1;
    #pragma unroll
    for (int Q = 0; Q < 4; ++Q) {
      bf16x8 aph[2][2];
      #pragma unroll
      for (int m2 = 0; m2 < 2; ++m2) {
        const int lrow = (Q * 2 + m2) * 16 + lr;
        aph[m2][0] = *(const bf16x8*)&aB[lrow * 64 + slot0];
        aph[m2][1] = *(const bf16x8*)&aB[lrow * 64 + slot1];
      }
      if (Q == 0) {
        #pragma unroll
        for (int n = 0; n < 4; ++n) {
          const int lrow = (wn & 1) * 64 + n * 16 + lr;
          breg[n][0] = *(const bf16x8*)&bB[lrow * 64 + slot0];
          breg[n][1] = *(const bf16x8*)&bB[lrow * 64 + slot1];
        }
      }
      if      (Q == 0) stageA(ta, 0);
      else if (Q == 1) stageA(ta, 1);
      else if (Q == 2) stageB(tb, 0);
      else             { stageB(tb, 1); VMCNT(4); }
      __builtin_amdgcn_sched_barrier(0);
      __builtin_amdgcn_s_barrier();
      __builtin_amdgcn_s_setprio(1);
      #pragma unroll
      for (int m2 = 0; m2 < 2; ++m2)
        #pragma unroll
        for (int n = 0; n < 4; ++n) {
          acc[Q * 2 + m2][n] = MFMA16(aph[m2][0], breg[n][0], acc[Q * 2 + m2][n]);
          acc[Q * 2 + m2][n] = MFMA16(aph[m2][1], breg[n][1], acc[Q * 2 + m2][n]);
        }
      __builtin_amdgcn_s_setprio(0);
      __builtin_amdgcn_sched_barrier(0);
      __builtin_amdgcn_s_barrier();
    }
  }
  VMCNT(0);

  // epilogue: D lane l reg r -> row=(l>>4)*4+r, col=l&15; bf16 partial out
  u16* Co = Cp + (long)z * strC;
  #pragma unroll
  for (int m = 0; m < 8; ++m)
    #pragma unroll
    for (int r = 0; r < 4; ++r) {
      const int row = m0 + wm * 128 + m * 16 + hi * 4 + r;
      if (row >= M) continue;
      #pragma unroll
      for (int n = 0; n < 4; ++n) {
        const int col = n0 + wn * 64 + n * 16 + lr;
        if (col < N) Co[(long)row * N + col] = f2bf(acc[m][n][r]);
      }
    }
}

// ---------------------------------------------------------------------------
// 256x128 MFMA GEMM, BK=32, depth-3 circular (72 KB, 2 blk/CU), vmcnt(6).
// XCD-chunked 1D grid. BF16 partials. (Used for conv1.)
// ---------------------------------------------------------------------------
template <int CONV>
__global__ __launch_bounds__(512, 4) void gemmRC(
    const u16* __restrict__ A, const u16* __restrict__ B, u16* __restrict__ Cp,
    int M, int N, int Kc, int fullK, int S,
    long strA, long strB, long strC, int Cin, int gx, int gy, int nwg)
{
  const int cpx = (int)gridDim.x >> 3;
  const int L = ((int)blockIdx.x & 7) * cpx + ((int)blockIdx.x >> 3);
  if (L >= nwg) return;
  const int by = L % gy;
  const int rest = L / gy;
  const int bx = rest % gx;
  const int z = rest / gx;

  extern __shared__ u16 smem[];
  u16* sA = smem;
  u16* sB = smem + 3 * 8192;
  const int t = threadIdx.x, lane = t & 63, wave = t >> 6;
  const int zb = z / S, s = z - zb * S;
  const int m0 = bx * 256, n0 = by * 128;
  const int kbeg = s * Kc;
  const int kavail = fullK - kbeg;
  const int kc = Kc < kavail ? Kc : kavail;
  const int niter = kc >> 5;

  const int schunk = ((t & 3) ^ ((t >> 4) & 3)) * 8;
  const u16* Ap[2]; const u16* Bp;
  #pragma unroll
  for (int q = 0; q < 2; ++q) {
    int ra = m0 + q * 128 + (t >> 2); if (ra >= M) ra = M - 1;
    Ap[q] = A + (long)zb * strA + (long)ra * fullK + schunk;
  }
  if constexpr (CONV) {
    int pn = n0 + (t >> 2); if (pn >= N) pn = 0;
    const int img = pn / 784, p = pn - img * 784;
    const int py = p / 28, px = p - py * 28;
    Bp = B + ((long)img * 900 + (py + 1) * 30 + (px + 1)) * Cin + schunk;
  } else {
    int rb = n0 + (t >> 2); if (rb >= N) rb = N - 1;
    Bp = B + (long)zb * strB + (long)rb * fullK + schunk;
  }
  const int ldst = t * 8;

  auto stage = [&](int buf, int kg) {
    long boff;
    if constexpr (CONV) {
      const int tap = kg / Cin, kcc = kg - tap * Cin;
      boff = (long)((tap / 3 - 1) * 30 + (tap % 3 - 1)) * Cin + kcc;
    } else {
      boff = kg;
    }
    u16* dA = sA + buf * 8192;
    gld_lds16(Ap[0] + kg, &dA[ldst]);
    gld_lds16(Ap[1] + kg, &dA[4096 + ldst]);
    gld_lds16(Bp + boff,  &sB[buf * 4096 + ldst]);
  };

  const int wrow = (wave & 3) * 64, wcol = (wave >> 2) * 64;
  const int lr = lane & 15, hi = lane >> 4;
  const int csw = (hi ^ (lr >> 2)) * 8;
  f32x4v acc[4][4] = {};

  for (int p = 0; p < 2 && p < niter; ++p) stage(p, kbeg + p * 32);
  int cur = 0, nxt = 2;
  for (int it = 0; it < niter; ++it) {
    if (it + 2 < niter) {
      stage(nxt, kbeg + (it + 2) * 32);
      VMCNT(6);
    } else {
      const int rem = niter - 1 - it;
      if (rem == 1) VMCNT(3); else VMCNT(0);
    }
    __builtin_amdgcn_s_barrier();
    __builtin_amdgcn_sched_barrier(0);
    const u16* cA = sA + cur * 8192;
    const u16* cB = sB + cur * 4096;
    bf16x8 af[4], bf[4];
    #pragma unroll
    for (int m = 0; m < 4; ++m) af[m] = *(const bf16x8*)&cA[(wrow + m*16 + lr) * 32 + csw];
    #pragma unroll
    for (int n = 0; n < 4; ++n) bf[n] = *(const bf16x8*)&cB[(wcol + n*16 + lr) * 32 + csw];
    __builtin_amdgcn_s_setprio(1);
    #pragma unroll
    for (int m = 0; m < 4; ++m)
      #pragma unroll
      for (int n = 0; n < 4; ++n)
        acc[m][n] = MFMA16(af[m], bf[n], acc[m][n]);
    __builtin_amdgcn_s_setprio(0);
    __builtin_amdgcn_sched_barrier(0);
    __builtin_amdgcn_s_barrier();
    cur = (cur + 1 == 3) ? 0 : cur + 1;
    nxt = (nxt + 1 == 3) ? 0 : nxt + 1;
  }

  u16* Co = Cp + (long)z * strC;
  const int lq = hi * 4;
  #pragma unroll
  for (int m = 0; m < 4; ++m)
    #pragma unroll
    for (int r = 0; r < 4; ++r) {
      const int row = m0 + wrow + m * 16 + lq + r;
      if (row >= M) continue;
      #pragma unroll
      for (int n = 0; n < 4; ++n) {
        const int col = n0 + wcol + n * 16 + lr;
        if (col < N) Co[(long)row * N + col] = f2bf(acc[m][n][r]);
      }
    }
}

// ---------------------------------------------------------------------------
// 128x128 glds GEMM (logits). Counted-vmcnt depth-1. bf16 out *scale.
// ---------------------------------------------------------------------------
template <int BK>
__global__ __launch_bounds__(256) void gemm_glds(
    const u16* __restrict__ A, const u16* __restrict__ B, u16* __restrict__ C,
    int M, int N, int Kc, int fullK, int S,
    long strA, long strB, long strC, float scale)
{
  constexpr int CPR = BK / 8;
  constexpr int ISS = BK / 16;
  __shared__ u16 sA[2][128 * BK];
  __shared__ u16 sB[2][128 * BK];
  const int t = threadIdx.x, lane = t & 63, wave = t >> 6;
  const int z = blockIdx.z, zb = z / S;
  const int m0 = blockIdx.x * 128, n0 = blockIdx.y * 128;
  const int kbeg = (z - zb * S) * Kc;

  const u16* Aptr[ISS]; const u16* Bptr[ISS]; int lofs[ISS];
  #pragma unroll
  for (int i = 0; i < ISS; ++i) {
    const int tp = i * 256 + t;
    const int r = tp / CPR;
    int c16 = tp % CPR;
    if constexpr (BK == 32) c16 = c16 ^ ((tp >> 4) & 3);
    else                    c16 = (c16 - (r & 7)) & 7;
    int ra = m0 + r; if (ra >= M) ra = M - 1;
    int rb = n0 + r; if (rb >= N) rb = N - 1;
    Aptr[i] = A + (long)zb * strA + (long)ra * fullK + kbeg + c16 * 8;
    Bptr[i] = B + (long)zb * strB + (long)rb * fullK + kbeg + c16 * 8;
    lofs[i] = (i * 256 + (wave << 6)) * 8;
  }
  auto stage = [&](int buf, int k0) {
    #pragma unroll
    for (int i = 0; i < ISS; ++i) {
      gld_lds16(Aptr[i] + k0, &sA[buf][lofs[i]]);
      gld_lds16(Bptr[i] + k0, &sB[buf][lofs[i]]);
    }
  };

  const int wr = (wave >> 1) * 64, wc = (wave & 1) * 64;
  const int lr = lane & 15, hi = lane >> 4;
  f32x4v acc[4][4] = {};
  const int niter = Kc / BK;

  stage(0, 0);
  for (int it = 0; it < niter; ++it) {
    const int cur = it & 1;
    if (it + 1 < niter) {
      stage(cur ^ 1, (it + 1) * BK);
      if constexpr (ISS == 2) VMCNT(4); else VMCNT(8);
    } else {
      VMCNT(0);
    }
    __builtin_amdgcn_s_barrier();
    __builtin_amdgcn_sched_barrier(0);
    #pragma unroll
    for (int kk = 0; kk < BK; kk += 32) {
      bf16x8 af[4], bv[4];
      #pragma unroll
      for (int i = 0; i < 4; ++i) {
        const int row = wr + i*16 + lr;
        int lk;
        if constexpr (BK == 32) lk = kk + ((hi ^ (lr >> 2)) * 8);
        else                    lk = ((((kk >> 3) + hi) + (row & 7)) & 7) * 8;
        af[i] = *(const bf16x8*)&sA[cur][row * BK + lk];
      }
      #pragma unroll
      for (int j = 0; j < 4; ++j) {
        const int row = wc + j*16 + lr;
        int lk;
        if constexpr (BK == 32) lk = kk + ((hi ^ (lr >> 2)) * 8);
        else                    lk = ((((kk >> 3) + hi) + (row & 7)) & 7) * 8;
        bv[j] = *(const bf16x8*)&sB[cur][row * BK + lk];
      }
      __builtin_amdgcn_s_setprio(1);
      #pragma unroll
      for (int i = 0; i < 4; ++i)
        #pragma unroll
        for (int j = 0; j < 4; ++j)
          acc[i][j] = MFMA16(af[i], bv[j], acc[i][j]);
      __builtin_amdgcn_s_setprio(0);
    }
    __builtin_amdgcn_sched_barrier(0);
    __builtin_amdgcn_s_barrier();
  }

  const int lq = hi * 4;
  u16* Cw = C + (long)zb * strC;
  #pragma unroll
  for (int i = 0; i < 4; ++i)
    #pragma unroll
    for (int r = 0; r < 4; ++r) {
      const int row = m0 + wr + i*16 + lq + r;
      if (row >= M) continue;
      #pragma unroll
      for (int j = 0; j < 4; ++j) {
        const int col = n0 + wc + j*16 + lr;
        if (col < N) Cw[(long)row * N + col] = f2bf(acc[i][j][r] * scale);
      }
    }
}

// ---------------------------------------------------------------------------
// 128x128 implicit-conv (conv2: M=64). Counted-vmcnt depth-1. fp32 partials.
// ---------------------------------------------------------------------------
__global__ __launch_bounds__(256) void conv_glds(
    const u16* __restrict__ Wt, const u16* __restrict__ imgP,
    float* __restrict__ Cp, int M, int Cin, int Ntot, int Kc)
{
  __shared__ u16 sA[2][128 * 32];
  __shared__ u16 sB[2][128 * 32];
  const int t = threadIdx.x, lane = t & 63, wave = t >> 6;
  const int z = blockIdx.z;
  const int m0 = blockIdx.x * 128, n0 = blockIdx.y * 128;
  const int kbeg = z * Kc;

  const u16* Aptr[2]; const u16* Bptr[2]; int lofs[2];
  #pragma unroll
  for (int i = 0; i < 2; ++i) {
    const int tp = i * 256 + t;
    const int r = tp >> 2;
    const int c16 = (tp & 3) ^ ((tp >> 4) & 3);
    int ra = m0 + r; if (ra >= M) ra = M - 1;
    int pn = n0 + r; if (pn >= Ntot) pn = 0;
    const int img = pn / 784, p = pn - img * 784;
    const int py = p / 28, px = p - py * 28;
    Aptr[i] = Wt + (long)ra * (9 * Cin) + c16 * 8;
    Bptr[i] = imgP + ((long)img * 900 + (py + 1) * 30 + (px + 1)) * Cin + c16 * 8;
    lofs[i] = (i * 256 + (wave << 6)) * 8;
  }
  auto stage = [&](int buf, int kg) {
    const int tap = kg / Cin, kc = kg - tap * Cin;
    const long off = (long)((tap / 3 - 1) * 30 + (tap % 3 - 1)) * Cin + kc;
    #pragma unroll
    for (int i = 0; i < 2; ++i) {
      gld_lds16(Aptr[i] + kg, &sA[buf][lofs[i]]);
      gld_lds16(Bptr[i] + off, &sB[buf][lofs[i]]);
    }
  };

  const int wr = (wave >> 1) * 64, wc = (wave & 1) * 64;
  const int lr = lane & 15, hi = lane >> 4;
  const int csw = (hi ^ (lr >> 2)) * 8;
  f32x4v acc[4][4] = {};
  const int niter = Kc >> 5;

  stage(0, kbeg);
  for (int it = 0; it < niter; ++it) {
    const int cur = it & 1;
    if (it + 1 < niter) {
      stage(cur ^ 1, kbeg + (it + 1) * 32);
      VMCNT(4);
    } else {
      VMCNT(0);
    }
    __builtin_amdgcn_s_barrier();
    __builtin_amdgcn_sched_barrier(0);
    bf16x8 af[4], bv[4];
    #pragma unroll
    for (int i = 0; i < 4; ++i) af[i] = *(const bf16x8*)&sA[cur][(wr + i*16 + lr) * 32 + csw];
    #pragma unroll
    for (int j = 0; j < 4; ++j) bv[j] = *(const bf16x8*)&sB[cur][(wc + j*16 + lr) * 32 + csw];
    __builtin_amdgcn_s_setprio(1);
    #pragma unroll
    for (int i = 0; i < 4; ++i)
      #pragma unroll
      for (int j = 0; j < 4; ++j)
        acc[i][j] = MFMA16(af[i], bv[j], acc[i][j]);
    __builtin_amdgcn_s_setprio(0);
    __builtin_amdgcn_sched_barrier(0);
    __builtin_amdgcn_s_barrier();
  }

  float* Co = Cp + (long)z * M * Ntot;
  const int lq = hi * 4;
  #pragma unroll
  for (int i = 0; i < 4; ++i)
    #pragma unroll
    for (int r = 0; r < 4; ++r) {
      const int row = m0 + wr + i*16 + lq + r;
      if (row >= M) continue;
      #pragma unroll
      for (int j = 0; j < 4; ++j) {
        const int col = n0 + wc + j*16 + lr;
        if (col < Ntot) Co[(long)row * Ntot + col] = acc[i][j][r];
      }
    }
}

// ---------------------------------------------------------------------------
// Helpers
// ---------------------------------------------------------------------------
__global__ __launch_bounds__(256) void transpose_bf(
    const float* __restrict__ in, u16* __restrict__ out,
    int R, int C, long strOutZ, int ldOut, int colOff)
{
  __shared__ float tile[32][33];
  in  += (long)blockIdx.z * R * C;
  out += (long)blockIdx.z * strOutZ;
  const int c0 = blockIdx.x * 32, r0 = blockIdx.y * 32;
  const int tx = threadIdx.x & 31, ty = threadIdx.x >> 5;
  for (int i = ty; i < 32; i += 8) {
    const int r = r0 + i, c = c0 + tx;
    tile[i][tx] = (r < R && c < C) ? in[(long)r * C + c] : 0.0f;
  }
  __syncthreads();
  for (int i = ty; i < 32; i += 8) {
    const int r = r0 + tx, c = c0 + i;
    if (c < C && r < R)
      out[(long)c * ldOut + colOff + r] = f2bf(tile[tx][i]);
  }
}

__global__ __launch_bounds__(256) void convert_bf(
    const float* __restrict__ in, u16* __restrict__ out, long n8)
{
  const long i = (long)blockIdx.x * 256 + threadIdx.x;
  if (i >= n8) return;
  const float4* p = (const float4*)in + i * 2;
  const float4 a = p[0], b = p[1];
  u16 o[8] = {f2bf(a.x), f2bf(a.y), f2bf(a.z), f2bf(a.w),
              f2bf(b.x), f2bf(b.y), f2bf(b.z), f2bf(b.w)};
  ((uint4*)out)[i] = *(uint4*)o;
}

__global__ __launch_bounds__(256) void permute_w(
    const float* __restrict__ src, u16* __restrict__ dst, int M, int Cin)
{
  const long total = (long)M * 9 * Cin;
  const long idx = (long)blockIdx.x * 256 + threadIdx.x;
  if (idx >= total) return;
  const int c = (int)(idx % Cin);
  const int tap = (int)((idx / Cin) % 9);
  const int m = (int)(idx / ((long)9 * Cin));
  dst[idx] = f2bf(src[((long)m * Cin + c) * 9 + tap]);
}

__global__ __launch_bounds__(256) void zfill(u32* __restrict__ p, long n) {
  const long stride = (long)gridDim.x * 256;
  for (long i = (long)blockIdx.x * 256 + threadIdx.x; i < n; i += stride) p[i] = 0;
}

// ---------------------------------------------------------------------------
// Reduce kernels
// ---------------------------------------------------------------------------
__device__ __forceinline__ void addbf4(float* a, uint2 v) {
  a[0] += bf2f((u16)(v.x & 0xFFFFu));
  a[1] += bf2f((u16)(v.x >> 16));
  a[2] += bf2f((u16)(v.y & 0xFFFFu));
  a[3] += bf2f((u16)(v.y >> 16));
}

// conv1: bf16 parts[S][1568][512] (pixel-major) -> out1P[b][900pad][512] +b1
__global__ __launch_bounds__(256) void reduce_c1_bf(
    const u16* __restrict__ parts, u16* __restrict__ dst,
    const float* __restrict__ bias, int S)
{
  const long idx = (long)blockIdx.x * 256 + threadIdx.x;
  if (idx >= 1568L * 128) return;
  const int c4 = (int)(idx & 127), p = (int)(idx >> 7);
  const int c = c4 * 4;
  float sum[4] = {bias[c], bias[c+1], bias[c+2], bias[c+3]};
  for (int s = 0; s < S; ++s)
    addbf4(sum, *(const uint2*)&parts[((long)s * 1568 + p) * 512 + c]);
  const int im = p / 784, q = p - im * 784;
  const int qpad = (q / 28 + 1) * 30 + (q % 28 + 1);
  u16 o[4] = {f2bf(sum[0]), f2bf(sum[1]), f2bf(sum[2]), f2bf(sum[3])};
  *(uint2*)&dst[((long)im * 900 + qpad) * 512 + c] = *(uint2*)o;
}

// readout: bf16 parts[(b*S+s)][1536][784] -> concatP[b*3+n][900pad][768]
__global__ __launch_bounds__(256) void reduceT_ro(
    const u16* __restrict__ parts, u16* __restrict__ dst, int S)
{
  __shared__ float tile[32][33];
  const int b = blockIdx.z, c0 = blockIdx.x * 32, p0 = blockIdx.y * 32;
  const int tx = threadIdx.x & 31, ty = threadIdx.x >> 5;
  for (int i = ty; i < 32; i += 8) {
    const int pc = min(p0 + tx, 783);
    float s = 0;
    for (int k = 0; k < S; ++k)
      s += bf2f(parts[((long)(b * S + k) * 1536 + c0 + i) * 784 + pc]);
    tile[i][tx] = s;
  }
  __syncthreads();
  for (int i = ty; i < 32; i += 8) {
    const int p = p0 + i, c = c0 + tx;
    if (p < 784) {
      const int n = c >> 9, cc = c & 511;
      const int qpad = (p / 28 + 1) * 30 + (p % 28 + 1);
      dst[((long)(b * 3 + n) * 900 + qpad) * 768 + cc] = f2bf(tile[tx][i]);
    }
  }
}

// conv2: fp32 parts[S][64][1568] -> qkT[b][784][64] (+b2)
__global__ __launch_bounds__(256) void reduceT_qk(
    const float* __restrict__ parts, u16* __restrict__ dst,
    const float* __restrict__ bias, int S)
{
  __shared__ float tile[32][33];
  const int b = blockIdx.z, c0 = blockIdx.x * 32, p0 = blockIdx.y * 32;
  const int tx = threadIdx.x & 31, ty = threadIdx.x >> 5;
  for (int i = ty; i < 32; i += 8) {
    const int pc = min(p0 + tx, 783);
    const long base = (long)(c0 + i) * 1568 + b * 784 + pc;
    float s = 0;
    for (int k = 0; k < S; ++k) s += parts[(long)k * 64 * 1568 + base];
    tile[i][tx] = s;
  }
  __syncthreads();
  for (int i = ty; i < 32; i += 8) {
    const int p = p0 + i, c = c0 + tx;
    if (p < 784)
      dst[((long)b * 784 + p) * 64 + c] = f2bf(tile[tx][i] + bias[c]);
  }
}

__global__ __launch_bounds__(256) void transT_h(
    const float* __restrict__ h, u16* __restrict__ dst)
{
  __shared__ float tile[32][33];
  const int zimg = blockIdx.z, c0 = blockIdx.x * 32, p0 = blockIdx.y * 32;
  const int tx = threadIdx.x & 31, ty = threadIdx.x >> 5;
  for (int i = ty; i < 32; i += 8) {
    const int pc = min(p0 + tx, 783);
    tile[i][tx] = h[((long)zimg * 256 + c0 + i) * 784 + pc];
  }
  __syncthreads();
  for (int i = ty; i < 32; i += 8) {
    const int p = p0 + i, c = c0 + tx;
    if (p < 784) {
      const int qpad = (p / 28 + 1) * 30 + (p % 28 + 1);
      dst[((long)zimg * 900 + qpad) * 768 + 512 + c] = f2bf(tile[tx][i]);
    }
  }
}

// ---------------------------------------------------------------------------
// SINGLE-PASS in-place softmax over rows of 12544 bf16 (one block per row)
// ---------------------------------------------------------------------------
__global__ __launch_bounds__(256) void softmax_inplace(u16* __restrict__ buf)
{
  uint4* p4 = (uint4*)(buf + (long)blockIdx.x * 12544);
  const int t = threadIdx.x;
  __shared__ float red[4];
  uint4 v[7];
  float mx = -3.0e38f;
  #pragma unroll
  for (int q = 0; q < 7; ++q) {
    const int idx = t + q * 256;
    if (idx < 1568) {
      v[q] = p4[idx];
      const u32 w[4] = {v[q].x, v[q].y, v[q].z, v[q].w};
      #pragma unroll
      for (int e = 0; e < 4; ++e) {
        mx = fmaxf(mx, bf2f((u16)(w[e] & 0xFFFFu)));
        mx = fmaxf(mx, bf2f((u16)(w[e] >> 16)));
      }
    }
  }
  #pragma unroll
  for (int o = 32; o > 0; o >>= 1) mx = fmaxf(mx, __shfl_xor(mx, o));
  if ((t & 63) == 0) red[t >> 6] = mx;
  __syncthreads();
  mx = fmaxf(fmaxf(red[0], red[1]), fmaxf(red[2], red[3]));

  float s = 0.0f;
  #pragma unroll
  for (int q = 0; q < 7; ++q) {
    const int idx = t + q * 256;
    if (idx < 1568) {
      const u32 w[4] = {v[q].x, v[q].y, v[q].z, v[q].w};
      #pragma unroll
      for (int e = 0; e < 4; ++e) {
        s += __expf(bf2f((u16)(w[e] & 0xFFFFu)) - mx);
        s += __expf(bf2f((u16)(w[e] >> 16)) - mx);
      }
    }
  }
  #pragma unroll
  for (int o = 32; o > 0; o >>= 1) s += __shfl_xor(s, o);
  __syncthreads();
  if ((t & 63) == 0) red[t >> 6] = s;
  __syncthreads();
  const float inv = 1.0f / (red[0] + red[1] + red[2] + red[3]);

  #pragma unroll
  for (int q = 0; q < 7; ++q) {
    const int idx = t + q * 256;
    if (idx < 1568) {
      u32 w[4] = {v[q].x, v[q].y, v[q].z, v[q].w};
      #pragma unroll
      for (int e = 0; e < 4; ++e) {
        const float a = __expf(bf2f((u16)(w[e] & 0xFFFFu)) - mx) * inv;
        const float b = __expf(bf2f((u16)(w[e] >> 16)) - mx) * inv;
        w[e] = (u32)f2bf(a) | ((u32)f2bf(b) << 16);
      }
      p4[idx] = make_uint4(w[0], w[1], w[2], w[3]);
    }
  }
}

// ---------------------------------------------------------------------------
// Fused transform-reduce + gating. bf16 parts [S][768][4704] (channel-major)
// ---------------------------------------------------------------------------
__global__ __launch_bounds__(256) void treduce_gate(
    const u16* __restrict__ parts, const float* __restrict__ bt,
    const float* __restrict__ h, float* __restrict__ out, int S)
{
  const long i = (long)blockIdx.x * 256 + threadIdx.x;
  if (i >= 6L * 256 * 196) return;
  const int p4 = (int)(i % 196);
  const int rest = (int)(i / 196);
  const int cs = rest % 256, im = rest / 256;
  const long slice = 768L * 4704;
  const long pbase = (long)im * 784 + p4 * 4;
  float F[4] = {}, U[4] = {}, NV[4] = {};
  for (int s = 0; s < S; ++s) {
    const u16* P = parts + (long)s * slice;
    addbf4(F,  *(const uint2*)&P[(long)cs         * 4704 + pbase]);
    addbf4(U,  *(const uint2*)&P[(long)(256 + cs) * 4704 + pbase]);
    addbf4(NV, *(const uint2*)&P[(long)(512 + cs) * 4704 + pbase]);
  }
  const float bF = bt[cs], bU = bt[256 + cs], bN = bt[512 + cs];
  const f32x4v hv = ((const f32x4v*)h)[((long)(im * 256 + cs) * 784 >> 2) + p4];
  f32x4v o;
  #pragma unroll
  for (int q = 0; q < 4; ++q) {
    const float f = F[q] + bF, u = U[q] + bU, nv = NV[q] + bN;
    const float sf = 1.0f / (1.0f + __expf(-f));
    const float su = 1.0f / (1.0f + __expf(-u));
    const float e2 = __expf(2.0f * nv);
    const float tv = (e2 - 1.0f) / (e2 + 1.0f);
    o[q] = sf * hv[q] * (1.0f - su) + su * tv;
  }
  ((f32x4v*)out)[((long)(im * 256 + cs) * 784 >> 2) + p4] = o;
}

__global__ __launch_bounds__(256) void fill_sentinel(float* p, long n) {
  const long i = (long)blockIdx.x * 256 + threadIdx.x;
  if (i < n) p[i] = 12345.0f;
}

// ---------------------------------------------------------------------------
extern "C" void kernel_launch(void* const* d_in, const int* in_sizes, int n_in,
                              void* d_out, int out_size, void* d_ws, size_t ws_size,
                              hipStream_t stream) {
  const float* f16 = (const float*)d_in[0];
  const float* mk  = (const float*)d_in[1];
  const float* mv  = (const float*)d_in[2];
  const float* hin = (const float*)d_in[3];
  const float* w1  = (const float*)d_in[4];
  const float* b1  = (const float*)d_in[5];
  const float* w2  = (const float*)d_in[6];
  const float* b2  = (const float*)d_in[7];
  const float* wt  = (const float*)d_in[8];
  const float* bt  = (const float*)d_in[9];
  float* out = (float*)d_out;

  (void)hipFuncSetAttribute((const void*)gemm8p<0>,
                            hipFuncAttributeMaxDynamicSharedMemorySize, 131072);
  (void)hipFuncSetAttribute((const void*)gemm8p<1>,
                            hipFuncAttributeMaxDynamicSharedMemorySize, 131072);
  (void)hipFuncSetAttribute((const void*)gemmRC<0>,
                            hipFuncAttributeMaxDynamicSharedMemorySize, 73728);
  constexpr unsigned DSM8 = 131072, DSMR = 73728;

  const size_t B_f16T   = 2UL*784*1024*2;
  const size_t B_w1b    = 512UL*1024*2;
  const size_t B_w2R    = 64UL*4608*2;
  const size_t B_out1P  = 2UL*900*512*2;
  const size_t B_qkT    = 2UL*784*64*2;
  const size_t B_concat = 6UL*900*768*2;
  const size_t B_wtR    = 768UL*6912*2;
  const size_t B_mkT    = 2UL*12544*64*2;
  const size_t B_logaff = 2UL*784*12544*2;
  const size_t B_mvb    = 38535168UL*2;
  auto al = [](size_t x) { return (x + 255) & ~(size_t)255; };
  auto pad8 = [](int n) { return (n + 7) & ~7; };

  const size_t phase1 = al(B_f16T) + al(B_w1b) + al(B_w2R) + al(B_out1P) + al(B_qkT);
  const size_t regionA = phase1 > al(B_concat) ? phase1 : al(B_concat);

  const int S_ro = 5, S_tr = 4, S_c1 = 8;
  const int Kc_ro = 2560;                 // 4x2560 + tail 2304 (all mult 64)
  const int Kc_tr = 1728;                 // 4x1728 = 6912 exact
  auto poolBytes = [&]() -> size_t {
    size_t p2 = 18UL*64*1568*4;                       // conv2 fp32
    size_t p1 = (size_t)S_c1*1568*512*2;              // conv1 bf16
    size_t pr = (size_t)(2*S_ro)*1536*784*2;          // readout bf16
    size_t pt = (size_t)S_tr*768*4704*2;              // transform bf16
    size_t m = p2; if (p1 > m) m = p1; if (pr > m) m = pr; if (pt > m) m = pt;
    return m;
  };
  const size_t fixed = regionA + al(B_wtR) + al(B_mkT) + al(B_logaff) + al(B_mvb);
  if (fixed + poolBytes() > ws_size) {
    fill_sentinel<<<4704, 256, 0, stream>>>(out, (long)out_size);
    return;
  }

  char* base = (char*)d_ws;
  size_t off = 0;
  auto alloc = [&](size_t bytes) -> char* { char* p = base + off; off += al(bytes); return p; };
  char* rA = alloc(regionA);
  u16* f16T   = (u16*)rA;
  u16* w1b    = (u16*)(rA + al(B_f16T));
  u16* w2R    = (u16*)(rA + al(B_f16T) + al(B_w1b));
  u16* out1P  = (u16*)(rA + al(B_f16T) + al(B_w1b) + al(B_w2R));
  u16* qkT    = (u16*)(rA + al(B_f16T) + al(B_w1b) + al(B_w2R) + al(B_out1P));
  u16* concatP = (u16*)rA;   // overlays phase-1 buffers (dead by then)
  u16*   wtR     = (u16*)alloc(B_wtR);
  u16*   mkT     = (u16*)alloc(B_mkT);
  u16*   logaff  = (u16*)alloc(B_logaff);
  u16*   mvb     = (u16*)alloc(B_mvb);
  char*  partsRaw = alloc(poolBytes());
  float* partsF  = (float*)partsRaw;
  u16*   partsH  = (u16*)partsRaw;

  // ---- zero padded conv1 image (borders must stay 0) ----
  zfill<<<512, 256, 0, stream>>>((u32*)out1P, (long)(B_out1P / 4));

  // ---- operand prep ----
  convert_bf<<<256, 256, 0, stream>>>(w1, w1b, 65536);
  permute_w<<<1152, 256, 0, stream>>>(w2, w2R, 64, 512);
  permute_w<<<20736, 256, 0, stream>>>(wt, wtR, 768, 768);
  transpose_bf<<<dim3(25, 32, 2), 256, 0, stream>>>(f16, f16T, 1024, 784, 784L*1024, 1024, 0);
  transpose_bf<<<dim3(392, 2, 2), 256, 0, stream>>>(mk, mkT, 64, 12544, 12544L*64, 64, 0);
  convert_bf<<<18816, 256, 0, stream>>>(mv, mvb, 4816896);

  // ---- conv1 (1x1): gemmRC split-K S=8, bf16 partials, fused-bias reduce ----
  {
    const int nwg = 7 * 4 * S_c1;        // gx=7 (M=1568), gy=4 (N=512)
    gemmRC<0><<<pad8(nwg), 512, DSMR, stream>>>(
        f16T, w1b, partsH, 1568, 512, 1024 / S_c1, 1024, S_c1,
        0, 0, 1568L*512, 0, 7, 4, nwg);
  }
  reduce_c1_bf<<<784, 256, 0, stream>>>(partsH, out1P, b1, S_c1);

  // ---- conv2 (3x3 implicit 128-tile): M=64, Cin=512, Ntot=1568, S=18 ----
  conv_glds<<<dim3(1, 13, 18), 256, 0, stream>>>(w2R, out1P, partsF, 64, 512, 1568, 256);
  reduceT_qk<<<dim3(2, 25, 2), 256, 0, stream>>>(partsF, qkT, b2, 18);

  // ---- logits: M=784, N=12544, K=64 -> bf16, scale 1/8 ----
  gemm_glds<64><<<dim3(7, 98, 2), 256, 0, stream>>>(
      qkT, mkT, logaff, 784, 12544, 64, 64, 1,
      784L*64, 12544L*64, 784L*12544, 0.125f);

  // ---- softmax over memory axis (single-pass, reg-resident) ----
  softmax_inplace<<<1568, 256, 0, stream>>>(logaff);

  // ---- zero concat image, fill h channels ----
  zfill<<<2048, 256, 0, stream>>>((u32*)concatP, (long)(B_concat / 4));
  transT_h<<<dim3(8, 25, 6), 256, 0, stream>>>(hin, concatP);

  // ---- readout (8-phase): A=mvb[1536][12544], B=logaff[784][12544] ----
  {
    const int nwg = 6 * 4 * 2 * S_ro;    // gx=6 (M=1536), gy=4 (N 784->1024), z=10
    gemm8p<0><<<pad8(nwg), 512, DSM8, stream>>>(
        mvb, logaff, partsH, 1536, 784, Kc_ro, 12544, S_ro,
        1536L*12544, 784L*12544, 1536L*784, 0, 6, 4, nwg);
  }
  reduceT_ro<<<dim3(48, 25, 2), 256, 0, stream>>>(partsH, concatP, S_ro);

  // ---- transform conv (8-phase): A=wtR[768][6912], B=concatP pixels ----
  {
    const int nwg = 3 * 19 * S_tr;       // gx=3 (M=768), gy=19 (N 4704->4864)
    gemm8p<1><<<pad8(nwg), 512, DSM8, stream>>>(
        wtR, concatP, partsH, 768, 4704, Kc_tr, 6912, S_tr,
        0, 0, 768L*4704, 768, 3, 19, nwg);
  }

  // ---- fused reduce + gating -> d_out ----
  treduce_gate<<<1176, 256, 0, stream>>>(partsH, bt, hin, out, S_tr);
}

// Round 12
// 305.764 us; speedup vs baseline: 1.3034x; 1.0618x over previous
//
#include <hip/hip_runtime.h>

typedef unsigned short u16;
typedef unsigned int u32;
typedef float f32x4v __attribute__((ext_vector_type(4)));
typedef __bf16 bf16x8 __attribute__((ext_vector_type(8)));

#define GAS __attribute__((address_space(1)))
#define LAS __attribute__((address_space(3)))

__device__ __forceinline__ u16 f2bf(float f) {
  u32 u = __builtin_bit_cast(u32, f);
  u32 r = (u + 0x7FFFu + ((u >> 16) & 1u)) >> 16;  // RNE
  return (u16)r;
}
__device__ __forceinline__ float bf2f(u16 h) {
  return __builtin_bit_cast(float, (u32)h << 16);
}
__device__ __forceinline__ void gld_lds16(const void* g, void* l) {
  __builtin_amdgcn_global_load_lds((const GAS void*)g, (LAS void*)l, 16, 0, 0);
}
#define VMCNT(N) asm volatile("s_waitcnt vmcnt(" #N ")" ::: "memory")
#define MFMA16(a, b, c) __builtin_amdgcn_mfma_f32_16x16x32_bf16((a), (b), (c), 0, 0, 0)

// ---------------------------------------------------------------------------
// 8-PHASE 256x256 MFMA GEMM device body (m201 structure). BK=64 K-tiles;
// 512 thr / 8 waves (2M x 4N), per-wave 128x64, acc 8x4. 128 KB LDS.
// Per K-tile tau, 4 phases: {ds_read A-quadrant (Q0 also all B frags->regs);
// stage ONE half-tile; Q3: vmcnt(4); barrier; setprio+16 MFMA; barrier}.
// Bank-conflict-free chunk rotation both-sides. XCD-chunked 1D remap over the
// gemm segment (Gpad blocks). BF16 partials (fp32 accum). Tail clamp restage.
// CONV=1: B rows = pixels of zero-padded channel-last stack [nImg][900][Cin].
// ---------------------------------------------------------------------------
template <int CONV>
__device__ __forceinline__ void gemm8p_dev(
    int lb, int Gpad, const u16* A, const u16* B, u16* Cp,
    int M, int N, int Kc, int fullK, int S,
    long strA, long strB, long strC, int Cin, int gx, int gy, int nwg, u16* smem)
{
  const int cpx = Gpad >> 3;
  const int L = (lb & 7) * cpx + (lb >> 3);
  if (L >= nwg) return;
  const int by = L % gy;
  const int rest = L / gy;
  const int bx = rest % gx;
  const int z = rest / gx;

  const int t = threadIdx.x, lane = t & 63, wave = t >> 6;
  const int zb = z / S, s = z - zb * S;
  const int m0 = bx * 256, n0 = by * 256;
  const int kbeg = s * Kc;
  const int kavail = fullK - kbeg;
  const int kc = Kc < kavail ? Kc : kavail;
  const int T = kc >> 6;

  const int srow = t >> 3;
  const int g = ((t & 7) - (srow & 7)) & 7;
  const int ldsoff = t * 8;

  const u16* Asrc[2][2];
  #pragma unroll
  for (int h = 0; h < 2; ++h)
    #pragma unroll
    for (int q = 0; q < 2; ++q) {
      int r = m0 + h * 128 + q * 64 + srow; if (r >= M) r = M - 1;
      Asrc[h][q] = A + (long)zb * strA + (long)r * fullK + kbeg + g * 8;
    }
  const u16* Bsrc[2][2];
  #pragma unroll
  for (int h = 0; h < 2; ++h)
    #pragma unroll
    for (int q = 0; q < 2; ++q) {
      if constexpr (CONV) {
        int pn = n0 + h * 128 + q * 64 + srow; if (pn >= N) pn = 0;
        const int img = pn / 784, p = pn - img * 784;
        const int py = p / 28, px = p - py * 28;
        Bsrc[h][q] = B + ((long)img * 900 + (py + 1) * 30 + (px + 1)) * Cin + g * 8;
      } else {
        int r = n0 + h * 128 + q * 64 + srow; if (r >= N) r = N - 1;
        Bsrc[h][q] = B + (long)zb * strB + (long)r * fullK + kbeg + g * 8;
      }
    }

  auto stageA = [&](int tile, int h) {
    u16* d = smem + (((tile & 1) * 2 + h) * 8192);
    const long ko = (long)tile * 64;
    gld_lds16(Asrc[h][0] + ko, d + ldsoff);
    gld_lds16(Asrc[h][1] + ko, d + 4096 + ldsoff);
  };
  auto stageB = [&](int tile, int h) {
    u16* d = smem + 32768 + (((tile & 1) * 2 + h) * 8192);
    long off;
    if constexpr (CONV) {
      const int kg = kbeg + tile * 64;
      const int tap = kg / Cin, kc2 = kg - tap * Cin;
      off = (long)((tap / 3 - 1) * 30 + (tap % 3 - 1)) * Cin + kc2;
    } else {
      off = (long)tile * 64;
    }
    gld_lds16(Bsrc[h][0] + off, d + ldsoff);
    gld_lds16(Bsrc[h][1] + off, d + 4096 + ldsoff);
  };

  const int wm = wave & 1, wn = wave >> 1;
  const int lr = lane & 15, hi = lane >> 4;
  const int slot0 = ((hi + (lr & 7)) & 7) * 8;
  const int slot1 = (((hi + 4) + (lr & 7)) & 7) * 8;
  f32x4v acc[8][4] = {};
  bf16x8 breg[4][2];

  stageB(0, 0); stageB(0, 1);
  stageA(0, 0); stageA(0, 1);
  stageB(1, 0); stageB(1, 1);
  VMCNT(4);
  __builtin_amdgcn_s_barrier();

  for (int tau = 0; tau < T; ++tau) {
    const int d = tau & 1;
    const u16* aB = smem + ((d * 2 + wm) * 8192);
    const u16* bB = smem + 32768 + ((d * 2 + (wn >> 1)) * 8192);
    const int ta = (tau + 1 < T) ? tau + 1 : T - 1;
    const int tb = (tau + 2 < T) ? tau + 2 : T - 1;
    #pragma unroll
    for (int Q = 0; Q < 4; ++Q) {
      bf16x8 aph[2][2];
      #pragma unroll
      for (int m2 = 0; m2 < 2; ++m2) {
        const int lrow = (Q * 2 + m2) * 16 + lr;
        aph[m2][0] = *(const bf16x8*)&aB[lrow * 64 + slot0];
        aph[m2][1] = *(const bf16x8*)&aB[lrow * 64 + slot1];
      }
      if (Q == 0) {
        #pragma unroll
        for (int n = 0; n < 4; ++n) {
          const int lrow = (wn & 1) * 64 + n * 16 + lr;
          breg[n][0] = *(const bf16x8*)&bB[lrow * 64 + slot0];
          breg[n][1] = *(const bf16x8*)&bB[lrow * 64 + slot1];
        }
      }
      if      (Q == 0) stageA(ta, 0);
      else if (Q == 1) stageA(ta, 1);
      else if (Q == 2) stageB(tb, 0);
      else             { stageB(tb, 1); VMCNT(4); }
      __builtin_amdgcn_sched_barrier(0);
      __builtin_amdgcn_s_barrier();
      __builtin_amdgcn_s_setprio(1);
      #pragma unroll
      for (int m2 = 0; m2 < 2; ++m2)
        #pragma unroll
        for (int n = 0; n < 4; ++n) {
          acc[Q * 2 + m2][n] = MFMA16(aph[m2][0], breg[n][0], acc[Q * 2 + m2][n]);
          acc[Q * 2 + m2][n] = MFMA16(aph[m2][1], breg[n][1], acc[Q * 2 + m2][n]);
        }
      __builtin_amdgcn_s_setprio(0);
      __builtin_amdgcn_sched_barrier(0);
      __builtin_amdgcn_s_barrier();
    }
  }
  VMCNT(0);

  u16* Co = Cp + (long)z * strC;
  #pragma unroll
  for (int m = 0; m < 8; ++m)
    #pragma unroll
    for (int r = 0; r < 4; ++r) {
      const int row = m0 + wm * 128 + m * 16 + hi * 4 + r;
      if (row >= M) continue;
      #pragma unroll
      for (int n = 0; n < 4; ++n) {
        const int col = n0 + wn * 64 + n * 16 + lr;
        if (col < N) Co[(long)row * N + col] = f2bf(acc[m][n][r]);
      }
    }
}

// ---------------------------------------------------------------------------
// 256x128 gemmRC device body (conv1): BK=32 depth-3 circular, vmcnt(6),
// 72 KB LDS, bf16 partials, XCD-chunked remap over Gpad segment.
// ---------------------------------------------------------------------------
__device__ __forceinline__ void gemmRC_dev(
    int lb, int Gpad, const u16* A, const u16* B, u16* Cp,
    int M, int N, int Kc, int fullK, int S,
    long strA, long strB, long strC, int gx, int gy, int nwg, u16* smem)
{
  const int cpx = Gpad >> 3;
  const int L = (lb & 7) * cpx + (lb >> 3);
  if (L >= nwg) return;
  const int by = L % gy;
  const int rest = L / gy;
  const int bx = rest % gx;
  const int z = rest / gx;

  u16* sA = smem;
  u16* sB = smem + 3 * 8192;
  const int t = threadIdx.x, lane = t & 63, wave = t >> 6;
  const int zb = z / S, s = z - zb * S;
  const int m0 = bx * 256, n0 = by * 128;
  const int kbeg = s * Kc;
  const int niter = Kc >> 5;

  const int schunk = ((t & 3) ^ ((t >> 4) & 3)) * 8;
  const u16* Ap[2]; const u16* Bp;
  #pragma unroll
  for (int q = 0; q < 2; ++q) {
    int ra = m0 + q * 128 + (t >> 2); if (ra >= M) ra = M - 1;
    Ap[q] = A + (long)zb * strA + (long)ra * fullK + schunk;
  }
  {
    int rb = n0 + (t >> 2); if (rb >= N) rb = N - 1;
    Bp = B + (long)zb * strB + (long)rb * fullK + schunk;
  }
  const int ldst = t * 8;

  auto stage = [&](int buf, int kg) {
    u16* dA = sA + buf * 8192;
    gld_lds16(Ap[0] + kg, &dA[ldst]);
    gld_lds16(Ap[1] + kg, &dA[4096 + ldst]);
    gld_lds16(Bp + kg,    &sB[buf * 4096 + ldst]);
  };

  const int wrow = (wave & 3) * 64, wcol = (wave >> 2) * 64;
  const int lr = lane & 15, hi = lane >> 4;
  const int csw = (hi ^ (lr >> 2)) * 8;
  f32x4v acc[4][4] = {};

  for (int p = 0; p < 2 && p < niter; ++p) stage(p, kbeg + p * 32);
  int cur = 0, nxt = 2;
  for (int it = 0; it < niter; ++it) {
    if (it + 2 < niter) {
      stage(nxt, kbeg + (it + 2) * 32);
      VMCNT(6);
    } else {
      const int rem = niter - 1 - it;
      if (rem == 1) VMCNT(3); else VMCNT(0);
    }
    __builtin_amdgcn_s_barrier();
    __builtin_amdgcn_sched_barrier(0);
    const u16* cA = sA + cur * 8192;
    const u16* cB = sB + cur * 4096;
    bf16x8 af[4], bf[4];
    #pragma unroll
    for (int m = 0; m < 4; ++m) af[m] = *(const bf16x8*)&cA[(wrow + m*16 + lr) * 32 + csw];
    #pragma unroll
    for (int n = 0; n < 4; ++n) bf[n] = *(const bf16x8*)&cB[(wcol + n*16 + lr) * 32 + csw];
    __builtin_amdgcn_s_setprio(1);
    #pragma unroll
    for (int m = 0; m < 4; ++m)
      #pragma unroll
      for (int n = 0; n < 4; ++n)
        acc[m][n] = MFMA16(af[m], bf[n], acc[m][n]);
    __builtin_amdgcn_s_setprio(0);
    __builtin_amdgcn_sched_barrier(0);
    __builtin_amdgcn_s_barrier();
    cur = (cur + 1 == 3) ? 0 : cur + 1;
    nxt = (nxt + 1 == 3) ? 0 : nxt + 1;
  }

  u16* Co = Cp + (long)z * strC;
  const int lq = hi * 4;
  #pragma unroll
  for (int m = 0; m < 4; ++m)
    #pragma unroll
    for (int r = 0; r < 4; ++r) {
      const int row = m0 + wrow + m * 16 + lq + r;
      if (row >= M) continue;
      #pragma unroll
      for (int n = 0; n < 4; ++n) {
        const int col = n0 + wcol + n * 16 + lr;
        if (col < N) Co[(long)row * N + col] = f2bf(acc[m][n][r]);
      }
    }
}

// ---------------------------------------------------------------------------
// Border slot id -> (py,px) in 30x30 frame (116 border slots)
// ---------------------------------------------------------------------------
__device__ __forceinline__ void border_slot(int slot, int& py, int& px) {
  if (slot < 30)      { py = 0;         px = slot; }
  else if (slot < 60) { py = 29;        px = slot - 30; }
  else if (slot < 88) { py = slot - 59; px = 0; }
  else                { py = slot - 87; px = 29; }
}

// ---------------------------------------------------------------------------
// prep1 (256t): f16 transpose + mk transpose + w1 convert
// ---------------------------------------------------------------------------
__device__ __forceinline__ void transp_dev(
    const float* in, u16* out, int R, int C, int ldOut,
    int bx, int by, int t, float (*tile)[33])
{
  const int c0 = bx * 32, r0 = by * 32;
  const int tx = t & 31, ty = t >> 5;
  for (int i = ty; i < 32; i += 8) {
    const int r = r0 + i, c = c0 + tx;
    tile[i][tx] = (r < R && c < C) ? in[(long)r * C + c] : 0.0f;
  }
  __syncthreads();
  for (int i = ty; i < 32; i += 8) {
    const int r = r0 + tx, c = c0 + i;
    if (c < C && r < R)
      out[(long)c * ldOut + r] = f2bf(tile[tx][i]);
  }
}

__global__ __launch_bounds__(256) void prep1(
    const float* __restrict__ f16, const float* __restrict__ mk,
    const float* __restrict__ w1,
    u16* __restrict__ f16T, u16* __restrict__ mkT, u16* __restrict__ w1b)
{
  __shared__ float tile[32][33];
  const int bid = blockIdx.x, t = threadIdx.x;
  if (bid < 1600) {                    // f16T: (25,32,2)
    const int bx = bid % 25, by = (bid / 25) % 32, bz = bid / 800;
    transp_dev(f16 + (long)bz * 1024 * 784, f16T + (long)bz * 784 * 1024,
               1024, 784, 1024, bx, by, t, tile);
    return;
  }
  if (bid < 3168) {                    // mkT: (392,2,2)
    const int lb = bid - 1600;
    const int bx = lb % 392, by = (lb / 392) % 2, bz = lb / 784;
    transp_dev(mk + (long)bz * 64 * 12544, mkT + (long)bz * 12544 * 64,
               64, 12544, 64, bx, by, t, tile);
    return;
  }
  const long i = (long)(bid - 3168) * 256 + t;   // w1b: 65536 groups
  const float4* p = (const float4*)w1 + i * 2;
  const float4 a = p[0], b = p[1];
  u16 o[8] = {f2bf(a.x), f2bf(a.y), f2bf(a.z), f2bf(a.w),
              f2bf(b.x), f2bf(b.y), f2bf(b.z), f2bf(b.w)};
  ((uint4*)w1b)[i] = *(uint4*)o;
}

// ---------------------------------------------------------------------------
// fused1 (512t, 72 KB dyn): conv1-gemmRC + mv convert + w2R + wtR + out1P borders
// segments: [0,224) gemm | [224,4928) mv | [4928,5504) w2R | [5504,15872) wtR
//           | [15872,15901) borders
// ---------------------------------------------------------------------------
__global__ __launch_bounds__(512, 4) void fused1(
    const u16* __restrict__ f16T, const u16* __restrict__ w1b, u16* __restrict__ parts,
    const float* __restrict__ mv, u16* __restrict__ mvb,
    const float* __restrict__ w2, u16* __restrict__ w2R,
    const float* __restrict__ wt, u16* __restrict__ wtR,
    u16* __restrict__ out1P)
{
  extern __shared__ u16 smem[];
  const int bid = blockIdx.x, t = threadIdx.x;
  if (bid < 224) {   // conv1: M=1568 N=512 K=1024 S=8, gx=7 gy=4, 224=8x28
    gemmRC_dev(bid, 224, f16T, w1b, parts, 1568, 512, 128, 1024, 8,
               0, 0, 1568L * 512, 7, 4, 224, smem);
    return;
  }
  int lb = bid - 224;
  if (lb < 4704) {   // mv convert: 4816896 uint4-groups, 2/thread
    const long g0 = (long)lb * 1024 + t;
    #pragma unroll
    for (int k = 0; k < 2; ++k) {
      const long g = g0 + k * 512;
      const float4* p = (const float4*)mv + g * 2;
      const float4 a = p[0], b = p[1];
      u16 o[8] = {f2bf(a.x), f2bf(a.y), f2bf(a.z), f2bf(a.w),
                  f2bf(b.x), f2bf(b.y), f2bf(b.z), f2bf(b.w)};
      ((uint4*)mvb)[g] = *(uint4*)o;
    }
    return;
  }
  lb -= 4704;
  if (lb < 576) {    // w2R permute: dst[m][tap][c] = src[m][c][tap], 294912
    const int idx = lb * 512 + t;
    const int c = idx % 512, tap = (idx / 512) % 9, m = idx / 4608;
    w2R[idx] = f2bf(w2[((long)m * 512 + c) * 9 + tap]);
    return;
  }
  lb -= 576;
  if (lb < 10368) {  // wtR permute: 5308416
    const long idx = (long)lb * 512 + t;
    const int c = (int)(idx % 768), tap = (int)((idx / 768) % 9), m = (int)(idx / 6912);
    wtR[idx] = f2bf(wt[((long)m * 768 + c) * 9 + tap]);
    return;
  }
  lb -= 10368;       // out1P borders: 2 img x 116 slots x 64 uint4 = 14848
  const int gid = lb * 512 + t;
  if (gid < 14848) {
    const int c8 = gid & 63, rest = gid >> 6;
    const int slot = rest % 116, img = rest / 116;
    int py, px; border_slot(slot, py, px);
    *(uint4*)&out1P[((long)img * 900 + py * 30 + px) * 512 + c8 * 8] =
        make_uint4(0, 0, 0, 0);
  }
}

// ---------------------------------------------------------------------------
// 128x128 glds GEMM (logits). Counted-vmcnt depth-1, BK=64 rotation swizzle.
// ---------------------------------------------------------------------------
template <int BK>
__global__ __launch_bounds__(256) void gemm_glds(
    const u16* __restrict__ A, const u16* __restrict__ B, u16* __restrict__ C,
    int M, int N, int Kc, int fullK, int S,
    long strA, long strB, long strC, float scale)
{
  constexpr int CPR = BK / 8;
  constexpr int ISS = BK / 16;
  __shared__ u16 sA[2][128 * BK];
  __shared__ u16 sB[2][128 * BK];
  const int t = threadIdx.x, lane = t & 63, wave = t >> 6;
  const int z = blockIdx.z, zb = z / S;
  const int m0 = blockIdx.x * 128, n0 = blockIdx.y * 128;
  const int kbeg = (z - zb * S) * Kc;

  const u16* Aptr[ISS]; const u16* Bptr[ISS]; int lofs[ISS];
  #pragma unroll
  for (int i = 0; i < ISS; ++i) {
    const int tp = i * 256 + t;
    const int r = tp / CPR;
    int c16 = tp % CPR;
    if constexpr (BK == 32) c16 = c16 ^ ((tp >> 4) & 3);
    else                    c16 = (c16 - (r & 7)) & 7;
    int ra = m0 + r; if (ra >= M) ra = M - 1;
    int rb = n0 + r; if (rb >= N) rb = N - 1;
    Aptr[i] = A + (long)zb * strA + (long)ra * fullK + kbeg + c16 * 8;
    Bptr[i] = B + (long)zb * strB + (long)rb * fullK + kbeg + c16 * 8;
    lofs[i] = (i * 256 + (wave << 6)) * 8;
  }
  auto stage = [&](int buf, int k0) {
    #pragma unroll
    for (int i = 0; i < ISS; ++i) {
      gld_lds16(Aptr[i] + k0, &sA[buf][lofs[i]]);
      gld_lds16(Bptr[i] + k0, &sB[buf][lofs[i]]);
    }
  };

  const int wr = (wave >> 1) * 64, wc = (wave & 1) * 64;
  const int lr = lane & 15, hi = lane >> 4;
  f32x4v acc[4][4] = {};
  const int niter = Kc / BK;

  stage(0, 0);
  for (int it = 0; it < niter; ++it) {
    const int cur = it & 1;
    if (it + 1 < niter) {
      stage(cur ^ 1, (it + 1) * BK);
      if constexpr (ISS == 2) VMCNT(4); else VMCNT(8);
    } else {
      VMCNT(0);
    }
    __builtin_amdgcn_s_barrier();
    __builtin_amdgcn_sched_barrier(0);
    #pragma unroll
    for (int kk = 0; kk < BK; kk += 32) {
      bf16x8 af[4], bv[4];
      #pragma unroll
      for (int i = 0; i < 4; ++i) {
        const int row = wr + i*16 + lr;
        int lk;
        if constexpr (BK == 32) lk = kk + ((hi ^ (lr >> 2)) * 8);
        else                    lk = ((((kk >> 3) + hi) + (row & 7)) & 7) * 8;
        af[i] = *(const bf16x8*)&sA[cur][row * BK + lk];
      }
      #pragma unroll
      for (int j = 0; j < 4; ++j) {
        const int row = wc + j*16 + lr;
        int lk;
        if constexpr (BK == 32) lk = kk + ((hi ^ (lr >> 2)) * 8);
        else                    lk = ((((kk >> 3) + hi) + (row & 7)) & 7) * 8;
        bv[j] = *(const bf16x8*)&sB[cur][row * BK + lk];
      }
      __builtin_amdgcn_s_setprio(1);
      #pragma unroll
      for (int i = 0; i < 4; ++i)
        #pragma unroll
        for (int j = 0; j < 4; ++j)
          acc[i][j] = MFMA16(af[i], bv[j], acc[i][j]);
      __builtin_amdgcn_s_setprio(0);
    }
    __builtin_amdgcn_sched_barrier(0);
    __builtin_amdgcn_s_barrier();
  }

  const int lq = hi * 4;
  u16* Cw = C + (long)zb * strC;
  #pragma unroll
  for (int i = 0; i < 4; ++i)
    #pragma unroll
    for (int r = 0; r < 4; ++r) {
      const int row = m0 + wr + i*16 + lq + r;
      if (row >= M) continue;
      #pragma unroll
      for (int j = 0; j < 4; ++j) {
        const int col = n0 + wc + j*16 + lr;
        if (col < N) Cw[(long)row * N + col] = f2bf(acc[i][j][r] * scale);
      }
    }
}

// ---------------------------------------------------------------------------
// 128x128 implicit-conv (conv2: M=64). fp32 partials.
// ---------------------------------------------------------------------------
__global__ __launch_bounds__(256) void conv_glds(
    const u16* __restrict__ Wt, const u16* __restrict__ imgP,
    float* __restrict__ Cp, int M, int Cin, int Ntot, int Kc)
{
  __shared__ u16 sA[2][128 * 32];
  __shared__ u16 sB[2][128 * 32];
  const int t = threadIdx.x, lane = t & 63, wave = t >> 6;
  const int z = blockIdx.z;
  const int m0 = blockIdx.x * 128, n0 = blockIdx.y * 128;
  const int kbeg = z * Kc;

  const u16* Aptr[2]; const u16* Bptr[2]; int lofs[2];
  #pragma unroll
  for (int i = 0; i < 2; ++i) {
    const int tp = i * 256 + t;
    const int r = tp >> 2;
    const int c16 = (tp & 3) ^ ((tp >> 4) & 3);
    int ra = m0 + r; if (ra >= M) ra = M - 1;
    int pn = n0 + r; if (pn >= Ntot) pn = 0;
    const int img = pn / 784, p = pn - img * 784;
    const int py = p / 28, px = p - py * 28;
    Aptr[i] = Wt + (long)ra * (9 * Cin) + c16 * 8;
    Bptr[i] = imgP + ((long)img * 900 + (py + 1) * 30 + (px + 1)) * Cin + c16 * 8;
    lofs[i] = (i * 256 + (wave << 6)) * 8;
  }
  auto stage = [&](int buf, int kg) {
    const int tap = kg / Cin, kc = kg - tap * Cin;
    const long off = (long)((tap / 3 - 1) * 30 + (tap % 3 - 1)) * Cin + kc;
    #pragma unroll
    for (int i = 0; i < 2; ++i) {
      gld_lds16(Aptr[i] + kg, &sA[buf][lofs[i]]);
      gld_lds16(Bptr[i] + off, &sB[buf][lofs[i]]);
    }
  };

  const int wr = (wave >> 1) * 64, wc = (wave & 1) * 64;
  const int lr = lane & 15, hi = lane >> 4;
  const int csw = (hi ^ (lr >> 2)) * 8;
  f32x4v acc[4][4] = {};
  const int niter = Kc >> 5;

  stage(0, kbeg);
  for (int it = 0; it < niter; ++it) {
    const int cur = it & 1;
    if (it + 1 < niter) {
      stage(cur ^ 1, kbeg + (it + 1) * 32);
      VMCNT(4);
    } else {
      VMCNT(0);
    }
    __builtin_amdgcn_s_barrier();
    __builtin_amdgcn_sched_barrier(0);
    bf16x8 af[4], bv[4];
    #pragma unroll
    for (int i = 0; i < 4; ++i) af[i] = *(const bf16x8*)&sA[cur][(wr + i*16 + lr) * 32 + csw];
    #pragma unroll
    for (int j = 0; j < 4; ++j) bv[j] = *(const bf16x8*)&sB[cur][(wc + j*16 + lr) * 32 + csw];
    __builtin_amdgcn_s_setprio(1);
    #pragma unroll
    for (int i = 0; i < 4; ++i)
      #pragma unroll
      for (int j = 0; j < 4; ++j)
        acc[i][j] = MFMA16(af[i], bv[j], acc[i][j]);
    __builtin_amdgcn_s_setprio(0);
    __builtin_amdgcn_sched_barrier(0);
    __builtin_amdgcn_s_barrier();
  }

  float* Co = Cp + (long)z * M * Ntot;
  const int lq = hi * 4;
  #pragma unroll
  for (int i = 0; i < 4; ++i)
    #pragma unroll
    for (int r = 0; r < 4; ++r) {
      const int row = m0 + wr + i*16 + lq + r;
      if (row >= M) continue;
      #pragma unroll
      for (int j = 0; j < 4; ++j) {
        const int col = n0 + wc + j*16 + lr;
        if (col < Ntot) Co[(long)row * Ntot + col] = acc[i][j][r];
      }
    }
}

// ---------------------------------------------------------------------------
// Reduce kernels
// ---------------------------------------------------------------------------
__device__ __forceinline__ void addbf4(float* a, uint2 v) {
  a[0] += bf2f((u16)(v.x & 0xFFFFu));
  a[1] += bf2f((u16)(v.x >> 16));
  a[2] += bf2f((u16)(v.y & 0xFFFFu));
  a[3] += bf2f((u16)(v.y >> 16));
}

__global__ __launch_bounds__(256) void reduce_c1_bf(
    const u16* __restrict__ parts, u16* __restrict__ dst,
    const float* __restrict__ bias, int S)
{
  const long idx = (long)blockIdx.x * 256 + threadIdx.x;
  if (idx >= 1568L * 128) return;
  const int c4 = (int)(idx & 127), p = (int)(idx >> 7);
  const int c = c4 * 4;
  float sum[4] = {bias[c], bias[c+1], bias[c+2], bias[c+3]};
  for (int s = 0; s < S; ++s)
    addbf4(sum, *(const uint2*)&parts[((long)s * 1568 + p) * 512 + c]);
  const int im = p / 784, q = p - im * 784;
  const int qpad = (q / 28 + 1) * 30 + (q % 28 + 1);
  u16 o[4] = {f2bf(sum[0]), f2bf(sum[1]), f2bf(sum[2]), f2bf(sum[3])};
  *(uint2*)&dst[((long)im * 900 + qpad) * 512 + c] = *(uint2*)o;
}

__global__ __launch_bounds__(256) void reduceT_ro(
    const u16* __restrict__ parts, u16* __restrict__ dst, int S)
{
  __shared__ float tile[32][33];
  const int b = blockIdx.z, c0 = blockIdx.x * 32, p0 = blockIdx.y * 32;
  const int tx = threadIdx.x & 31, ty = threadIdx.x >> 5;
  for (int i = ty; i < 32; i += 8) {
    const int pc = min(p0 + tx, 783);
    float s = 0;
    for (int k = 0; k < S; ++k)
      s += bf2f(parts[((long)(b * S + k) * 1536 + c0 + i) * 784 + pc]);
    tile[i][tx] = s;
  }
  __syncthreads();
  for (int i = ty; i < 32; i += 8) {
    const int p = p0 + i, c = c0 + tx;
    if (p < 784) {
      const int n = c >> 9, cc = c & 511;
      const int qpad = (p / 28 + 1) * 30 + (p % 28 + 1);
      dst[((long)(b * 3 + n) * 900 + qpad) * 768 + cc] = f2bf(tile[tx][i]);
    }
  }
}

__global__ __launch_bounds__(256) void reduceT_qk(
    const float* __restrict__ parts, u16* __restrict__ dst,
    const float* __restrict__ bias, int S)
{
  __shared__ float tile[32][33];
  const int b = blockIdx.z, c0 = blockIdx.x * 32, p0 = blockIdx.y * 32;
  const int tx = threadIdx.x & 31, ty = threadIdx.x >> 5;
  for (int i = ty; i < 32; i += 8) {
    const int pc = min(p0 + tx, 783);
    const long base = (long)(c0 + i) * 1568 + b * 784 + pc;
    float s = 0;
    for (int k = 0; k < S; ++k) s += parts[(long)k * 64 * 1568 + base];
    tile[i][tx] = s;
  }
  __syncthreads();
  for (int i = ty; i < 32; i += 8) {
    const int p = p0 + i, c = c0 + tx;
    if (p < 784)
      dst[((long)b * 784 + p) * 64 + c] = f2bf(tile[tx][i] + bias[c]);
  }
}

// ---------------------------------------------------------------------------
// SINGLE-PASS in-place softmax over rows of 12544 bf16 (one block per row)
// ---------------------------------------------------------------------------
__global__ __launch_bounds__(256) void softmax_inplace(u16* __restrict__ buf)
{
  uint4* p4 = (uint4*)(buf + (long)blockIdx.x * 12544);
  const int t = threadIdx.x;
  __shared__ float red[4];
  uint4 v[7];
  float mx = -3.0e38f;
  #pragma unroll
  for (int q = 0; q < 7; ++q) {
    const int idx = t + q * 256;
    if (idx < 1568) {
      v[q] = p4[idx];
      const u32 w[4] = {v[q].x, v[q].y, v[q].z, v[q].w};
      #pragma unroll
      for (int e = 0; e < 4; ++e) {
        mx = fmaxf(mx, bf2f((u16)(w[e] & 0xFFFFu)));
        mx = fmaxf(mx, bf2f((u16)(w[e] >> 16)));
      }
    }
  }
  #pragma unroll
  for (int o = 32; o > 0; o >>= 1) mx = fmaxf(mx, __shfl_xor(mx, o));
  if ((t & 63) == 0) red[t >> 6] = mx;
  __syncthreads();
  mx = fmaxf(fmaxf(red[0], red[1]), fmaxf(red[2], red[3]));

  float s = 0.0f;
  #pragma unroll
  for (int q = 0; q < 7; ++q) {
    const int idx = t + q * 256;
    if (idx < 1568) {
      const u32 w[4] = {v[q].x, v[q].y, v[q].z, v[q].w};
      #pragma unroll
      for (int e = 0; e < 4; ++e) {
        s += __expf(bf2f((u16)(w[e] & 0xFFFFu)) - mx);
        s += __expf(bf2f((u16)(w[e] >> 16)) - mx);
      }
    }
  }
  #pragma unroll
  for (int o = 32; o > 0; o >>= 1) s += __shfl_xor(s, o);
  __syncthreads();
  if ((t & 63) == 0) red[t >> 6] = s;
  __syncthreads();
  const float inv = 1.0f / (red[0] + red[1] + red[2] + red[3]);

  #pragma unroll
  for (int q = 0; q < 7; ++q) {
    const int idx = t + q * 256;
    if (idx < 1568) {
      u32 w[4] = {v[q].x, v[q].y, v[q].z, v[q].w};
      #pragma unroll
      for (int e = 0; e < 4; ++e) {
        const float a = __expf(bf2f((u16)(w[e] & 0xFFFFu)) - mx) * inv;
        const float b = __expf(bf2f((u16)(w[e] >> 16)) - mx) * inv;
        w[e] = (u32)f2bf(a) | ((u32)f2bf(b) << 16);
      }
      p4[idx] = make_uint4(w[0], w[1], w[2], w[3]);
    }
  }
}

// ---------------------------------------------------------------------------
// fused_ro (512t, 128 KB dyn): readout gemm8p + transT_h + concatP borders.
// segments: [0,240) gemm | [240,1440) transT_h | [1440,1571) borders
// ---------------------------------------------------------------------------
__global__ __launch_bounds__(512, 2) void fused_ro(
    const u16* __restrict__ mvb, const u16* __restrict__ logaff,
    u16* __restrict__ parts, const float* __restrict__ hin,
    u16* __restrict__ concatP, int Kc, int S)
{
  extern __shared__ u16 smem[];
  const int bid = blockIdx.x, t = threadIdx.x;
  if (bid < 240) {   // readout: M=1536 N=784 S; gx=6 gy=4, nwg=240=8x30
    gemm8p_dev<0>(bid, 240, mvb, logaff, parts, 1536, 784, Kc, 12544, S,
                  1536L * 12544, 784L * 12544, 1536L * 784, 0, 6, 4, 240, smem);
    return;
  }
  int lb = bid - 240;
  if (lb < 1200) {   // transT_h: hin[img][256][784] -> concatP[img][900][512+c]
    float (*tile)[33] = (float(*)[33])smem;
    const int bx = lb % 8, by = (lb / 8) % 25, zimg = lb / 200;
    const int c0 = bx * 32, p0 = by * 32;
    const int tx = t & 31, ty = t >> 5;   // ty 0..15
    for (int i = ty; i < 32; i += 16) {
      const int pc = min(p0 + tx, 783);
      tile[i][tx] = hin[((long)zimg * 256 + c0 + i) * 784 + pc];
    }
    __syncthreads();
    for (int i = ty; i < 32; i += 16) {
      const int p = p0 + i, c = c0 + tx;
      if (p < 784) {
        const int qpad = (p / 28 + 1) * 30 + (p % 28 + 1);
        concatP[((long)zimg * 900 + qpad) * 768 + 512 + c] = f2bf(tile[tx][i]);
      }
    }
    return;
  }
  lb -= 1200;        // concat borders: 6 img x 116 slots x 96 uint4 = 66816
  const int gid = lb * 512 + t;
  if (gid < 66816) {
    const int c8 = gid % 96, rest = gid / 96;
    const int slot = rest % 116, img = rest / 116;
    int py, px; border_slot(slot, py, px);
    *(uint4*)&concatP[((long)img * 900 + py * 30 + px) * 768 + c8 * 8] =
        make_uint4(0, 0, 0, 0);
  }
}

// transform conv wrapper (8-phase, CONV=1)
__global__ __launch_bounds__(512, 2) void gemm8p_tr(
    const u16* __restrict__ A, const u16* __restrict__ B, u16* __restrict__ Cp,
    int M, int N, int Kc, int fullK, int S,
    long strC, int Cin, int gx, int gy, int nwg)
{
  extern __shared__ u16 smem[];
  gemm8p_dev<1>(blockIdx.x, (int)gridDim.x, A, B, Cp, M, N, Kc, fullK, S,
                0, 0, strC, Cin, gx, gy, nwg, smem);
}

// ---------------------------------------------------------------------------
// Fused transform-reduce + gating. bf16 parts [S][768][4704] (channel-major)
// ---------------------------------------------------------------------------
__global__ __launch_bounds__(256) void treduce_gate(
    const u16* __restrict__ parts, const float* __restrict__ bt,
    const float* __restrict__ h, float* __restrict__ out, int S)
{
  const long i = (long)blockIdx.x * 256 + threadIdx.x;
  if (i >= 6L * 256 * 196) return;
  const int p4 = (int)(i % 196);
  const int rest = (int)(i / 196);
  const int cs = rest % 256, im = rest / 256;
  const long slice = 768L * 4704;
  const long pbase = (long)im * 784 + p4 * 4;
  float F[4] = {}, U[4] = {}, NV[4] = {};
  for (int s = 0; s < S; ++s) {
    const u16* P = parts + (long)s * slice;
    addbf4(F,  *(const uint2*)&P[(long)cs         * 4704 + pbase]);
    addbf4(U,  *(const uint2*)&P[(long)(256 + cs) * 4704 + pbase]);
    addbf4(NV, *(const uint2*)&P[(long)(512 + cs) * 4704 + pbase]);
  }
  const float bF = bt[cs], bU = bt[256 + cs], bN = bt[512 + cs];
  const f32x4v hv = ((const f32x4v*)h)[((long)(im * 256 + cs) * 784 >> 2) + p4];
  f32x4v o;
  #pragma unroll
  for (int q = 0; q < 4; ++q) {
    const float f = F[q] + bF, u = U[q] + bU, nv = NV[q] + bN;
    const float sf = 1.0f / (1.0f + __expf(-f));
    const float su = 1.0f / (1.0f + __expf(-u));
    const float e2 = __expf(2.0f * nv);
    const float tv = (e2 - 1.0f) / (e2 + 1.0f);
    o[q] = sf * hv[q] * (1.0f - su) + su * tv;
  }
  ((f32x4v*)out)[((long)(im * 256 + cs) * 784 >> 2) + p4] = o;
}

__global__ __launch_bounds__(256) void fill_sentinel(float* p, long n) {
  const long i = (long)blockIdx.x * 256 + threadIdx.x;
  if (i < n) p[i] = 12345.0f;
}

// ---------------------------------------------------------------------------
extern "C" void kernel_launch(void* const* d_in, const int* in_sizes, int n_in,
                              void* d_out, int out_size, void* d_ws, size_t ws_size,
                              hipStream_t stream) {
  const float* f16 = (const float*)d_in[0];
  const float* mk  = (const float*)d_in[1];
  const float* mv  = (const float*)d_in[2];
  const float* hin = (const float*)d_in[3];
  const float* w1  = (const float*)d_in[4];
  const float* b1  = (const float*)d_in[5];
  const float* w2  = (const float*)d_in[6];
  const float* b2  = (const float*)d_in[7];
  const float* wt  = (const float*)d_in[8];
  const float* bt  = (const float*)d_in[9];
  float* out = (float*)d_out;

  (void)hipFuncSetAttribute((const void*)fused1,
                            hipFuncAttributeMaxDynamicSharedMemorySize, 73728);
  (void)hipFuncSetAttribute((const void*)fused_ro,
                            hipFuncAttributeMaxDynamicSharedMemorySize, 131072);
  (void)hipFuncSetAttribute((const void*)gemm8p_tr,
                            hipFuncAttributeMaxDynamicSharedMemorySize, 131072);
  constexpr unsigned DSMR = 73728, DSM8 = 131072;

  const size_t B_f16T   = 2UL*784*1024*2;
  const size_t B_w1b    = 512UL*1024*2;
  const size_t B_w2R    = 64UL*4608*2;
  const size_t B_out1P  = 2UL*900*512*2;
  const size_t B_qkT    = 2UL*784*64*2;
  const size_t B_concat = 6UL*900*768*2;
  const size_t B_wtR    = 768UL*6912*2;
  const size_t B_mkT    = 2UL*12544*64*2;
  const size_t B_logaff = 2UL*784*12544*2;
  const size_t B_mvb    = 38535168UL*2;
  auto al = [](size_t x) { return (x + 255) & ~(size_t)255; };

  const size_t phase1 = al(B_f16T) + al(B_w1b) + al(B_w2R) + al(B_out1P) + al(B_qkT);
  const size_t regionA = phase1 > al(B_concat) ? phase1 : al(B_concat);

  const int S_ro = 5, S_tr = 4, S_c1 = 8;
  const int Kc_ro = 2560, Kc_tr = 1728;
  auto poolBytes = [&]() -> size_t {
    size_t p2 = 18UL*64*1568*4;
    size_t p1 = (size_t)S_c1*1568*512*2;
    size_t pr = (size_t)(2*S_ro)*1536*784*2;
    size_t pt = (size_t)S_tr*768*4704*2;
    size_t m = p2; if (p1 > m) m = p1; if (pr > m) m = pr; if (pt > m) m = pt;
    return m;
  };
  const size_t fixed = regionA + al(B_wtR) + al(B_mkT) + al(B_logaff) + al(B_mvb);
  if (fixed + poolBytes() > ws_size) {
    fill_sentinel<<<4704, 256, 0, stream>>>(out, (long)out_size);
    return;
  }

  char* base = (char*)d_ws;
  size_t off = 0;
  auto alloc = [&](size_t bytes) -> char* { char* p = base + off; off += al(bytes); return p; };
  char* rA = alloc(regionA);
  u16* f16T   = (u16*)rA;
  u16* w1b    = (u16*)(rA + al(B_f16T));
  u16* w2R    = (u16*)(rA + al(B_f16T) + al(B_w1b));
  u16* out1P  = (u16*)(rA + al(B_f16T) + al(B_w1b) + al(B_w2R));
  u16* qkT    = (u16*)(rA + al(B_f16T) + al(B_w1b) + al(B_w2R) + al(B_out1P));
  u16* concatP = (u16*)rA;   // overlays phase-1 buffers (all dead before use)
  u16*   wtR     = (u16*)alloc(B_wtR);
  u16*   mkT     = (u16*)alloc(B_mkT);
  u16*   logaff  = (u16*)alloc(B_logaff);
  u16*   mvb     = (u16*)alloc(B_mvb);
  char*  partsRaw = alloc(poolBytes());
  float* partsF  = (float*)partsRaw;
  u16*   partsH  = (u16*)partsRaw;

  // 1) prep: f16T + mkT transposes, w1b convert
  prep1<<<3424, 256, 0, stream>>>(f16, mk, w1, f16T, mkT, w1b);

  // 2) fused: conv1 gemm + mv convert + w2R + wtR + out1P borders
  fused1<<<15901, 512, DSMR, stream>>>(f16T, w1b, partsH, mv, mvb,
                                       w2, w2R, wt, wtR, out1P);

  // 3) conv1 reduce (+bias) -> padded channel-last out1P interior
  reduce_c1_bf<<<784, 256, 0, stream>>>(partsH, out1P, b1, S_c1);

  // 4) conv2 (3x3 implicit): M=64, Cin=512, Ntot=1568, S=18
  conv_glds<<<dim3(1, 13, 18), 256, 0, stream>>>(w2R, out1P, partsF, 64, 512, 1568, 256);

  // 5) conv2 reduce -> qkT
  reduceT_qk<<<dim3(2, 25, 2), 256, 0, stream>>>(partsF, qkT, b2, 18);

  // 6) logits: M=784, N=12544, K=64 -> bf16, scale 1/8
  gemm_glds<64><<<dim3(7, 98, 2), 256, 0, stream>>>(
      qkT, mkT, logaff, 784, 12544, 64, 64, 1,
      784L*64, 12544L*64, 784L*12544, 0.125f);

  // 7) softmax over memory axis
  softmax_inplace<<<1568, 256, 0, stream>>>(logaff);

  // 8) fused: readout gemm8p + transT_h + concatP borders
  fused_ro<<<1571, 512, DSM8, stream>>>(mvb, logaff, partsH, hin, concatP,
                                        Kc_ro, S_ro);

  // 9) readout reduce -> concatP interior ch 0..511
  reduceT_ro<<<dim3(48, 25, 2), 256, 0, stream>>>(partsH, concatP, S_ro);

  // 10) transform conv (8-phase, CONV=1)
  gemm8p_tr<<<232, 512, DSM8, stream>>>(wtR, concatP, partsH,
                                        768, 4704, Kc_tr, 6912, S_tr,
                                        768L*4704, 768, 3, 19, 228);

  // 11) fused reduce + gating -> d_out
  treduce_gate<<<1176, 256, 0, stream>>>(partsH, bt, hin, out, S_tr);
}

// Round 13
// 299.996 us; speedup vs baseline: 1.3285x; 1.0192x over previous
//
#include <hip/hip_runtime.h>

typedef unsigned short u16;
typedef unsigned int u32;
typedef float f32x4v __attribute__((ext_vector_type(4)));
typedef __bf16 bf16x8 __attribute__((ext_vector_type(8)));

#define GAS __attribute__((address_space(1)))
#define LAS __attribute__((address_space(3)))

__device__ __forceinline__ u16 f2bf(float f) {
  u32 u = __builtin_bit_cast(u32, f);
  u32 r = (u + 0x7FFFu + ((u >> 16) & 1u)) >> 16;  // RNE
  return (u16)r;
}
__device__ __forceinline__ float bf2f(u16 h) {
  return __builtin_bit_cast(float, (u32)h << 16);
}
__device__ __forceinline__ void gld_lds16(const void* g, void* l) {
  __builtin_amdgcn_global_load_lds((const GAS void*)g, (LAS void*)l, 16, 0, 0);
}
#define VMCNT(N) asm volatile("s_waitcnt vmcnt(" #N ")" ::: "memory")
#define MFMA16(a, b, c) __builtin_amdgcn_mfma_f32_16x16x32_bf16((a), (b), (c), 0, 0, 0)

// ---------------------------------------------------------------------------
// 8-PHASE 256x256 MFMA GEMM device body (m201 structure). BK=64 K-tiles;
// 512 thr / 8 waves (2M x 4N), per-wave 128x64, acc 8x4. 128 KB LDS.
// Counted vmcnt(4); bank-conflict-free chunk rotation both-sides; XCD-chunked
// remap; BF16 partials (fp32 accum); tail clamp restage.
// CONV=1: B rows = pixels of zero-padded channel-last stack [nImg][900][Cin].
// ---------------------------------------------------------------------------
template <int CONV>
__device__ __forceinline__ void gemm8p_dev(
    int lb, int Gpad, const u16* A, const u16* B, u16* Cp,
    int M, int N, int Kc, int fullK, int S,
    long strA, long strB, long strC, int Cin, int gx, int gy, int nwg, u16* smem)
{
  const int cpx = Gpad >> 3;
  const int L = (lb & 7) * cpx + (lb >> 3);
  if (L >= nwg) return;
  const int by = L % gy;
  const int rest = L / gy;
  const int bx = rest % gx;
  const int z = rest / gx;

  const int t = threadIdx.x, lane = t & 63, wave = t >> 6;
  const int zb = z / S, s = z - zb * S;
  const int m0 = bx * 256, n0 = by * 256;
  const int kbeg = s * Kc;
  const int kavail = fullK - kbeg;
  const int kc = Kc < kavail ? Kc : kavail;
  const int T = kc >> 6;

  const int srow = t >> 3;
  const int g = ((t & 7) - (srow & 7)) & 7;
  const int ldsoff = t * 8;

  const u16* Asrc[2][2];
  #pragma unroll
  for (int h = 0; h < 2; ++h)
    #pragma unroll
    for (int q = 0; q < 2; ++q) {
      int r = m0 + h * 128 + q * 64 + srow; if (r >= M) r = M - 1;
      Asrc[h][q] = A + (long)zb * strA + (long)r * fullK + kbeg + g * 8;
    }
  const u16* Bsrc[2][2];
  #pragma unroll
  for (int h = 0; h < 2; ++h)
    #pragma unroll
    for (int q = 0; q < 2; ++q) {
      if constexpr (CONV) {
        int pn = n0 + h * 128 + q * 64 + srow; if (pn >= N) pn = 0;
        const int img = pn / 784, p = pn - img * 784;
        const int py = p / 28, px = p - py * 28;
        Bsrc[h][q] = B + ((long)img * 900 + (py + 1) * 30 + (px + 1)) * Cin + g * 8;
      } else {
        int r = n0 + h * 128 + q * 64 + srow; if (r >= N) r = N - 1;
        Bsrc[h][q] = B + (long)zb * strB + (long)r * fullK + kbeg + g * 8;
      }
    }

  auto stageA = [&](int tile, int h) {
    u16* d = smem + (((tile & 1) * 2 + h) * 8192);
    const long ko = (long)tile * 64;
    gld_lds16(Asrc[h][0] + ko, d + ldsoff);
    gld_lds16(Asrc[h][1] + ko, d + 4096 + ldsoff);
  };
  auto stageB = [&](int tile, int h) {
    u16* d = smem + 32768 + (((tile & 1) * 2 + h) * 8192);
    long off;
    if constexpr (CONV) {
      const int kg = kbeg + tile * 64;
      const int tap = kg / Cin, kc2 = kg - tap * Cin;
      off = (long)((tap / 3 - 1) * 30 + (tap % 3 - 1)) * Cin + kc2;
    } else {
      off = (long)tile * 64;
    }
    gld_lds16(Bsrc[h][0] + off, d + ldsoff);
    gld_lds16(Bsrc[h][1] + off, d + 4096 + ldsoff);
  };

  const int wm = wave & 1, wn = wave >> 1;
  const int lr = lane & 15, hi = lane >> 4;
  const int slot0 = ((hi + (lr & 7)) & 7) * 8;
  const int slot1 = (((hi + 4) + (lr & 7)) & 7) * 8;
  f32x4v acc[8][4] = {};
  bf16x8 breg[4][2];

  stageB(0, 0); stageB(0, 1);
  stageA(0, 0); stageA(0, 1);
  stageB(1, 0); stageB(1, 1);
  VMCNT(4);
  __builtin_amdgcn_s_barrier();

  for (int tau = 0; tau < T; ++tau) {
    const int d = tau & 1;
    const u16* aB = smem + ((d * 2 + wm) * 8192);
    const u16* bB = smem + 32768 + ((d * 2 + (wn >> 1)) * 8192);
    const int ta = (tau + 1 < T) ? tau + 1 : T - 1;
    const int tb = (tau + 2 < T) ? tau + 2 : T - 1;
    #pragma unroll
    for (int Q = 0; Q < 4; ++Q) {
      bf16x8 aph[2][2];
      #pragma unroll
      for (int m2 = 0; m2 < 2; ++m2) {
        const int lrow = (Q * 2 + m2) * 16 + lr;
        aph[m2][0] = *(const bf16x8*)&aB[lrow * 64 + slot0];
        aph[m2][1] = *(const bf16x8*)&aB[lrow * 64 + slot1];
      }
      if (Q == 0) {
        #pragma unroll
        for (int n = 0; n < 4; ++n) {
          const int lrow = (wn & 1) * 64 + n * 16 + lr;
          breg[n][0] = *(const bf16x8*)&bB[lrow * 64 + slot0];
          breg[n][1] = *(const bf16x8*)&bB[lrow * 64 + slot1];
        }
      }
      if      (Q == 0) stageA(ta, 0);
      else if (Q == 1) stageA(ta, 1);
      else if (Q == 2) stageB(tb, 0);
      else             { stageB(tb, 1); VMCNT(4); }
      __builtin_amdgcn_sched_barrier(0);
      __builtin_amdgcn_s_barrier();
      __builtin_amdgcn_s_setprio(1);
      #pragma unroll
      for (int m2 = 0; m2 < 2; ++m2)
        #pragma unroll
        for (int n = 0; n < 4; ++n) {
          acc[Q * 2 + m2][n] = MFMA16(aph[m2][0], breg[n][0], acc[Q * 2 + m2][n]);
          acc[Q * 2 + m2][n] = MFMA16(aph[m2][1], breg[n][1], acc[Q * 2 + m2][n]);
        }
      __builtin_amdgcn_s_setprio(0);
      __builtin_amdgcn_sched_barrier(0);
      __builtin_amdgcn_s_barrier();
    }
  }
  VMCNT(0);

  u16* Co = Cp + (long)z * strC;
  #pragma unroll
  for (int m = 0; m < 8; ++m)
    #pragma unroll
    for (int r = 0; r < 4; ++r) {
      const int row = m0 + wm * 128 + m * 16 + hi * 4 + r;
      if (row >= M) continue;
      #pragma unroll
      for (int n = 0; n < 4; ++n) {
        const int col = n0 + wn * 64 + n * 16 + lr;
        if (col < N) Co[(long)row * N + col] = f2bf(acc[m][n][r]);
      }
    }
}

// ---------------------------------------------------------------------------
// 256x128 gemmRC device body (conv1): BK=32 depth-3 circular, vmcnt(6),
// 72 KB LDS, bf16 partials, XCD-chunked remap over Gpad segment.
// ---------------------------------------------------------------------------
__device__ __forceinline__ void gemmRC_dev(
    int lb, int Gpad, const u16* A, const u16* B, u16* Cp,
    int M, int N, int Kc, int fullK, int S,
    long strA, long strB, long strC, int gx, int gy, int nwg, u16* smem)
{
  const int cpx = Gpad >> 3;
  const int L = (lb & 7) * cpx + (lb >> 3);
  if (L >= nwg) return;
  const int by = L % gy;
  const int rest = L / gy;
  const int bx = rest % gx;
  const int z = rest / gx;

  u16* sA = smem;
  u16* sB = smem + 3 * 8192;
  const int t = threadIdx.x, lane = t & 63, wave = t >> 6;
  const int zb = z / S, s = z - zb * S;
  const int m0 = bx * 256, n0 = by * 128;
  const int kbeg = s * Kc;
  const int niter = Kc >> 5;

  const int schunk = ((t & 3) ^ ((t >> 4) & 3)) * 8;
  const u16* Ap[2]; const u16* Bp;
  #pragma unroll
  for (int q = 0; q < 2; ++q) {
    int ra = m0 + q * 128 + (t >> 2); if (ra >= M) ra = M - 1;
    Ap[q] = A + (long)zb * strA + (long)ra * fullK + schunk;
  }
  {
    int rb = n0 + (t >> 2); if (rb >= N) rb = N - 1;
    Bp = B + (long)zb * strB + (long)rb * fullK + schunk;
  }
  const int ldst = t * 8;

  auto stage = [&](int buf, int kg) {
    u16* dA = sA + buf * 8192;
    gld_lds16(Ap[0] + kg, &dA[ldst]);
    gld_lds16(Ap[1] + kg, &dA[4096 + ldst]);
    gld_lds16(Bp + kg,    &sB[buf * 4096 + ldst]);
  };

  const int wrow = (wave & 3) * 64, wcol = (wave >> 2) * 64;
  const int lr = lane & 15, hi = lane >> 4;
  const int csw = (hi ^ (lr >> 2)) * 8;
  f32x4v acc[4][4] = {};

  for (int p = 0; p < 2 && p < niter; ++p) stage(p, kbeg + p * 32);
  int cur = 0, nxt = 2;
  for (int it = 0; it < niter; ++it) {
    if (it + 2 < niter) {
      stage(nxt, kbeg + (it + 2) * 32);
      VMCNT(6);
    } else {
      const int rem = niter - 1 - it;
      if (rem == 1) VMCNT(3); else VMCNT(0);
    }
    __builtin_amdgcn_s_barrier();
    __builtin_amdgcn_sched_barrier(0);
    const u16* cA = sA + cur * 8192;
    const u16* cB = sB + cur * 4096;
    bf16x8 af[4], bf[4];
    #pragma unroll
    for (int m = 0; m < 4; ++m) af[m] = *(const bf16x8*)&cA[(wrow + m*16 + lr) * 32 + csw];
    #pragma unroll
    for (int n = 0; n < 4; ++n) bf[n] = *(const bf16x8*)&cB[(wcol + n*16 + lr) * 32 + csw];
    __builtin_amdgcn_s_setprio(1);
    #pragma unroll
    for (int m = 0; m < 4; ++m)
      #pragma unroll
      for (int n = 0; n < 4; ++n)
        acc[m][n] = MFMA16(af[m], bf[n], acc[m][n]);
    __builtin_amdgcn_s_setprio(0);
    __builtin_amdgcn_sched_barrier(0);
    __builtin_amdgcn_s_barrier();
    cur = (cur + 1 == 3) ? 0 : cur + 1;
    nxt = (nxt + 1 == 3) ? 0 : nxt + 1;
  }

  u16* Co = Cp + (long)z * strC;
  const int lq = hi * 4;
  #pragma unroll
  for (int m = 0; m < 4; ++m)
    #pragma unroll
    for (int r = 0; r < 4; ++r) {
      const int row = m0 + wrow + m * 16 + lq + r;
      if (row >= M) continue;
      #pragma unroll
      for (int n = 0; n < 4; ++n) {
        const int col = n0 + wcol + n * 16 + lr;
        if (col < N) Co[(long)row * N + col] = f2bf(acc[m][n][r]);
      }
    }
}

// ---------------------------------------------------------------------------
// Border slot id -> (py,px) in 30x30 frame (116 border slots)
// ---------------------------------------------------------------------------
__device__ __forceinline__ void border_slot(int slot, int& py, int& px) {
  if (slot < 30)      { py = 0;         px = slot; }
  else if (slot < 60) { py = 29;        px = slot - 30; }
  else if (slot < 88) { py = slot - 59; px = 0; }
  else                { py = slot - 87; px = 29; }
}

// ---------------------------------------------------------------------------
// prep1 (256t): f16/mk transposes + w1 convert + w2R/wtR permutes.
// segments: [0,1600) f16T | [1600,3168) mkT | [3168,3424) w1b
//           | [3424,4576) w2R | [4576,25312) wtR
// ---------------------------------------------------------------------------
__device__ __forceinline__ void transp_dev(
    const float* in, u16* out, int R, int C, int ldOut,
    int bx, int by, int t, float (*tile)[33])
{
  const int c0 = bx * 32, r0 = by * 32;
  const int tx = t & 31, ty = t >> 5;
  for (int i = ty; i < 32; i += 8) {
    const int r = r0 + i, c = c0 + tx;
    tile[i][tx] = (r < R && c < C) ? in[(long)r * C + c] : 0.0f;
  }
  __syncthreads();
  for (int i = ty; i < 32; i += 8) {
    const int r = r0 + tx, c = c0 + i;
    if (c < C && r < R)
      out[(long)c * ldOut + r] = f2bf(tile[tx][i]);
  }
}

__global__ __launch_bounds__(256) void prep1(
    const float* __restrict__ f16, const float* __restrict__ mk,
    const float* __restrict__ w1, const float* __restrict__ w2,
    const float* __restrict__ wt,
    u16* __restrict__ f16T, u16* __restrict__ mkT, u16* __restrict__ w1b,
    u16* __restrict__ w2R, u16* __restrict__ wtR)
{
  __shared__ float tile[32][33];
  const int bid = blockIdx.x, t = threadIdx.x;
  if (bid < 1600) {
    const int bx = bid % 25, by = (bid / 25) % 32, bz = bid / 800;
    transp_dev(f16 + (long)bz * 1024 * 784, f16T + (long)bz * 784 * 1024,
               1024, 784, 1024, bx, by, t, tile);
    return;
  }
  if (bid < 3168) {
    const int lb = bid - 1600;
    const int bx = lb % 392, by = (lb / 392) % 2, bz = lb / 784;
    transp_dev(mk + (long)bz * 64 * 12544, mkT + (long)bz * 12544 * 64,
               64, 12544, 64, bx, by, t, tile);
    return;
  }
  if (bid < 3424) {
    const long i = (long)(bid - 3168) * 256 + t;
    const float4* p = (const float4*)w1 + i * 2;
    const float4 a = p[0], b = p[1];
    u16 o[8] = {f2bf(a.x), f2bf(a.y), f2bf(a.z), f2bf(a.w),
                f2bf(b.x), f2bf(b.y), f2bf(b.z), f2bf(b.w)};
    ((uint4*)w1b)[i] = *(uint4*)o;
    return;
  }
  if (bid < 4576) {   // w2R: dst[m][tap][c] = src[m][c][tap]
    const int idx = (bid - 3424) * 256 + t;
    const int c = idx % 512, tap = (idx / 512) % 9, m = idx / 4608;
    w2R[idx] = f2bf(w2[((long)m * 512 + c) * 9 + tap]);
    return;
  }
  const long idx = (long)(bid - 4576) * 256 + t;   // wtR: 5308416
  const int c = (int)(idx % 768), tap = (int)((idx / 768) % 9), m = (int)(idx / 6912);
  wtR[idx] = f2bf(wt[((long)m * 768 + c) * 9 + tap]);
}

// ---------------------------------------------------------------------------
// fused1 (512t, 72 KB dyn): conv1-gemmRC + out1P borders.
// segments: [0,224) gemm | [224,253) borders
// ---------------------------------------------------------------------------
__global__ __launch_bounds__(512, 4) void fused1(
    const u16* __restrict__ f16T, const u16* __restrict__ w1b,
    u16* __restrict__ parts, u16* __restrict__ out1P)
{
  extern __shared__ u16 smem[];
  const int bid = blockIdx.x, t = threadIdx.x;
  if (bid < 224) {
    gemmRC_dev(bid, 224, f16T, w1b, parts, 1568, 512, 128, 1024, 8,
               0, 0, 1568L * 512, 7, 4, 224, smem);
    return;
  }
  const int gid = (bid - 224) * 512 + t;   // out1P borders: 14848
  if (gid < 14848) {
    const int c8 = gid & 63, rest = gid >> 6;
    const int slot = rest % 116, img = rest / 116;
    int py, px; border_slot(slot, py, px);
    *(uint4*)&out1P[((long)img * 900 + py * 30 + px) * 512 + c8 * 8] =
        make_uint4(0, 0, 0, 0);
  }
}

// ---------------------------------------------------------------------------
// conv2_mv (256t, 32 KB static): conv2 implicit-gemm + mv fp32->bf16 convert.
// segments: [0,234) gemm (by=bid%13, z=bid/13) | [234,2282) convert (stride)
// ---------------------------------------------------------------------------
__global__ __launch_bounds__(256) void conv2_mv(
    const u16* __restrict__ Wt, const u16* __restrict__ imgP,
    float* __restrict__ Cp, const float* __restrict__ mv, u16* __restrict__ mvb)
{
  __shared__ u16 sA[2][128 * 32];
  __shared__ u16 sB[2][128 * 32];
  const int bid = blockIdx.x, t = threadIdx.x;
  if (bid >= 234) {   // mv convert: 4816896 uint4-groups, grid-stride
    for (long g = (long)(bid - 234) * 256 + t; g < 4816896L; g += 2048L * 256) {
      const float4* p = (const float4*)mv + g * 2;
      const float4 a = p[0], b = p[1];
      u16 o[8] = {f2bf(a.x), f2bf(a.y), f2bf(a.z), f2bf(a.w),
                  f2bf(b.x), f2bf(b.y), f2bf(b.z), f2bf(b.w)};
      ((uint4*)mvb)[g] = *(uint4*)o;
    }
    return;
  }
  const int lane = t & 63, wave = t >> 6;
  const int z = bid / 13;
  const int m0 = 0, n0 = (bid % 13) * 128;
  const int Cin = 512, Ntot = 1568, M = 64, Kc = 256;
  const int kbeg = z * Kc;

  const u16* Aptr[2]; const u16* Bptr[2]; int lofs[2];
  #pragma unroll
  for (int i = 0; i < 2; ++i) {
    const int tp = i * 256 + t;
    const int r = tp >> 2;
    const int c16 = (tp & 3) ^ ((tp >> 4) & 3);
    int ra = m0 + r; if (ra >= M) ra = M - 1;
    int pn = n0 + r; if (pn >= Ntot) pn = 0;
    const int img = pn / 784, p = pn - img * 784;
    const int py = p / 28, px = p - py * 28;
    Aptr[i] = Wt + (long)ra * (9 * Cin) + c16 * 8;
    Bptr[i] = imgP + ((long)img * 900 + (py + 1) * 30 + (px + 1)) * Cin + c16 * 8;
    lofs[i] = (i * 256 + (wave << 6)) * 8;
  }
  auto stage = [&](int buf, int kg) {
    const int tap = kg / Cin, kc = kg - tap * Cin;
    const long off = (long)((tap / 3 - 1) * 30 + (tap % 3 - 1)) * Cin + kc;
    #pragma unroll
    for (int i = 0; i < 2; ++i) {
      gld_lds16(Aptr[i] + kg, &sA[buf][lofs[i]]);
      gld_lds16(Bptr[i] + off, &sB[buf][lofs[i]]);
    }
  };

  const int wr = (wave >> 1) * 64, wc = (wave & 1) * 64;
  const int lr = lane & 15, hi = lane >> 4;
  const int csw = (hi ^ (lr >> 2)) * 8;
  f32x4v acc[4][4] = {};
  const int niter = Kc >> 5;

  stage(0, kbeg);
  for (int it = 0; it < niter; ++it) {
    const int cur = it & 1;
    if (it + 1 < niter) {
      stage(cur ^ 1, kbeg + (it + 1) * 32);
      VMCNT(4);
    } else {
      VMCNT(0);
    }
    __builtin_amdgcn_s_barrier();
    __builtin_amdgcn_sched_barrier(0);
    bf16x8 af[4], bv[4];
    #pragma unroll
    for (int i = 0; i < 4; ++i) af[i] = *(const bf16x8*)&sA[cur][(wr + i*16 + lr) * 32 + csw];
    #pragma unroll
    for (int j = 0; j < 4; ++j) bv[j] = *(const bf16x8*)&sB[cur][(wc + j*16 + lr) * 32 + csw];
    __builtin_amdgcn_s_setprio(1);
    #pragma unroll
    for (int i = 0; i < 4; ++i)
      #pragma unroll
      for (int j = 0; j < 4; ++j)
        acc[i][j] = MFMA16(af[i], bv[j], acc[i][j]);
    __builtin_amdgcn_s_setprio(0);
    __builtin_amdgcn_sched_barrier(0);
    __builtin_amdgcn_s_barrier();
  }

  float* Co = Cp + (long)z * M * Ntot;
  const int lq = hi * 4;
  #pragma unroll
  for (int i = 0; i < 4; ++i)
    #pragma unroll
    for (int r = 0; r < 4; ++r) {
      const int row = m0 + wr + i*16 + lq + r;
      if (row >= M) continue;
      #pragma unroll
      for (int j = 0; j < 4; ++j) {
        const int col = n0 + wc + j*16 + lr;
        if (col < Ntot) Co[(long)row * Ntot + col] = acc[i][j][r];
      }
    }
}

// ---------------------------------------------------------------------------
// 128x128 glds GEMM (logits). Counted-vmcnt depth-1, BK=64 rotation swizzle.
// ---------------------------------------------------------------------------
template <int BK>
__global__ __launch_bounds__(256) void gemm_glds(
    const u16* __restrict__ A, const u16* __restrict__ B, u16* __restrict__ C,
    int M, int N, int Kc, int fullK, int S,
    long strA, long strB, long strC, float scale)
{
  constexpr int CPR = BK / 8;
  constexpr int ISS = BK / 16;
  __shared__ u16 sA[2][128 * BK];
  __shared__ u16 sB[2][128 * BK];
  const int t = threadIdx.x, lane = t & 63, wave = t >> 6;
  const int z = blockIdx.z, zb = z / S;
  const int m0 = blockIdx.x * 128, n0 = blockIdx.y * 128;
  const int kbeg = (z - zb * S) * Kc;

  const u16* Aptr[ISS]; const u16* Bptr[ISS]; int lofs[ISS];
  #pragma unroll
  for (int i = 0; i < ISS; ++i) {
    const int tp = i * 256 + t;
    const int r = tp / CPR;
    int c16 = tp % CPR;
    if constexpr (BK == 32) c16 = c16 ^ ((tp >> 4) & 3);
    else                    c16 = (c16 - (r & 7)) & 7;
    int ra = m0 + r; if (ra >= M) ra = M - 1;
    int rb = n0 + r; if (rb >= N) rb = N - 1;
    Aptr[i] = A + (long)zb * strA + (long)ra * fullK + kbeg + c16 * 8;
    Bptr[i] = B + (long)zb * strB + (long)rb * fullK + kbeg + c16 * 8;
    lofs[i] = (i * 256 + (wave << 6)) * 8;
  }
  auto stage = [&](int buf, int k0) {
    #pragma unroll
    for (int i = 0; i < ISS; ++i) {
      gld_lds16(Aptr[i] + k0, &sA[buf][lofs[i]]);
      gld_lds16(Bptr[i] + k0, &sB[buf][lofs[i]]);
    }
  };

  const int wr = (wave >> 1) * 64, wc = (wave & 1) * 64;
  const int lr = lane & 15, hi = lane >> 4;
  f32x4v acc[4][4] = {};
  const int niter = Kc / BK;

  stage(0, 0);
  for (int it = 0; it < niter; ++it) {
    const int cur = it & 1;
    if (it + 1 < niter) {
      stage(cur ^ 1, (it + 1) * BK);
      if constexpr (ISS == 2) VMCNT(4); else VMCNT(8);
    } else {
      VMCNT(0);
    }
    __builtin_amdgcn_s_barrier();
    __builtin_amdgcn_sched_barrier(0);
    #pragma unroll
    for (int kk = 0; kk < BK; kk += 32) {
      bf16x8 af[4], bv[4];
      #pragma unroll
      for (int i = 0; i < 4; ++i) {
        const int row = wr + i*16 + lr;
        int lk;
        if constexpr (BK == 32) lk = kk + ((hi ^ (lr >> 2)) * 8);
        else                    lk = ((((kk >> 3) + hi) + (row & 7)) & 7) * 8;
        af[i] = *(const bf16x8*)&sA[cur][row * BK + lk];
      }
      #pragma unroll
      for (int j = 0; j < 4; ++j) {
        const int row = wc + j*16 + lr;
        int lk;
        if constexpr (BK == 32) lk = kk + ((hi ^ (lr >> 2)) * 8);
        else                    lk = ((((kk >> 3) + hi) + (row & 7)) & 7) * 8;
        bv[j] = *(const bf16x8*)&sB[cur][row * BK + lk];
      }
      __builtin_amdgcn_s_setprio(1);
      #pragma unroll
      for (int i = 0; i < 4; ++i)
        #pragma unroll
        for (int j = 0; j < 4; ++j)
          acc[i][j] = MFMA16(af[i], bv[j], acc[i][j]);
      __builtin_amdgcn_s_setprio(0);
    }
    __builtin_amdgcn_sched_barrier(0);
    __builtin_amdgcn_s_barrier();
  }

  const int lq = hi * 4;
  u16* Cw = C + (long)zb * strC;
  #pragma unroll
  for (int i = 0; i < 4; ++i)
    #pragma unroll
    for (int r = 0; r < 4; ++r) {
      const int row = m0 + wr + i*16 + lq + r;
      if (row >= M) continue;
      #pragma unroll
      for (int j = 0; j < 4; ++j) {
        const int col = n0 + wc + j*16 + lr;
        if (col < N) Cw[(long)row * N + col] = f2bf(acc[i][j][r] * scale);
      }
    }
}

// ---------------------------------------------------------------------------
// Reduce kernels
// ---------------------------------------------------------------------------
__device__ __forceinline__ void addbf4(float* a, uint2 v) {
  a[0] += bf2f((u16)(v.x & 0xFFFFu));
  a[1] += bf2f((u16)(v.x >> 16));
  a[2] += bf2f((u16)(v.y & 0xFFFFu));
  a[3] += bf2f((u16)(v.y >> 16));
}

__global__ __launch_bounds__(256) void reduce_c1_bf(
    const u16* __restrict__ parts, u16* __restrict__ dst,
    const float* __restrict__ bias, int S)
{
  const long idx = (long)blockIdx.x * 256 + threadIdx.x;
  if (idx >= 1568L * 128) return;
  const int c4 = (int)(idx & 127), p = (int)(idx >> 7);
  const int c = c4 * 4;
  float sum[4] = {bias[c], bias[c+1], bias[c+2], bias[c+3]};
  for (int s = 0; s < S; ++s)
    addbf4(sum, *(const uint2*)&parts[((long)s * 1568 + p) * 512 + c]);
  const int im = p / 784, q = p - im * 784;
  const int qpad = (q / 28 + 1) * 30 + (q % 28 + 1);
  u16 o[4] = {f2bf(sum[0]), f2bf(sum[1]), f2bf(sum[2]), f2bf(sum[3])};
  *(uint2*)&dst[((long)im * 900 + qpad) * 512 + c] = *(uint2*)o;
}

__global__ __launch_bounds__(256) void reduceT_ro(
    const u16* __restrict__ parts, u16* __restrict__ dst, int S)
{
  __shared__ float tile[32][33];
  const int b = blockIdx.z, c0 = blockIdx.x * 32, p0 = blockIdx.y * 32;
  const int tx = threadIdx.x & 31, ty = threadIdx.x >> 5;
  for (int i = ty; i < 32; i += 8) {
    const int pc = min(p0 + tx, 783);
    float s = 0;
    for (int k = 0; k < S; ++k)
      s += bf2f(parts[((long)(b * S + k) * 1536 + c0 + i) * 784 + pc]);
    tile[i][tx] = s;
  }
  __syncthreads();
  for (int i = ty; i < 32; i += 8) {
    const int p = p0 + i, c = c0 + tx;
    if (p < 784) {
      const int n = c >> 9, cc = c & 511;
      const int qpad = (p / 28 + 1) * 30 + (p % 28 + 1);
      dst[((long)(b * 3 + n) * 900 + qpad) * 768 + cc] = f2bf(tile[tx][i]);
    }
  }
}

__global__ __launch_bounds__(256) void reduceT_qk(
    const float* __restrict__ parts, u16* __restrict__ dst,
    const float* __restrict__ bias, int S)
{
  __shared__ float tile[32][33];
  const int b = blockIdx.z, c0 = blockIdx.x * 32, p0 = blockIdx.y * 32;
  const int tx = threadIdx.x & 31, ty = threadIdx.x >> 5;
  for (int i = ty; i < 32; i += 8) {
    const int pc = min(p0 + tx, 783);
    const long base = (long)(c0 + i) * 1568 + b * 784 + pc;
    float s = 0;
    for (int k = 0; k < S; ++k) s += parts[(long)k * 64 * 1568 + base];
    tile[i][tx] = s;
  }
  __syncthreads();
  for (int i = ty; i < 32; i += 8) {
    const int p = p0 + i, c = c0 + tx;
    if (p < 784)
      dst[((long)b * 784 + p) * 64 + c] = f2bf(tile[tx][i] + bias[c]);
  }
}

// ---------------------------------------------------------------------------
// SINGLE-PASS in-place softmax over rows of 12544 bf16 (one block per row)
// ---------------------------------------------------------------------------
__global__ __launch_bounds__(256) void softmax_inplace(u16* __restrict__ buf)
{
  uint4* p4 = (uint4*)(buf + (long)blockIdx.x * 12544);
  const int t = threadIdx.x;
  __shared__ float red[4];
  uint4 v[7];
  float mx = -3.0e38f;
  #pragma unroll
  for (int q = 0; q < 7; ++q) {
    const int idx = t + q * 256;
    if (idx < 1568) {
      v[q] = p4[idx];
      const u32 w[4] = {v[q].x, v[q].y, v[q].z, v[q].w};
      #pragma unroll
      for (int e = 0; e < 4; ++e) {
        mx = fmaxf(mx, bf2f((u16)(w[e] & 0xFFFFu)));
        mx = fmaxf(mx, bf2f((u16)(w[e] >> 16)));
      }
    }
  }
  #pragma unroll
  for (int o = 32; o > 0; o >>= 1) mx = fmaxf(mx, __shfl_xor(mx, o));
  if ((t & 63) == 0) red[t >> 6] = mx;
  __syncthreads();
  mx = fmaxf(fmaxf(red[0], red[1]), fmaxf(red[2], red[3]));

  float s = 0.0f;
  #pragma unroll
  for (int q = 0; q < 7; ++q) {
    const int idx = t + q * 256;
    if (idx < 1568) {
      const u32 w[4] = {v[q].x, v[q].y, v[q].z, v[q].w};
      #pragma unroll
      for (int e = 0; e < 4; ++e) {
        s += __expf(bf2f((u16)(w[e] & 0xFFFFu)) - mx);
        s += __expf(bf2f((u16)(w[e] >> 16)) - mx);
      }
    }
  }
  #pragma unroll
  for (int o = 32; o > 0; o >>= 1) s += __shfl_xor(s, o);
  __syncthreads();
  if ((t & 63) == 0) red[t >> 6] = s;
  __syncthreads();
  const float inv = 1.0f / (red[0] + red[1] + red[2] + red[3]);

  #pragma unroll
  for (int q = 0; q < 7; ++q) {
    const int idx = t + q * 256;
    if (idx < 1568) {
      u32 w[4] = {v[q].x, v[q].y, v[q].z, v[q].w};
      #pragma unroll
      for (int e = 0; e < 4; ++e) {
        const float a = __expf(bf2f((u16)(w[e] & 0xFFFFu)) - mx) * inv;
        const float b = __expf(bf2f((u16)(w[e] >> 16)) - mx) * inv;
        w[e] = (u32)f2bf(a) | ((u32)f2bf(b) << 16);
      }
      p4[idx] = make_uint4(w[0], w[1], w[2], w[3]);
    }
  }
}

// ---------------------------------------------------------------------------
// fused_ro (512t, 128 KB dyn): readout gemm8p + transT_h + concatP borders.
// segments: [0,240) gemm | [240,1440) transT_h | [1440,1571) borders
// ---------------------------------------------------------------------------
__global__ __launch_bounds__(512, 2) void fused_ro(
    const u16* __restrict__ mvb, const u16* __restrict__ logaff,
    u16* __restrict__ parts, const float* __restrict__ hin,
    u16* __restrict__ concatP, int Kc, int S)
{
  extern __shared__ u16 smem[];
  const int bid = blockIdx.x, t = threadIdx.x;
  if (bid < 240) {
    gemm8p_dev<0>(bid, 240, mvb, logaff, parts, 1536, 784, Kc, 12544, S,
                  1536L * 12544, 784L * 12544, 1536L * 784, 0, 6, 4, 240, smem);
    return;
  }
  int lb = bid - 240;
  if (lb < 1200) {
    float (*tile)[33] = (float(*)[33])smem;
    const int bx = lb % 8, by = (lb / 8) % 25, zimg = lb / 200;
    const int c0 = bx * 32, p0 = by * 32;
    const int tx = t & 31, ty = t >> 5;
    for (int i = ty; i < 32; i += 16) {
      const int pc = min(p0 + tx, 783);
      tile[i][tx] = hin[((long)zimg * 256 + c0 + i) * 784 + pc];
    }
    __syncthreads();
    for (int i = ty; i < 32; i += 16) {
      const int p = p0 + i, c = c0 + tx;
      if (p < 784) {
        const int qpad = (p / 28 + 1) * 30 + (p % 28 + 1);
        concatP[((long)zimg * 900 + qpad) * 768 + 512 + c] = f2bf(tile[tx][i]);
      }
    }
    return;
  }
  lb -= 1200;
  const int gid = lb * 512 + t;
  if (gid < 66816) {
    const int c8 = gid % 96, rest = gid / 96;
    const int slot = rest % 116, img = rest / 116;
    int py, px; border_slot(slot, py, px);
    *(uint4*)&concatP[((long)img * 900 + py * 30 + px) * 768 + c8 * 8] =
        make_uint4(0, 0, 0, 0);
  }
}

// transform conv wrapper (8-phase, CONV=1)
__global__ __launch_bounds__(512, 2) void gemm8p_tr(
    const u16* __restrict__ A, const u16* __restrict__ B, u16* __restrict__ Cp,
    int M, int N, int Kc, int fullK, int S,
    long strC, int Cin, int gx, int gy, int nwg)
{
  extern __shared__ u16 smem[];
  gemm8p_dev<1>(blockIdx.x, (int)gridDim.x, A, B, Cp, M, N, Kc, fullK, S,
                0, 0, strC, Cin, gx, gy, nwg, smem);
}

// ---------------------------------------------------------------------------
// Fused transform-reduce + gating. bf16 parts [S][768][4704] (channel-major)
// ---------------------------------------------------------------------------
__global__ __launch_bounds__(256) void treduce_gate(
    const u16* __restrict__ parts, const float* __restrict__ bt,
    const float* __restrict__ h, float* __restrict__ out, int S)
{
  const long i = (long)blockIdx.x * 256 + threadIdx.x;
  if (i >= 6L * 256 * 196) return;
  const int p4 = (int)(i % 196);
  const int rest = (int)(i / 196);
  const int cs = rest % 256, im = rest / 256;
  const long slice = 768L * 4704;
  const long pbase = (long)im * 784 + p4 * 4;
  float F[4] = {}, U[4] = {}, NV[4] = {};
  for (int s = 0; s < S; ++s) {
    const u16* P = parts + (long)s * slice;
    addbf4(F,  *(const uint2*)&P[(long)cs         * 4704 + pbase]);
    addbf4(U,  *(const uint2*)&P[(long)(256 + cs) * 4704 + pbase]);
    addbf4(NV, *(const uint2*)&P[(long)(512 + cs) * 4704 + pbase]);
  }
  const float bF = bt[cs], bU = bt[256 + cs], bN = bt[512 + cs];
  const f32x4v hv = ((const f32x4v*)h)[((long)(im * 256 + cs) * 784 >> 2) + p4];
  f32x4v o;
  #pragma unroll
  for (int q = 0; q < 4; ++q) {
    const float f = F[q] + bF, u = U[q] + bU, nv = NV[q] + bN;
    const float sf = 1.0f / (1.0f + __expf(-f));
    const float su = 1.0f / (1.0f + __expf(-u));
    const float e2 = __expf(2.0f * nv);
    const float tv = (e2 - 1.0f) / (e2 + 1.0f);
    o[q] = sf * hv[q] * (1.0f - su) + su * tv;
  }
  ((f32x4v*)out)[((long)(im * 256 + cs) * 784 >> 2) + p4] = o;
}

__global__ __launch_bounds__(256) void fill_sentinel(float* p, long n) {
  const long i = (long)blockIdx.x * 256 + threadIdx.x;
  if (i < n) p[i] = 12345.0f;
}

// ---------------------------------------------------------------------------
extern "C" void kernel_launch(void* const* d_in, const int* in_sizes, int n_in,
                              void* d_out, int out_size, void* d_ws, size_t ws_size,
                              hipStream_t stream) {
  const float* f16 = (const float*)d_in[0];
  const float* mk  = (const float*)d_in[1];
  const float* mv  = (const float*)d_in[2];
  const float* hin = (const float*)d_in[3];
  const float* w1  = (const float*)d_in[4];
  const float* b1  = (const float*)d_in[5];
  const float* w2  = (const float*)d_in[6];
  const float* b2  = (const float*)d_in[7];
  const float* wt  = (const float*)d_in[8];
  const float* bt  = (const float*)d_in[9];
  float* out = (float*)d_out;

  (void)hipFuncSetAttribute((const void*)fused1,
                            hipFuncAttributeMaxDynamicSharedMemorySize, 73728);
  (void)hipFuncSetAttribute((const void*)fused_ro,
                            hipFuncAttributeMaxDynamicSharedMemorySize, 131072);
  (void)hipFuncSetAttribute((const void*)gemm8p_tr,
                            hipFuncAttributeMaxDynamicSharedMemorySize, 131072);
  constexpr unsigned DSMR = 73728, DSM8 = 131072;

  const size_t B_f16T   = 2UL*784*1024*2;
  const size_t B_w1b    = 512UL*1024*2;
  const size_t B_w2R    = 64UL*4608*2;
  const size_t B_out1P  = 2UL*900*512*2;
  const size_t B_qkT    = 2UL*784*64*2;
  const size_t B_concat = 6UL*900*768*2;
  const size_t B_wtR    = 768UL*6912*2;
  const size_t B_mkT    = 2UL*12544*64*2;
  const size_t B_logaff = 2UL*784*12544*2;
  const size_t B_mvb    = 38535168UL*2;
  auto al = [](size_t x) { return (x + 255) & ~(size_t)255; };

  const size_t phase1 = al(B_f16T) + al(B_w1b) + al(B_w2R) + al(B_out1P) + al(B_qkT);
  const size_t regionA = phase1 > al(B_concat) ? phase1 : al(B_concat);

  const int S_ro = 5, S_tr = 4, S_c1 = 8;
  const int Kc_ro = 2560, Kc_tr = 1728;
  auto poolBytes = [&]() -> size_t {
    size_t p2 = 18UL*64*1568*4;
    size_t p1 = (size_t)S_c1*1568*512*2;
    size_t pr = (size_t)(2*S_ro)*1536*784*2;
    size_t pt = (size_t)S_tr*768*4704*2;
    size_t m = p2; if (p1 > m) m = p1; if (pr > m) m = pr; if (pt > m) m = pt;
    return m;
  };
  const size_t fixed = regionA + al(B_wtR) + al(B_mkT) + al(B_logaff) + al(B_mvb);
  if (fixed + poolBytes() > ws_size) {
    fill_sentinel<<<4704, 256, 0, stream>>>(out, (long)out_size);
    return;
  }

  char* base = (char*)d_ws;
  size_t off = 0;
  auto alloc = [&](size_t bytes) -> char* { char* p = base + off; off += al(bytes); return p; };
  char* rA = alloc(regionA);
  u16* f16T   = (u16*)rA;
  u16* w1b    = (u16*)(rA + al(B_f16T));
  u16* w2R    = (u16*)(rA + al(B_f16T) + al(B_w1b));
  u16* out1P  = (u16*)(rA + al(B_f16T) + al(B_w1b) + al(B_w2R));
  u16* qkT    = (u16*)(rA + al(B_f16T) + al(B_w1b) + al(B_w2R) + al(B_out1P));
  u16* concatP = (u16*)rA;   // overlays phase-1 buffers (all dead before use)
  u16*   wtR     = (u16*)alloc(B_wtR);
  u16*   mkT     = (u16*)alloc(B_mkT);
  u16*   logaff  = (u16*)alloc(B_logaff);
  u16*   mvb     = (u16*)alloc(B_mvb);
  char*  partsRaw = alloc(poolBytes());
  float* partsF  = (float*)partsRaw;
  u16*   partsH  = (u16*)partsRaw;

  // 1) prep: transposes + w1 convert + weight permutes (high occupancy)
  prep1<<<25312, 256, 0, stream>>>(f16, mk, w1, w2, wt, f16T, mkT, w1b, w2R, wtR);

  // 2) fused: conv1 gemm + out1P borders
  fused1<<<253, 512, DSMR, stream>>>(f16T, w1b, partsH, out1P);

  // 3) conv1 reduce (+bias) -> padded channel-last out1P interior
  reduce_c1_bf<<<784, 256, 0, stream>>>(partsH, out1P, b1, S_c1);

  // 4) conv2 implicit-gemm + mv fp32->bf16 convert (32 KB static, 5 blk/CU)
  conv2_mv<<<2282, 256, 0, stream>>>(w2R, out1P, partsF, mv, mvb);

  // 5) conv2 reduce -> qkT
  reduceT_qk<<<dim3(2, 25, 2), 256, 0, stream>>>(partsF, qkT, b2, 18);

  // 6) logits: M=784, N=12544, K=64 -> bf16, scale 1/8
  gemm_glds<64><<<dim3(7, 98, 2), 256, 0, stream>>>(
      qkT, mkT, logaff, 784, 12544, 64, 64, 1,
      784L*64, 12544L*64, 784L*12544, 0.125f);

  // 7) softmax over memory axis
  softmax_inplace<<<1568, 256, 0, stream>>>(logaff);

  // 8) fused: readout gemm8p + transT_h + concatP borders
  fused_ro<<<1571, 512, DSM8, stream>>>(mvb, logaff, partsH, hin, concatP,
                                        Kc_ro, S_ro);

  // 9) readout reduce -> concatP interior ch 0..511
  reduceT_ro<<<dim3(48, 25, 2), 256, 0, stream>>>(partsH, concatP, S_ro);

  // 10) transform conv (8-phase, CONV=1)
  gemm8p_tr<<<232, 512, DSM8, stream>>>(wtR, concatP, partsH,
                                        768, 4704, Kc_tr, 6912, S_tr,
                                        768L*4704, 768, 3, 19, 228);

  // 11) fused reduce + gating -> d_out
  treduce_gate<<<1176, 256, 0, stream>>>(partsH, bt, hin, out, S_tr);
}

// Round 14
// 289.443 us; speedup vs baseline: 1.3769x; 1.0365x over previous
//
#include <hip/hip_runtime.h>

typedef unsigned short u16;
typedef unsigned int u32;
typedef float f32x4v __attribute__((ext_vector_type(4)));
typedef __bf16 bf16x8 __attribute__((ext_vector_type(8)));

#define GAS __attribute__((address_space(1)))
#define LAS __attribute__((address_space(3)))

__device__ __forceinline__ u16 f2bf(float f) {
  u32 u = __builtin_bit_cast(u32, f);
  u32 r = (u + 0x7FFFu + ((u >> 16) & 1u)) >> 16;  // RNE
  return (u16)r;
}
__device__ __forceinline__ float bf2f(u16 h) {
  return __builtin_bit_cast(float, (u32)h << 16);
}
__device__ __forceinline__ void gld_lds16(const void* g, void* l) {
  __builtin_amdgcn_global_load_lds((const GAS void*)g, (LAS void*)l, 16, 0, 0);
}
#define VMCNT(N) asm volatile("s_waitcnt vmcnt(" #N ")" ::: "memory")
#define MFMA16(a, b, c) __builtin_amdgcn_mfma_f32_16x16x32_bf16((a), (b), (c), 0, 0, 0)

// ---------------------------------------------------------------------------
// 8-PHASE 256x256 MFMA GEMM device body (m201 structure). BK=64 K-tiles;
// 512 thr / 8 waves (2M x 4N), per-wave 128x64, acc 8x4. 128 KB LDS.
// Counted vmcnt(4); bank-conflict-free chunk rotation both-sides; XCD-chunked
// remap; BF16 partials (fp32 accum); tail clamp restage.
// CONV=1: B rows = pixels of zero-padded channel-last stack [nImg][900][Cin].
// ---------------------------------------------------------------------------
template <int CONV>
__device__ __forceinline__ void gemm8p_dev(
    int lb, int Gpad, const u16* A, const u16* B, u16* Cp,
    int M, int N, int Kc, int fullK, int S,
    long strA, long strB, long strC, int Cin, int gx, int gy, int nwg, u16* smem)
{
  const int cpx = Gpad >> 3;
  const int L = (lb & 7) * cpx + (lb >> 3);
  if (L >= nwg) return;
  const int by = L % gy;
  const int rest = L / gy;
  const int bx = rest % gx;
  const int z = rest / gx;

  const int t = threadIdx.x, lane = t & 63, wave = t >> 6;
  const int zb = z / S, s = z - zb * S;
  const int m0 = bx * 256, n0 = by * 256;
  const int kbeg = s * Kc;
  const int kavail = fullK - kbeg;
  const int kc = Kc < kavail ? Kc : kavail;
  const int T = kc >> 6;

  const int srow = t >> 3;
  const int g = ((t & 7) - (srow & 7)) & 7;
  const int ldsoff = t * 8;

  const u16* Asrc[2][2];
  #pragma unroll
  for (int h = 0; h < 2; ++h)
    #pragma unroll
    for (int q = 0; q < 2; ++q) {
      int r = m0 + h * 128 + q * 64 + srow; if (r >= M) r = M - 1;
      Asrc[h][q] = A + (long)zb * strA + (long)r * fullK + kbeg + g * 8;
    }
  const u16* Bsrc[2][2];
  #pragma unroll
  for (int h = 0; h < 2; ++h)
    #pragma unroll
    for (int q = 0; q < 2; ++q) {
      if constexpr (CONV) {
        int pn = n0 + h * 128 + q * 64 + srow; if (pn >= N) pn = 0;
        const int img = pn / 784, p = pn - img * 784;
        const int py = p / 28, px = p - py * 28;
        Bsrc[h][q] = B + ((long)img * 900 + (py + 1) * 30 + (px + 1)) * Cin + g * 8;
      } else {
        int r = n0 + h * 128 + q * 64 + srow; if (r >= N) r = N - 1;
        Bsrc[h][q] = B + (long)zb * strB + (long)r * fullK + kbeg + g * 8;
      }
    }

  auto stageA = [&](int tile, int h) {
    u16* d = smem + (((tile & 1) * 2 + h) * 8192);
    const long ko = (long)tile * 64;
    gld_lds16(Asrc[h][0] + ko, d + ldsoff);
    gld_lds16(Asrc[h][1] + ko, d + 4096 + ldsoff);
  };
  auto stageB = [&](int tile, int h) {
    u16* d = smem + 32768 + (((tile & 1) * 2 + h) * 8192);
    long off;
    if constexpr (CONV) {
      const int kg = kbeg + tile * 64;
      const int tap = kg / Cin, kc2 = kg - tap * Cin;
      off = (long)((tap / 3 - 1) * 30 + (tap % 3 - 1)) * Cin + kc2;
    } else {
      off = (long)tile * 64;
    }
    gld_lds16(Bsrc[h][0] + off, d + ldsoff);
    gld_lds16(Bsrc[h][1] + off, d + 4096 + ldsoff);
  };

  const int wm = wave & 1, wn = wave >> 1;
  const int lr = lane & 15, hi = lane >> 4;
  const int slot0 = ((hi + (lr & 7)) & 7) * 8;
  const int slot1 = (((hi + 4) + (lr & 7)) & 7) * 8;
  f32x4v acc[8][4] = {};
  bf16x8 breg[4][2];

  stageB(0, 0); stageB(0, 1);
  stageA(0, 0); stageA(0, 1);
  stageB(1, 0); stageB(1, 1);
  VMCNT(4);
  __builtin_amdgcn_s_barrier();

  for (int tau = 0; tau < T; ++tau) {
    const int d = tau & 1;
    const u16* aB = smem + ((d * 2 + wm) * 8192);
    const u16* bB = smem + 32768 + ((d * 2 + (wn >> 1)) * 8192);
    const int ta = (tau + 1 < T) ? tau + 1 : T - 1;
    const int tb = (tau + 2 < T) ? tau + 2 : T - 1;
    #pragma unroll
    for (int Q = 0; Q < 4; ++Q) {
      bf16x8 aph[2][2];
      #pragma unroll
      for (int m2 = 0; m2 < 2; ++m2) {
        const int lrow = (Q * 2 + m2) * 16 + lr;
        aph[m2][0] = *(const bf16x8*)&aB[lrow * 64 + slot0];
        aph[m2][1] = *(const bf16x8*)&aB[lrow * 64 + slot1];
      }
      if (Q == 0) {
        #pragma unroll
        for (int n = 0; n < 4; ++n) {
          const int lrow = (wn & 1) * 64 + n * 16 + lr;
          breg[n][0] = *(const bf16x8*)&bB[lrow * 64 + slot0];
          breg[n][1] = *(const bf16x8*)&bB[lrow * 64 + slot1];
        }
      }
      if      (Q == 0) stageA(ta, 0);
      else if (Q == 1) stageA(ta, 1);
      else if (Q == 2) stageB(tb, 0);
      else             { stageB(tb, 1); VMCNT(4); }
      __builtin_amdgcn_sched_barrier(0);
      __builtin_amdgcn_s_barrier();
      __builtin_amdgcn_s_setprio(1);
      #pragma unroll
      for (int m2 = 0; m2 < 2; ++m2)
        #pragma unroll
        for (int n = 0; n < 4; ++n) {
          acc[Q * 2 + m2][n] = MFMA16(aph[m2][0], breg[n][0], acc[Q * 2 + m2][n]);
          acc[Q * 2 + m2][n] = MFMA16(aph[m2][1], breg[n][1], acc[Q * 2 + m2][n]);
        }
      __builtin_amdgcn_s_setprio(0);
      __builtin_amdgcn_sched_barrier(0);
      __builtin_amdgcn_s_barrier();
    }
  }
  VMCNT(0);

  u16* Co = Cp + (long)z * strC;
  #pragma unroll
  for (int m = 0; m < 8; ++m)
    #pragma unroll
    for (int r = 0; r < 4; ++r) {
      const int row = m0 + wm * 128 + m * 16 + hi * 4 + r;
      if (row >= M) continue;
      #pragma unroll
      for (int n = 0; n < 4; ++n) {
        const int col = n0 + wn * 64 + n * 16 + lr;
        if (col < N) Co[(long)row * N + col] = f2bf(acc[m][n][r]);
      }
    }
}

// ---------------------------------------------------------------------------
// 256x128 gemmRC device body (conv1): BK=32 depth-3 circular, vmcnt(6),
// 72 KB LDS, bf16 partials, XCD-chunked remap over Gpad segment.
// ---------------------------------------------------------------------------
__device__ __forceinline__ void gemmRC_dev(
    int lb, int Gpad, const u16* A, const u16* B, u16* Cp,
    int M, int N, int Kc, int fullK, int S,
    long strA, long strB, long strC, int gx, int gy, int nwg, u16* smem)
{
  const int cpx = Gpad >> 3;
  const int L = (lb & 7) * cpx + (lb >> 3);
  if (L >= nwg) return;
  const int by = L % gy;
  const int rest = L / gy;
  const int bx = rest % gx;
  const int z = rest / gx;

  u16* sA = smem;
  u16* sB = smem + 3 * 8192;
  const int t = threadIdx.x, lane = t & 63, wave = t >> 6;
  const int zb = z / S, s = z - zb * S;
  const int m0 = bx * 256, n0 = by * 128;
  const int kbeg = s * Kc;
  const int niter = Kc >> 5;

  const int schunk = ((t & 3) ^ ((t >> 4) & 3)) * 8;
  const u16* Ap[2]; const u16* Bp;
  #pragma unroll
  for (int q = 0; q < 2; ++q) {
    int ra = m0 + q * 128 + (t >> 2); if (ra >= M) ra = M - 1;
    Ap[q] = A + (long)zb * strA + (long)ra * fullK + schunk;
  }
  {
    int rb = n0 + (t >> 2); if (rb >= N) rb = N - 1;
    Bp = B + (long)zb * strB + (long)rb * fullK + schunk;
  }
  const int ldst = t * 8;

  auto stage = [&](int buf, int kg) {
    u16* dA = sA + buf * 8192;
    gld_lds16(Ap[0] + kg, &dA[ldst]);
    gld_lds16(Ap[1] + kg, &dA[4096 + ldst]);
    gld_lds16(Bp + kg,    &sB[buf * 4096 + ldst]);
  };

  const int wrow = (wave & 3) * 64, wcol = (wave >> 2) * 64;
  const int lr = lane & 15, hi = lane >> 4;
  const int csw = (hi ^ (lr >> 2)) * 8;
  f32x4v acc[4][4] = {};

  for (int p = 0; p < 2 && p < niter; ++p) stage(p, kbeg + p * 32);
  int cur = 0, nxt = 2;
  for (int it = 0; it < niter; ++it) {
    if (it + 2 < niter) {
      stage(nxt, kbeg + (it + 2) * 32);
      VMCNT(6);
    } else {
      const int rem = niter - 1 - it;
      if (rem == 1) VMCNT(3); else VMCNT(0);
    }
    __builtin_amdgcn_s_barrier();
    __builtin_amdgcn_sched_barrier(0);
    const u16* cA = sA + cur * 8192;
    const u16* cB = sB + cur * 4096;
    bf16x8 af[4], bf[4];
    #pragma unroll
    for (int m = 0; m < 4; ++m) af[m] = *(const bf16x8*)&cA[(wrow + m*16 + lr) * 32 + csw];
    #pragma unroll
    for (int n = 0; n < 4; ++n) bf[n] = *(const bf16x8*)&cB[(wcol + n*16 + lr) * 32 + csw];
    __builtin_amdgcn_s_setprio(1);
    #pragma unroll
    for (int m = 0; m < 4; ++m)
      #pragma unroll
      for (int n = 0; n < 4; ++n)
        acc[m][n] = MFMA16(af[m], bf[n], acc[m][n]);
    __builtin_amdgcn_s_setprio(0);
    __builtin_amdgcn_sched_barrier(0);
    __builtin_amdgcn_s_barrier();
    cur = (cur + 1 == 3) ? 0 : cur + 1;
    nxt = (nxt + 1 == 3) ? 0 : nxt + 1;
  }

  u16* Co = Cp + (long)z * strC;
  const int lq = hi * 4;
  #pragma unroll
  for (int m = 0; m < 4; ++m)
    #pragma unroll
    for (int r = 0; r < 4; ++r) {
      const int row = m0 + wrow + m * 16 + lq + r;
      if (row >= M) continue;
      #pragma unroll
      for (int n = 0; n < 4; ++n) {
        const int col = n0 + wcol + n * 16 + lr;
        if (col < N) Co[(long)row * N + col] = f2bf(acc[m][n][r]);
      }
    }
}

// ---------------------------------------------------------------------------
// Border slot id -> (py,px) in 30x30 frame (116 border slots)
// ---------------------------------------------------------------------------
__device__ __forceinline__ void border_slot(int slot, int& py, int& px) {
  if (slot < 30)      { py = 0;         px = slot; }
  else if (slot < 60) { py = 29;        px = slot - 30; }
  else if (slot < 88) { py = slot - 59; px = 0; }
  else                { py = slot - 87; px = 29; }
}

// ---------------------------------------------------------------------------
// prep1 (256t, 27.6 KB LDS -> 5 blk/CU): all independent BW prep work.
// segments: [0,1600) f16T | [1600,3168) mkT | [3168,3424) w1b
//   | [3424,3488) w2R (LDS-coalesced, 1 blk/m) | [3488,4256) wtR (1 blk/m)
//   | [4256,13664) mv convert (2 uint4-groups/thread)
// ---------------------------------------------------------------------------
__device__ __forceinline__ void transp_dev(
    const float* in, u16* out, int R, int C, int ldOut,
    int bx, int by, int t, float (*tile)[33])
{
  const int c0 = bx * 32, r0 = by * 32;
  const int tx = t & 31, ty = t >> 5;
  for (int i = ty; i < 32; i += 8) {
    const int r = r0 + i, c = c0 + tx;
    tile[i][tx] = (r < R && c < C) ? in[(long)r * C + c] : 0.0f;
  }
  __syncthreads();
  for (int i = ty; i < 32; i += 8) {
    const int r = r0 + tx, c = c0 + i;
    if (c < C && r < R)
      out[(long)c * ldOut + r] = f2bf(tile[tx][i]);
  }
}

__global__ __launch_bounds__(256) void prep1(
    const float* __restrict__ f16, const float* __restrict__ mk,
    const float* __restrict__ w1, const float* __restrict__ w2,
    const float* __restrict__ wt, const float* __restrict__ mv,
    u16* __restrict__ f16T, u16* __restrict__ mkT, u16* __restrict__ w1b,
    u16* __restrict__ w2R, u16* __restrict__ wtR, u16* __restrict__ mvb)
{
  __shared__ float scratch[6912];   // 27.6 KB; transposes use first 4.2 KB
  const int bid = blockIdx.x, t = threadIdx.x;
  if (bid < 1600) {
    const int bx = bid % 25, by = (bid / 25) % 32, bz = bid / 800;
    transp_dev(f16 + (long)bz * 1024 * 784, f16T + (long)bz * 784 * 1024,
               1024, 784, 1024, bx, by, t, (float(*)[33])scratch);
    return;
  }
  if (bid < 3168) {
    const int lb = bid - 1600;
    const int bx = lb % 392, by = (lb / 392) % 2, bz = lb / 784;
    transp_dev(mk + (long)bz * 64 * 12544, mkT + (long)bz * 12544 * 64,
               64, 12544, 64, bx, by, t, (float(*)[33])scratch);
    return;
  }
  if (bid < 3424) {
    const long i = (long)(bid - 3168) * 256 + t;
    const float4* p = (const float4*)w1 + i * 2;
    const float4 a = p[0], b = p[1];
    u16 o[8] = {f2bf(a.x), f2bf(a.y), f2bf(a.z), f2bf(a.w),
                f2bf(b.x), f2bf(b.y), f2bf(b.z), f2bf(b.w)};
    ((uint4*)w1b)[i] = *(uint4*)o;
    return;
  }
  if (bid < 3488) {   // w2R: m = bid-3424; coalesced read 512*9 f32 -> LDS
    const int m = bid - 3424;
    const float* src = w2 + (long)m * 4608;
    for (int j = t; j < 4608; j += 256) scratch[j] = src[j];
    __syncthreads();
    u16* dst = w2R + (long)m * 4608;
    #pragma unroll
    for (int tap = 0; tap < 9; ++tap)
      for (int c = t; c < 512; c += 256)
        dst[tap * 512 + c] = f2bf(scratch[c * 9 + tap]);   // stride-9: conflict-free
    return;
  }
  if (bid < 4256) {   // wtR: m = bid-3488; 768*9 f32 via LDS
    const int m = bid - 3488;
    const float* src = wt + (long)m * 6912;
    for (int j = t; j < 6912; j += 256) scratch[j] = src[j];
    __syncthreads();
    u16* dst = wtR + (long)m * 6912;
    #pragma unroll
    for (int tap = 0; tap < 9; ++tap)
      for (int c = t; c < 768; c += 256)
        dst[tap * 768 + c] = f2bf(scratch[c * 9 + tap]);
    return;
  }
  {                   // mv convert: 4816896 uint4-groups, 2/thread
    const long g0 = (long)(bid - 4256) * 512 + t;
    #pragma unroll
    for (int k = 0; k < 2; ++k) {
      const long g = g0 + k * 256;
      const float4* p = (const float4*)mv + g * 2;
      const float4 a = p[0], b = p[1];
      u16 o[8] = {f2bf(a.x), f2bf(a.y), f2bf(a.z), f2bf(a.w),
                  f2bf(b.x), f2bf(b.y), f2bf(b.z), f2bf(b.w)};
      ((uint4*)mvb)[g] = *(uint4*)o;
    }
  }
}

// ---------------------------------------------------------------------------
// fused1 (512t, 72 KB dyn): conv1-gemmRC + out1P borders.
// ---------------------------------------------------------------------------
__global__ __launch_bounds__(512, 4) void fused1(
    const u16* __restrict__ f16T, const u16* __restrict__ w1b,
    u16* __restrict__ parts, u16* __restrict__ out1P)
{
  extern __shared__ u16 smem[];
  const int bid = blockIdx.x, t = threadIdx.x;
  if (bid < 224) {
    gemmRC_dev(bid, 224, f16T, w1b, parts, 1568, 512, 128, 1024, 8,
               0, 0, 1568L * 512, 7, 4, 224, smem);
    return;
  }
  const int gid = (bid - 224) * 512 + t;
  if (gid < 14848) {
    const int c8 = gid & 63, rest = gid >> 6;
    const int slot = rest % 116, img = rest / 116;
    int py, px; border_slot(slot, py, px);
    *(uint4*)&out1P[((long)img * 900 + py * 30 + px) * 512 + c8 * 8] =
        make_uint4(0, 0, 0, 0);
  }
}

// ---------------------------------------------------------------------------
// conv2_k (256t, 32 KB static): conv2 implicit-gemm only (grid 234).
// ---------------------------------------------------------------------------
__global__ __launch_bounds__(256) void conv2_k(
    const u16* __restrict__ Wt, const u16* __restrict__ imgP,
    float* __restrict__ Cp)
{
  __shared__ u16 sA[2][128 * 32];
  __shared__ u16 sB[2][128 * 32];
  const int bid = blockIdx.x, t = threadIdx.x;
  const int lane = t & 63, wave = t >> 6;
  const int z = bid / 13;
  const int m0 = 0, n0 = (bid % 13) * 128;
  const int Cin = 512, Ntot = 1568, M = 64, Kc = 256;
  const int kbeg = z * Kc;

  const u16* Aptr[2]; const u16* Bptr[2]; int lofs[2];
  #pragma unroll
  for (int i = 0; i < 2; ++i) {
    const int tp = i * 256 + t;
    const int r = tp >> 2;
    const int c16 = (tp & 3) ^ ((tp >> 4) & 3);
    int ra = m0 + r; if (ra >= M) ra = M - 1;
    int pn = n0 + r; if (pn >= Ntot) pn = 0;
    const int img = pn / 784, p = pn - img * 784;
    const int py = p / 28, px = p - py * 28;
    Aptr[i] = Wt + (long)ra * (9 * Cin) + c16 * 8;
    Bptr[i] = imgP + ((long)img * 900 + (py + 1) * 30 + (px + 1)) * Cin + c16 * 8;
    lofs[i] = (i * 256 + (wave << 6)) * 8;
  }
  auto stage = [&](int buf, int kg) {
    const int tap = kg / Cin, kc = kg - tap * Cin;
    const long off = (long)((tap / 3 - 1) * 30 + (tap % 3 - 1)) * Cin + kc;
    #pragma unroll
    for (int i = 0; i < 2; ++i) {
      gld_lds16(Aptr[i] + kg, &sA[buf][lofs[i]]);
      gld_lds16(Bptr[i] + off, &sB[buf][lofs[i]]);
    }
  };

  const int wr = (wave >> 1) * 64, wc = (wave & 1) * 64;
  const int lr = lane & 15, hi = lane >> 4;
  const int csw = (hi ^ (lr >> 2)) * 8;
  f32x4v acc[4][4] = {};
  const int niter = Kc >> 5;

  stage(0, kbeg);
  for (int it = 0; it < niter; ++it) {
    const int cur = it & 1;
    if (it + 1 < niter) {
      stage(cur ^ 1, kbeg + (it + 1) * 32);
      VMCNT(4);
    } else {
      VMCNT(0);
    }
    __builtin_amdgcn_s_barrier();
    __builtin_amdgcn_sched_barrier(0);
    bf16x8 af[4], bv[4];
    #pragma unroll
    for (int i = 0; i < 4; ++i) af[i] = *(const bf16x8*)&sA[cur][(wr + i*16 + lr) * 32 + csw];
    #pragma unroll
    for (int j = 0; j < 4; ++j) bv[j] = *(const bf16x8*)&sB[cur][(wc + j*16 + lr) * 32 + csw];
    __builtin_amdgcn_s_setprio(1);
    #pragma unroll
    for (int i = 0; i < 4; ++i)
      #pragma unroll
      for (int j = 0; j < 4; ++j)
        acc[i][j] = MFMA16(af[i], bv[j], acc[i][j]);
    __builtin_amdgcn_s_setprio(0);
    __builtin_amdgcn_sched_barrier(0);
    __builtin_amdgcn_s_barrier();
  }

  float* Co = Cp + (long)z * M * Ntot;
  const int lq = hi * 4;
  #pragma unroll
  for (int i = 0; i < 4; ++i)
    #pragma unroll
    for (int r = 0; r < 4; ++r) {
      const int row = m0 + wr + i*16 + lq + r;
      if (row >= M) continue;
      #pragma unroll
      for (int j = 0; j < 4; ++j) {
        const int col = n0 + wc + j*16 + lr;
        if (col < Ntot) Co[(long)row * Ntot + col] = acc[i][j][r];
      }
    }
}

// ---------------------------------------------------------------------------
// 128x128 glds GEMM (logits). Counted-vmcnt depth-1, BK=64 rotation swizzle.
// ---------------------------------------------------------------------------
template <int BK>
__global__ __launch_bounds__(256) void gemm_glds(
    const u16* __restrict__ A, const u16* __restrict__ B, u16* __restrict__ C,
    int M, int N, int Kc, int fullK, int S,
    long strA, long strB, long strC, float scale)
{
  constexpr int CPR = BK / 8;
  constexpr int ISS = BK / 16;
  __shared__ u16 sA[2][128 * BK];
  __shared__ u16 sB[2][128 * BK];
  const int t = threadIdx.x, lane = t & 63, wave = t >> 6;
  const int z = blockIdx.z, zb = z / S;
  const int m0 = blockIdx.x * 128, n0 = blockIdx.y * 128;
  const int kbeg = (z - zb * S) * Kc;

  const u16* Aptr[ISS]; const u16* Bptr[ISS]; int lofs[ISS];
  #pragma unroll
  for (int i = 0; i < ISS; ++i) {
    const int tp = i * 256 + t;
    const int r = tp / CPR;
    int c16 = tp % CPR;
    if constexpr (BK == 32) c16 = c16 ^ ((tp >> 4) & 3);
    else                    c16 = (c16 - (r & 7)) & 7;
    int ra = m0 + r; if (ra >= M) ra = M - 1;
    int rb = n0 + r; if (rb >= N) rb = N - 1;
    Aptr[i] = A + (long)zb * strA + (long)ra * fullK + kbeg + c16 * 8;
    Bptr[i] = B + (long)zb * strB + (long)rb * fullK + kbeg + c16 * 8;
    lofs[i] = (i * 256 + (wave << 6)) * 8;
  }
  auto stage = [&](int buf, int k0) {
    #pragma unroll
    for (int i = 0; i < ISS; ++i) {
      gld_lds16(Aptr[i] + k0, &sA[buf][lofs[i]]);
      gld_lds16(Bptr[i] + k0, &sB[buf][lofs[i]]);
    }
  };

  const int wr = (wave >> 1) * 64, wc = (wave & 1) * 64;
  const int lr = lane & 15, hi = lane >> 4;
  f32x4v acc[4][4] = {};
  const int niter = Kc / BK;

  stage(0, 0);
  for (int it = 0; it < niter; ++it) {
    const int cur = it & 1;
    if (it + 1 < niter) {
      stage(cur ^ 1, (it + 1) * BK);
      if constexpr (ISS == 2) VMCNT(4); else VMCNT(8);
    } else {
      VMCNT(0);
    }
    __builtin_amdgcn_s_barrier();
    __builtin_amdgcn_sched_barrier(0);
    #pragma unroll
    for (int kk = 0; kk < BK; kk += 32) {
      bf16x8 af[4], bv[4];
      #pragma unroll
      for (int i = 0; i < 4; ++i) {
        const int row = wr + i*16 + lr;
        int lk;
        if constexpr (BK == 32) lk = kk + ((hi ^ (lr >> 2)) * 8);
        else                    lk = ((((kk >> 3) + hi) + (row & 7)) & 7) * 8;
        af[i] = *(const bf16x8*)&sA[cur][row * BK + lk];
      }
      #pragma unroll
      for (int j = 0; j < 4; ++j) {
        const int row = wc + j*16 + lr;
        int lk;
        if constexpr (BK == 32) lk = kk + ((hi ^ (lr >> 2)) * 8);
        else                    lk = ((((kk >> 3) + hi) + (row & 7)) & 7) * 8;
        bv[j] = *(const bf16x8*)&sB[cur][row * BK + lk];
      }
      __builtin_amdgcn_s_setprio(1);
      #pragma unroll
      for (int i = 0; i < 4; ++i)
        #pragma unroll
        for (int j = 0; j < 4; ++j)
          acc[i][j] = MFMA16(af[i], bv[j], acc[i][j]);
      __builtin_amdgcn_s_setprio(0);
    }
    __builtin_amdgcn_sched_barrier(0);
    __builtin_amdgcn_s_barrier();
  }

  const int lq = hi * 4;
  u16* Cw = C + (long)zb * strC;
  #pragma unroll
  for (int i = 0; i < 4; ++i)
    #pragma unroll
    for (int r = 0; r < 4; ++r) {
      const int row = m0 + wr + i*16 + lq + r;
      if (row >= M) continue;
      #pragma unroll
      for (int j = 0; j < 4; ++j) {
        const int col = n0 + wc + j*16 + lr;
        if (col < N) Cw[(long)row * N + col] = f2bf(acc[i][j][r] * scale);
      }
    }
}

// ---------------------------------------------------------------------------
// Reduce kernels
// ---------------------------------------------------------------------------
__device__ __forceinline__ void addbf4(float* a, uint2 v) {
  a[0] += bf2f((u16)(v.x & 0xFFFFu));
  a[1] += bf2f((u16)(v.x >> 16));
  a[2] += bf2f((u16)(v.y & 0xFFFFu));
  a[3] += bf2f((u16)(v.y >> 16));
}

__global__ __launch_bounds__(256) void reduce_c1_bf(
    const u16* __restrict__ parts, u16* __restrict__ dst,
    const float* __restrict__ bias, int S)
{
  const long idx = (long)blockIdx.x * 256 + threadIdx.x;
  if (idx >= 1568L * 128) return;
  const int c4 = (int)(idx & 127), p = (int)(idx >> 7);
  const int c = c4 * 4;
  float sum[4] = {bias[c], bias[c+1], bias[c+2], bias[c+3]};
  for (int s = 0; s < S; ++s)
    addbf4(sum, *(const uint2*)&parts[((long)s * 1568 + p) * 512 + c]);
  const int im = p / 784, q = p - im * 784;
  const int qpad = (q / 28 + 1) * 30 + (q % 28 + 1);
  u16 o[4] = {f2bf(sum[0]), f2bf(sum[1]), f2bf(sum[2]), f2bf(sum[3])};
  *(uint2*)&dst[((long)im * 900 + qpad) * 512 + c] = *(uint2*)o;
}

__global__ __launch_bounds__(256) void reduceT_ro(
    const u16* __restrict__ parts, u16* __restrict__ dst, int S)
{
  __shared__ float tile[32][33];
  const int b = blockIdx.z, c0 = blockIdx.x * 32, p0 = blockIdx.y * 32;
  const int tx = threadIdx.x & 31, ty = threadIdx.x >> 5;
  for (int i = ty; i < 32; i += 8) {
    const int pc = min(p0 + tx, 783);
    float s = 0;
    for (int k = 0; k < S; ++k)
      s += bf2f(parts[((long)(b * S + k) * 1536 + c0 + i) * 784 + pc]);
    tile[i][tx] = s;
  }
  __syncthreads();
  for (int i = ty; i < 32; i += 8) {
    const int p = p0 + i, c = c0 + tx;
    if (p < 784) {
      const int n = c >> 9, cc = c & 511;
      const int qpad = (p / 28 + 1) * 30 + (p % 28 + 1);
      dst[((long)(b * 3 + n) * 900 + qpad) * 768 + cc] = f2bf(tile[tx][i]);
    }
  }
}

__global__ __launch_bounds__(256) void reduceT_qk(
    const float* __restrict__ parts, u16* __restrict__ dst,
    const float* __restrict__ bias, int S)
{
  __shared__ float tile[32][33];
  const int b = blockIdx.z, c0 = blockIdx.x * 32, p0 = blockIdx.y * 32;
  const int tx = threadIdx.x & 31, ty = threadIdx.x >> 5;
  for (int i = ty; i < 32; i += 8) {
    const int pc = min(p0 + tx, 783);
    const long base = (long)(c0 + i) * 1568 + b * 784 + pc;
    float s = 0;
    for (int k = 0; k < S; ++k) s += parts[(long)k * 64 * 1568 + base];
    tile[i][tx] = s;
  }
  __syncthreads();
  for (int i = ty; i < 32; i += 8) {
    const int p = p0 + i, c = c0 + tx;
    if (p < 784)
      dst[((long)b * 784 + p) * 64 + c] = f2bf(tile[tx][i] + bias[c]);
  }
}

// ---------------------------------------------------------------------------
// SINGLE-PASS in-place softmax over rows of 12544 bf16 (one block per row)
// ---------------------------------------------------------------------------
__global__ __launch_bounds__(256) void softmax_inplace(u16* __restrict__ buf)
{
  uint4* p4 = (uint4*)(buf + (long)blockIdx.x * 12544);
  const int t = threadIdx.x;
  __shared__ float red[4];
  uint4 v[7];
  float mx = -3.0e38f;
  #pragma unroll
  for (int q = 0; q < 7; ++q) {
    const int idx = t + q * 256;
    if (idx < 1568) {
      v[q] = p4[idx];
      const u32 w[4] = {v[q].x, v[q].y, v[q].z, v[q].w};
      #pragma unroll
      for (int e = 0; e < 4; ++e) {
        mx = fmaxf(mx, bf2f((u16)(w[e] & 0xFFFFu)));
        mx = fmaxf(mx, bf2f((u16)(w[e] >> 16)));
      }
    }
  }
  #pragma unroll
  for (int o = 32; o > 0; o >>= 1) mx = fmaxf(mx, __shfl_xor(mx, o));
  if ((t & 63) == 0) red[t >> 6] = mx;
  __syncthreads();
  mx = fmaxf(fmaxf(red[0], red[1]), fmaxf(red[2], red[3]));

  float s = 0.0f;
  #pragma unroll
  for (int q = 0; q < 7; ++q) {
    const int idx = t + q * 256;
    if (idx < 1568) {
      const u32 w[4] = {v[q].x, v[q].y, v[q].z, v[q].w};
      #pragma unroll
      for (int e = 0; e < 4; ++e) {
        s += __expf(bf2f((u16)(w[e] & 0xFFFFu)) - mx);
        s += __expf(bf2f((u16)(w[e] >> 16)) - mx);
      }
    }
  }
  #pragma unroll
  for (int o = 32; o > 0; o >>= 1) s += __shfl_xor(s, o);
  __syncthreads();
  if ((t & 63) == 0) red[t >> 6] = s;
  __syncthreads();
  const float inv = 1.0f / (red[0] + red[1] + red[2] + red[3]);

  #pragma unroll
  for (int q = 0; q < 7; ++q) {
    const int idx = t + q * 256;
    if (idx < 1568) {
      u32 w[4] = {v[q].x, v[q].y, v[q].z, v[q].w};
      #pragma unroll
      for (int e = 0; e < 4; ++e) {
        const float a = __expf(bf2f((u16)(w[e] & 0xFFFFu)) - mx) * inv;
        const float b = __expf(bf2f((u16)(w[e] >> 16)) - mx) * inv;
        w[e] = (u32)f2bf(a) | ((u32)f2bf(b) << 16);
      }
      p4[idx] = make_uint4(w[0], w[1], w[2], w[3]);
    }
  }
}

// ---------------------------------------------------------------------------
// fused_ro (512t, 128 KB dyn): readout gemm8p + transT_h + concatP borders.
// ---------------------------------------------------------------------------
__global__ __launch_bounds__(512, 2) void fused_ro(
    const u16* __restrict__ mvb, const u16* __restrict__ logaff,
    u16* __restrict__ parts, const float* __restrict__ hin,
    u16* __restrict__ concatP, int Kc, int S)
{
  extern __shared__ u16 smem[];
  const int bid = blockIdx.x, t = threadIdx.x;
  if (bid < 240) {
    gemm8p_dev<0>(bid, 240, mvb, logaff, parts, 1536, 784, Kc, 12544, S,
                  1536L * 12544, 784L * 12544, 1536L * 784, 0, 6, 4, 240, smem);
    return;
  }
  int lb = bid - 240;
  if (lb < 1200) {
    float (*tile)[33] = (float(*)[33])smem;
    const int bx = lb % 8, by = (lb / 8) % 25, zimg = lb / 200;
    const int c0 = bx * 32, p0 = by * 32;
    const int tx = t & 31, ty = t >> 5;
    for (int i = ty; i < 32; i += 16) {
      const int pc = min(p0 + tx, 783);
      tile[i][tx] = hin[((long)zimg * 256 + c0 + i) * 784 + pc];
    }
    __syncthreads();
    for (int i = ty; i < 32; i += 16) {
      const int p = p0 + i, c = c0 + tx;
      if (p < 784) {
        const int qpad = (p / 28 + 1) * 30 + (p % 28 + 1);
        concatP[((long)zimg * 900 + qpad) * 768 + 512 + c] = f2bf(tile[tx][i]);
      }
    }
    return;
  }
  lb -= 1200;
  const int gid = lb * 512 + t;
  if (gid < 66816) {
    const int c8 = gid % 96, rest = gid / 96;
    const int slot = rest % 116, img = rest / 116;
    int py, px; border_slot(slot, py, px);
    *(uint4*)&concatP[((long)img * 900 + py * 30 + px) * 768 + c8 * 8] =
        make_uint4(0, 0, 0, 0);
  }
}

// transform conv wrapper (8-phase, CONV=1)
__global__ __launch_bounds__(512, 2) void gemm8p_tr(
    const u16* __restrict__ A, const u16* __restrict__ B, u16* __restrict__ Cp,
    int M, int N, int Kc, int fullK, int S,
    long strC, int Cin, int gx, int gy, int nwg)
{
  extern __shared__ u16 smem[];
  gemm8p_dev<1>(blockIdx.x, (int)gridDim.x, A, B, Cp, M, N, Kc, fullK, S,
                0, 0, strC, Cin, gx, gy, nwg, smem);
}

// ---------------------------------------------------------------------------
// Fused transform-reduce + gating. bf16 parts [S][768][4704] (channel-major)
// ---------------------------------------------------------------------------
__global__ __launch_bounds__(256) void treduce_gate(
    const u16* __restrict__ parts, const float* __restrict__ bt,
    const float* __restrict__ h, float* __restrict__ out, int S)
{
  const long i = (long)blockIdx.x * 256 + threadIdx.x;
  if (i >= 6L * 256 * 196) return;
  const int p4 = (int)(i % 196);
  const int rest = (int)(i / 196);
  const int cs = rest % 256, im = rest / 256;
  const long slice = 768L * 4704;
  const long pbase = (long)im * 784 + p4 * 4;
  float F[4] = {}, U[4] = {}, NV[4] = {};
  for (int s = 0; s < S; ++s) {
    const u16* P = parts + (long)s * slice;
    addbf4(F,  *(const uint2*)&P[(long)cs         * 4704 + pbase]);
    addbf4(U,  *(const uint2*)&P[(long)(256 + cs) * 4704 + pbase]);
    addbf4(NV, *(const uint2*)&P[(long)(512 + cs) * 4704 + pbase]);
  }
  const float bF = bt[cs], bU = bt[256 + cs], bN = bt[512 + cs];
  const f32x4v hv = ((const f32x4v*)h)[((long)(im * 256 + cs) * 784 >> 2) + p4];
  f32x4v o;
  #pragma unroll
  for (int q = 0; q < 4; ++q) {
    const float f = F[q] + bF, u = U[q] + bU, nv = NV[q] + bN;
    const float sf = 1.0f / (1.0f + __expf(-f));
    const float su = 1.0f / (1.0f + __expf(-u));
    const float e2 = __expf(2.0f * nv);
    const float tv = (e2 - 1.0f) / (e2 + 1.0f);
    o[q] = sf * hv[q] * (1.0f - su) + su * tv;
  }
  ((f32x4v*)out)[((long)(im * 256 + cs) * 784 >> 2) + p4] = o;
}

__global__ __launch_bounds__(256) void fill_sentinel(float* p, long n) {
  const long i = (long)blockIdx.x * 256 + threadIdx.x;
  if (i < n) p[i] = 12345.0f;
}

// ---------------------------------------------------------------------------
extern "C" void kernel_launch(void* const* d_in, const int* in_sizes, int n_in,
                              void* d_out, int out_size, void* d_ws, size_t ws_size,
                              hipStream_t stream) {
  const float* f16 = (const float*)d_in[0];
  const float* mk  = (const float*)d_in[1];
  const float* mv  = (const float*)d_in[2];
  const float* hin = (const float*)d_in[3];
  const float* w1  = (const float*)d_in[4];
  const float* b1  = (const float*)d_in[5];
  const float* w2  = (const float*)d_in[6];
  const float* b2  = (const float*)d_in[7];
  const float* wt  = (const float*)d_in[8];
  const float* bt  = (const float*)d_in[9];
  float* out = (float*)d_out;

  (void)hipFuncSetAttribute((const void*)fused1,
                            hipFuncAttributeMaxDynamicSharedMemorySize, 73728);
  (void)hipFuncSetAttribute((const void*)fused_ro,
                            hipFuncAttributeMaxDynamicSharedMemorySize, 131072);
  (void)hipFuncSetAttribute((const void*)gemm8p_tr,
                            hipFuncAttributeMaxDynamicSharedMemorySize, 131072);
  constexpr unsigned DSMR = 73728, DSM8 = 131072;

  const size_t B_f16T   = 2UL*784*1024*2;
  const size_t B_w1b    = 512UL*1024*2;
  const size_t B_w2R    = 64UL*4608*2;
  const size_t B_out1P  = 2UL*900*512*2;
  const size_t B_qkT    = 2UL*784*64*2;
  const size_t B_concat = 6UL*900*768*2;
  const size_t B_wtR    = 768UL*6912*2;
  const size_t B_mkT    = 2UL*12544*64*2;
  const size_t B_logaff = 2UL*784*12544*2;
  const size_t B_mvb    = 38535168UL*2;
  auto al = [](size_t x) { return (x + 255) & ~(size_t)255; };

  const size_t phase1 = al(B_f16T) + al(B_w1b) + al(B_w2R) + al(B_out1P) + al(B_qkT);
  const size_t regionA = phase1 > al(B_concat) ? phase1 : al(B_concat);

  const int S_ro = 5, S_tr = 4, S_c1 = 8;
  const int Kc_ro = 2560, Kc_tr = 1728;
  auto poolBytes = [&]() -> size_t {
    size_t p2 = 18UL*64*1568*4;
    size_t p1 = (size_t)S_c1*1568*512*2;
    size_t pr = (size_t)(2*S_ro)*1536*784*2;
    size_t pt = (size_t)S_tr*768*4704*2;
    size_t m = p2; if (p1 > m) m = p1; if (pr > m) m = pr; if (pt > m) m = pt;
    return m;
  };
  const size_t fixed = regionA + al(B_wtR) + al(B_mkT) + al(B_logaff) + al(B_mvb);
  if (fixed + poolBytes() > ws_size) {
    fill_sentinel<<<4704, 256, 0, stream>>>(out, (long)out_size);
    return;
  }

  char* base = (char*)d_ws;
  size_t off = 0;
  auto alloc = [&](size_t bytes) -> char* { char* p = base + off; off += al(bytes); return p; };
  char* rA = alloc(regionA);
  u16* f16T   = (u16*)rA;
  u16* w1b    = (u16*)(rA + al(B_f16T));
  u16* w2R    = (u16*)(rA + al(B_f16T) + al(B_w1b));
  u16* out1P  = (u16*)(rA + al(B_f16T) + al(B_w1b) + al(B_w2R));
  u16* qkT    = (u16*)(rA + al(B_f16T) + al(B_w1b) + al(B_w2R) + al(B_out1P));
  u16* concatP = (u16*)rA;   // overlays phase-1 buffers (all dead before use)
  u16*   wtR     = (u16*)alloc(B_wtR);
  u16*   mkT     = (u16*)alloc(B_mkT);
  u16*   logaff  = (u16*)alloc(B_logaff);
  u16*   mvb     = (u16*)alloc(B_mvb);
  char*  partsRaw = alloc(poolBytes());
  float* partsF  = (float*)partsRaw;
  u16*   partsH  = (u16*)partsRaw;

  // 1) prep: ALL independent BW work incl. mv convert (high occupancy)
  prep1<<<13664, 256, 0, stream>>>(f16, mk, w1, w2, wt, mv,
                                   f16T, mkT, w1b, w2R, wtR, mvb);

  // 2) fused: conv1 gemm + out1P borders
  fused1<<<253, 512, DSMR, stream>>>(f16T, w1b, partsH, out1P);

  // 3) conv1 reduce (+bias) -> padded channel-last out1P interior
  reduce_c1_bf<<<784, 256, 0, stream>>>(partsH, out1P, b1, S_c1);

  // 4) conv2 implicit-gemm (grid 234)
  conv2_k<<<234, 256, 0, stream>>>(w2R, out1P, partsF);

  // 5) conv2 reduce -> qkT
  reduceT_qk<<<dim3(2, 25, 2), 256, 0, stream>>>(partsF, qkT, b2, 18);

  // 6) logits: M=784, N=12544, K=64 -> bf16, scale 1/8
  gemm_glds<64><<<dim3(7, 98, 2), 256, 0, stream>>>(
      qkT, mkT, logaff, 784, 12544, 64, 64, 1,
      784L*64, 12544L*64, 784L*12544, 0.125f);

  // 7) softmax over memory axis
  softmax_inplace<<<1568, 256, 0, stream>>>(logaff);

  // 8) fused: readout gemm8p + transT_h + concatP borders
  fused_ro<<<1571, 512, DSM8, stream>>>(mvb, logaff, partsH, hin, concatP,
                                        Kc_ro, S_ro);

  // 9) readout reduce -> concatP interior ch 0..511
  reduceT_ro<<<dim3(48, 25, 2), 256, 0, stream>>>(partsH, concatP, S_ro);

  // 10) transform conv (8-phase, CONV=1)
  gemm8p_tr<<<232, 512, DSM8, stream>>>(wtR, concatP, partsH,
                                        768, 4704, Kc_tr, 6912, S_tr,
                                        768L*4704, 768, 3, 19, 228);

  // 11) fused reduce + gating -> d_out
  treduce_gate<<<1176, 256, 0, stream>>>(partsH, bt, hin, out, S_tr);
}